// Round 1
// baseline (2047.044 us; speedup 1.0000x reference)
//
#include <hip/hip_runtime.h>
#include <math.h>

// ---------------- problem constants (fixed instance) ----------------
constexpr int Bn   = 8;
constexpr int Hh   = 64;
constexpr int Ww   = 64;
constexpr int Nn   = Hh * Ww;      // 4096
constexpr int Mrows = Bn * Nn;     // 32768
constexpr int QKVC = 512;          // qv channels
constexpr int DIMc = 256;

__device__ __forceinline__ float hswish(float x) {
    float r = fminf(fmaxf(x + 3.f, 0.f), 6.f);
    return x * r * (1.f / 6.f);
}

// ---------------- tiled SGEMM: C = act(A) @ B + bias ----------------
// BM=BN=128, BK=8, TM=TN=8, 256 threads
template<bool ACT_IN>
__global__ __launch_bounds__(256) void sgemm_kernel(
    const float* __restrict__ A, const float* __restrict__ Bm,
    const float* __restrict__ bias, float* __restrict__ C,
    int Md, int Nd, int Kd)
{
    constexpr int BM = 128, BN = 128, BK = 8, TM = 8, TN = 8;
    __shared__ float As[BK][BM + 4];
    __shared__ float Bs[BK][BN];
    const int tid = threadIdx.x;
    const int tx = tid & 15, ty = tid >> 4;
    const int brow = blockIdx.y * BM;
    const int bcol = blockIdx.x * BN;

    float acc[TM][TN] = {};

    const int arow = tid >> 1;            // 0..127
    const int akq  = (tid & 1) * 4;       // 0 or 4
    const int bkrow = tid >> 5;           // 0..7
    const int bncol = (tid & 31) * 4;     // 0..124

    for (int k0 = 0; k0 < Kd; k0 += BK) {
        float4 av = *reinterpret_cast<const float4*>(
            &A[(size_t)(brow + arow) * Kd + k0 + akq]);
        if (ACT_IN) {
            av.x = hswish(av.x); av.y = hswish(av.y);
            av.z = hswish(av.z); av.w = hswish(av.w);
        }
        As[akq + 0][arow] = av.x;
        As[akq + 1][arow] = av.y;
        As[akq + 2][arow] = av.z;
        As[akq + 3][arow] = av.w;
        float4 bv = *reinterpret_cast<const float4*>(
            &Bm[(size_t)(k0 + bkrow) * Nd + bcol + bncol]);
        *reinterpret_cast<float4*>(&Bs[bkrow][bncol]) = bv;
        __syncthreads();
        #pragma unroll
        for (int k = 0; k < BK; ++k) {
            float a[TM], b[TN];
            #pragma unroll
            for (int i = 0; i < TM; ++i) a[i] = As[k][ty * TM + i];
            #pragma unroll
            for (int j = 0; j < TN; ++j) b[j] = Bs[k][tx * TN + j];
            #pragma unroll
            for (int i = 0; i < TM; ++i)
                #pragma unroll
                for (int j = 0; j < TN; ++j) acc[i][j] += a[i] * b[j];
        }
        __syncthreads();
    }

    float bj[TN];
    #pragma unroll
    for (int j = 0; j < TN; ++j) bj[j] = bias[bcol + tx * TN + j];
    #pragma unroll
    for (int i = 0; i < TM; ++i) {
        float* crow = &C[(size_t)(brow + ty * TM + i) * Nd + bcol + tx * TN];
        #pragma unroll
        for (int j = 0; j < TN; j += 4) {
            float4 o;
            o.x = acc[i][j + 0] + bj[j + 0];
            o.y = acc[i][j + 1] + bj[j + 1];
            o.z = acc[i][j + 2] + bj[j + 2];
            o.w = acc[i][j + 3] + bj[j + 3];
            *reinterpret_cast<float4*>(&crow[j]) = o;
        }
    }
}

// ---------------- depthwise 3x3 on hard_swish(v): A = v_conv ----------------
__global__ __launch_bounds__(256) void vconv_kernel(
    const float* __restrict__ qv, const float* __restrict__ pw,
    const float* __restrict__ pb, float* __restrict__ Abuf)
{
    int idx = blockIdx.x * 256 + threadIdx.x;   // B*N*256 = 2^23
    int c = idx & 255;
    int n = (idx >> 8) & (Nn - 1);
    int b = idx >> 20;
    int x = n & 63, y = n >> 6;
    float sum = pb[c];
    #pragma unroll
    for (int ky = 0; ky < 3; ++ky) {
        int yy = y + ky - 1;
        if (yy >= 0 && yy < Hh) {
            #pragma unroll
            for (int kx = 0; kx < 3; ++kx) {
                int xx = x + kx - 1;
                if (xx >= 0 && xx < Ww) {
                    float v = qv[(size_t)(b * Nn + yy * Ww + xx) * QKVC + 256 + c];
                    sum += hswish(v) * pw[c * 9 + ky * 3 + kx];
                }
            }
        }
    }
    Abuf[(size_t)(b * Nn + n) * DIMc + c] = sum;
}

// ---------------- conv-attention branch step 1: fc over raw-reshaped f ----------------
// Fbuf[b][s*9+o][n]  (n = y*W+x), replicates reshape(B,8,16,N) exactly.
__global__ __launch_bounds__(256) void fconv_fc_kernel(
    const float* __restrict__ qv, const float* __restrict__ fcw,
    float* __restrict__ Fbuf, int qoff)
{
    int idx = blockIdx.x * 256 + threadIdx.x;   // B*16*N = 2^19
    int n = idx & (Nn - 1);
    int s = (idx >> 12) & 15;
    int b = idx >> 16;
    int t = n >> 7, u = n & 127;
    float fq[8], fv[8];
    #pragma unroll
    for (int a = 0; a < 8; ++a) {
        int nq = (a * 16 + s) * 32 + t;
        size_t base = (size_t)(b * Nn + nq) * QKVC;
        fq[a] = qv[base + qoff + u];
        fv[a] = qv[base + 256 + qoff + u];
    }
    #pragma unroll
    for (int o = 0; o < 9; ++o) {
        float acc = 0.f;
        #pragma unroll
        for (int a = 0; a < 8; ++a) {
            acc += fcw[o * 24 + a] * fq[a]
                 + (fcw[o * 24 + 8 + a] + fcw[o * 24 + 16 + a]) * fv[a];
        }
        Fbuf[(size_t)(b * 144 + (s * 9 + o)) * Nn + n] = acc;
    }
}

// ---------------- conv-attention branch step 2: grouped 3x3 conv, accumulate ----------------
__global__ __launch_bounds__(256) void depconv_kernel(
    const float* __restrict__ Fbuf, const float* __restrict__ dw,
    const float* __restrict__ db, const float* __restrict__ rate2p,
    float* __restrict__ Abuf, int coff)
{
    int idx = blockIdx.x * 256 + threadIdx.x;   // B*N*128 = 2^22
    int oc = idx & 127;
    int n = (idx >> 7) & (Nn - 1);
    int b = idx >> 19;
    int x = n & 63, y = n >> 6;
    int gi = oc >> 3;
    float sum = db[oc];
    for (int ic = 0; ic < 9; ++ic) {
        const float* fch = &Fbuf[(size_t)(b * 144 + gi * 9 + ic) * Nn];
        const float* wr = &dw[(oc * 9 + ic) * 9];
        #pragma unroll
        for (int ky = 0; ky < 3; ++ky) {
            int yy = y + ky - 1;
            if (yy >= 0 && yy < Hh) {
                #pragma unroll
                for (int kx = 0; kx < 3; ++kx) {
                    int xx = x + kx - 1;
                    if (xx >= 0 && xx < Ww)
                        sum += wr[ky * 3 + kx] * fch[yy * 64 + xx];
                }
            }
        }
    }
    float* ap = &Abuf[(size_t)(b * Nn + n) * DIMc + coff + oc];
    *ap += rate2p[0] * sum;
}

// ---------------- cross-shaped window attention (k == v), flash-style ----------------
// 512 blocks: bid<256 horizontal, else vertical. One (b,g,h) tile per block.
__global__ __launch_bounds__(512) void attn_kernel(
    const float* __restrict__ qv, const float* __restrict__ rate1p,
    float* __restrict__ Abuf)
{
    int bid = blockIdx.x;
    bool hor = bid < 256;
    int lb = bid & 255;
    int h = lb & 3;
    int g = (lb >> 2) & 7;
    int b = lb >> 5;
    int half = hor ? 0 : 128;
    int qoff = half + h * 32;
    int kvoff = 256 + qoff;

    __shared__ float kv[512 * 32];   // 64 KB
    int tid = threadIdx.x;

    for (int i = tid; i < 512 * 8; i += 512) {
        int l = i >> 3, d4 = i & 7;
        int n = hor ? (g * 512 + l) : ((l & 63) * 64 + g * 8 + (l >> 6));
        float4 vv = *reinterpret_cast<const float4*>(
            &qv[(size_t)(b * Nn + n) * QKVC + kvoff + d4 * 4]);
        *reinterpret_cast<float4*>(&kv[l * 32 + d4 * 4]) = vv;
    }
    __syncthreads();

    int l = tid;
    int nq = hor ? (g * 512 + l) : ((l & 63) * 64 + g * 8 + (l >> 6));
    const float* qp = &qv[(size_t)(b * Nn + nq) * QKVC + qoff];
    float4 q4[8];
    #pragma unroll
    for (int d4 = 0; d4 < 8; ++d4)
        q4[d4] = *reinterpret_cast<const float4*>(&qp[d4 * 4]);

    float4 acc[8] = {};
    float lsum = 0.f;
    const float scale = 0.17677669529663687f;   // 32^-0.5
    const float M0 = 16.f;                      // fixed shift (exact: softmax shift-invariant)

    for (int k = 0; k < 512; ++k) {
        const float4* kp = reinterpret_cast<const float4*>(&kv[k * 32]);
        float4 kr[8];
        #pragma unroll
        for (int d4 = 0; d4 < 8; ++d4) kr[d4] = kp[d4];
        float s = 0.f;
        #pragma unroll
        for (int d4 = 0; d4 < 8; ++d4)
            s += q4[d4].x * kr[d4].x + q4[d4].y * kr[d4].y
               + q4[d4].z * kr[d4].z + q4[d4].w * kr[d4].w;
        float p = __expf(s * scale - M0);
        lsum += p;
        #pragma unroll
        for (int d4 = 0; d4 < 8; ++d4) {
            acc[d4].x += p * kr[d4].x;
            acc[d4].y += p * kr[d4].y;
            acc[d4].z += p * kr[d4].z;
            acc[d4].w += p * kr[d4].w;
        }
    }

    float inv = rate1p[0] / lsum;
    float* op = &Abuf[(size_t)(b * Nn + nq) * DIMc + qoff];
    #pragma unroll
    for (int d4 = 0; d4 < 8; ++d4) {
        float4 o4;
        o4.x = op[d4 * 4 + 0] + acc[d4].x * inv;
        o4.y = op[d4 * 4 + 1] + acc[d4].y * inv;
        o4.z = op[d4 * 4 + 2] + acc[d4].z * inv;
        o4.w = op[d4 * 4 + 3] + acc[d4].w * inv;
        *reinterpret_cast<float4*>(&op[d4 * 4]) = o4;
    }
}

// ---------------- BatchNorm stats (sum, sumsq per channel) ----------------
__global__ __launch_bounds__(256) void bnstats_kernel(
    const float* __restrict__ Y, float* __restrict__ stats)
{
    int c = threadIdx.x;
    int rows = Mrows / gridDim.x;
    int r0 = blockIdx.x * rows;
    float s = 0.f, s2 = 0.f;
    for (int r = r0; r < r0 + rows; ++r) {
        float v = Y[(size_t)r * DIMc + c];
        s += v; s2 += v * v;
    }
    atomicAdd(&stats[c], s);
    atomicAdd(&stats[256 + c], s2);
}

// ---------------- BatchNorm normalize ----------------
__global__ __launch_bounds__(256) void bnnorm_kernel(
    const float* __restrict__ Y, const float* __restrict__ stats,
    const float* __restrict__ g, const float* __restrict__ bta,
    float* __restrict__ out)
{
    int idx = blockIdx.x * 256 + threadIdx.x;
    int c = idx & 255;
    float mu = stats[c] * (1.f / (float)Mrows);
    float var = stats[256 + c] * (1.f / (float)Mrows) - mu * mu;
    float inv = rsqrtf(var + 1e-5f);
    out[idx] = (Y[idx] - mu) * inv * g[c] + bta[c];
}

// ---------------- launch ----------------
extern "C" void kernel_launch(void* const* d_in, const int* in_sizes, int n_in,
                              void* d_out, int out_size, void* d_ws, size_t ws_size,
                              hipStream_t stream)
{
    const float* x      = (const float*)d_in[0];
    const float* w_qkv  = (const float*)d_in[1];
    const float* b_qkv  = (const float*)d_in[2];
    const float* w_out  = (const float*)d_in[3];
    const float* b_out  = (const float*)d_in[4];
    const float* bn_g   = (const float*)d_in[5];
    const float* bn_b   = (const float*)d_in[6];
    const float* pconv_w = (const float*)d_in[7];
    const float* pconv_b = (const float*)d_in[8];
    const float* fc_w   = (const float*)d_in[9];
    const float* dep_w  = (const float*)d_in[10];
    const float* dep_b  = (const float*)d_in[11];
    const float* rate1  = (const float*)d_in[12];
    const float* rate2  = (const float*)d_in[13];
    float* out = (float*)d_out;

    char* ws = (char*)d_ws;
    float* qv    = (float*)(ws);                        // 32768*512*4 = 64 MB
    float* Abuf  = (float*)(ws + 67108864);             // 32768*256*4 = 32 MB
    float* Fbuf  = (float*)(ws + 100663296);            // 8*144*4096*4 = 18 MB
    float* Ybuf  = (float*)(ws + 100663296);            // aliases Fbuf (Fbuf dead by GEMM2)
    float* stats = (float*)(ws + 134217728);            // 512 floats

    // 1. qv = x @ w_qkv + b_qkv            [32768,256]@[256,512]
    sgemm_kernel<false><<<dim3(4, 256), 256, 0, stream>>>(
        x, w_qkv, b_qkv, qv, Mrows, 512, 256);

    // 2. A = depthwise3x3(hard_swish(v)) + pconv_b
    vconv_kernel<<<(Mrows * 256) / 256, 256, 0, stream>>>(qv, pconv_w, pconv_b, Abuf);

    // 3. conv-attention branch, horizontal then vertical (Fbuf reused)
    fconv_fc_kernel<<<(Bn * 16 * Nn) / 256, 256, 0, stream>>>(qv, fc_w, Fbuf, 0);
    depconv_kernel<<<(Bn * Nn * 128) / 256, 256, 0, stream>>>(
        Fbuf, dep_w, dep_b, rate2, Abuf, 0);
    fconv_fc_kernel<<<(Bn * 16 * Nn) / 256, 256, 0, stream>>>(qv, fc_w, Fbuf, 128);
    depconv_kernel<<<(Bn * Nn * 128) / 256, 256, 0, stream>>>(
        Fbuf, dep_w, dep_b, rate2, Abuf, 128);

    // 4. cross-shaped window attention, both branches (A += rate1 * o)
    attn_kernel<<<512, 512, 0, stream>>>(qv, rate1, Abuf);

    // 5. Y = hard_swish(A) @ w_out + b_out
    sgemm_kernel<true><<<dim3(2, 256), 256, 0, stream>>>(
        Abuf, w_out, b_out, Ybuf, Mrows, 256, 256);

    // 6. BatchNorm (training mode, biased var)
    hipMemsetAsync(stats, 0, 2 * 256 * sizeof(float), stream);
    bnstats_kernel<<<256, 256, 0, stream>>>(Ybuf, stats);
    bnnorm_kernel<<<(Mrows * 256) / 256, 256, 0, stream>>>(Ybuf, stats, bn_g, bn_b, out);
}

// Round 2
// 744.991 us; speedup vs baseline: 2.7477x; 2.7477x over previous
//
#include <hip/hip_runtime.h>
#include <math.h>

// ---------------- problem constants (fixed instance) ----------------
constexpr int Bn   = 8;
constexpr int Hh   = 64;
constexpr int Ww   = 64;
constexpr int Nn   = Hh * Ww;      // 4096
constexpr int Mrows = Bn * Nn;     // 32768
constexpr int QKVC = 512;          // qv channels
constexpr int DIMc = 256;

__device__ __forceinline__ float hswish(float x) {
    float r = fminf(fmaxf(x + 3.f, 0.f), 6.f);
    return x * r * (1.f / 6.f);
}

// ---------------- tiled SGEMM: C = act(A) @ B + bias ----------------
// BM=BN=128, BK=8, TM=TN=8, 256 threads
template<bool ACT_IN>
__global__ __launch_bounds__(256) void sgemm_kernel(
    const float* __restrict__ A, const float* __restrict__ Bm,
    const float* __restrict__ bias, float* __restrict__ C,
    int Md, int Nd, int Kd)
{
    constexpr int BM = 128, BN = 128, BK = 8, TM = 8, TN = 8;
    __shared__ float As[BK][BM + 4];
    __shared__ float Bs[BK][BN];
    const int tid = threadIdx.x;
    const int tx = tid & 15, ty = tid >> 4;
    const int brow = blockIdx.y * BM;
    const int bcol = blockIdx.x * BN;

    float acc[TM][TN] = {};

    const int arow = tid >> 1;            // 0..127
    const int akq  = (tid & 1) * 4;       // 0 or 4
    const int bkrow = tid >> 5;           // 0..7
    const int bncol = (tid & 31) * 4;     // 0..124

    for (int k0 = 0; k0 < Kd; k0 += BK) {
        float4 av = *reinterpret_cast<const float4*>(
            &A[(size_t)(brow + arow) * Kd + k0 + akq]);
        if (ACT_IN) {
            av.x = hswish(av.x); av.y = hswish(av.y);
            av.z = hswish(av.z); av.w = hswish(av.w);
        }
        As[akq + 0][arow] = av.x;
        As[akq + 1][arow] = av.y;
        As[akq + 2][arow] = av.z;
        As[akq + 3][arow] = av.w;
        float4 bv = *reinterpret_cast<const float4*>(
            &Bm[(size_t)(k0 + bkrow) * Nd + bcol + bncol]);
        *reinterpret_cast<float4*>(&Bs[bkrow][bncol]) = bv;
        __syncthreads();
        #pragma unroll
        for (int k = 0; k < BK; ++k) {
            float a[TM], b[TN];
            #pragma unroll
            for (int i = 0; i < TM; ++i) a[i] = As[k][ty * TM + i];
            #pragma unroll
            for (int j = 0; j < TN; ++j) b[j] = Bs[k][tx * TN + j];
            #pragma unroll
            for (int i = 0; i < TM; ++i)
                #pragma unroll
                for (int j = 0; j < TN; ++j) acc[i][j] += a[i] * b[j];
        }
        __syncthreads();
    }

    float bj[TN];
    #pragma unroll
    for (int j = 0; j < TN; ++j) bj[j] = bias[bcol + tx * TN + j];
    #pragma unroll
    for (int i = 0; i < TM; ++i) {
        float* crow = &C[(size_t)(brow + ty * TM + i) * Nd + bcol + tx * TN];
        #pragma unroll
        for (int j = 0; j < TN; j += 4) {
            float4 o;
            o.x = acc[i][j + 0] + bj[j + 0];
            o.y = acc[i][j + 1] + bj[j + 1];
            o.z = acc[i][j + 2] + bj[j + 2];
            o.w = acc[i][j + 3] + bj[j + 3];
            *reinterpret_cast<float4*>(&crow[j]) = o;
        }
    }
}

// ---------------- depthwise 3x3 on hard_swish(v): A = v_conv ----------------
__global__ __launch_bounds__(256) void vconv_kernel(
    const float* __restrict__ qv, const float* __restrict__ pw,
    const float* __restrict__ pb, float* __restrict__ Abuf)
{
    int idx = blockIdx.x * 256 + threadIdx.x;   // B*N*256 = 2^23
    int c = idx & 255;
    int n = (idx >> 8) & (Nn - 1);
    int b = idx >> 20;
    int x = n & 63, y = n >> 6;
    float sum = pb[c];
    #pragma unroll
    for (int ky = 0; ky < 3; ++ky) {
        int yy = y + ky - 1;
        if (yy >= 0 && yy < Hh) {
            #pragma unroll
            for (int kx = 0; kx < 3; ++kx) {
                int xx = x + kx - 1;
                if (xx >= 0 && xx < Ww) {
                    float v = qv[(size_t)(b * Nn + yy * Ww + xx) * QKVC + 256 + c];
                    sum += hswish(v) * pw[c * 9 + ky * 3 + kx];
                }
            }
        }
    }
    Abuf[(size_t)(b * Nn + n) * DIMc + c] = sum;
}

// ---------------- conv-attention branch step 1: fc over raw-reshaped f ----------------
// Fbuf[b][s*9+o][n]  (n = y*W+x), replicates reshape(B,8,16,N) exactly.
__global__ __launch_bounds__(256) void fconv_fc_kernel(
    const float* __restrict__ qv, const float* __restrict__ fcw,
    float* __restrict__ Fbuf, int qoff)
{
    int idx = blockIdx.x * 256 + threadIdx.x;   // B*16*N = 2^19
    int n = idx & (Nn - 1);
    int s = (idx >> 12) & 15;
    int b = idx >> 16;
    int t = n >> 7, u = n & 127;
    float fq[8], fv[8];
    #pragma unroll
    for (int a = 0; a < 8; ++a) {
        int nq = (a * 16 + s) * 32 + t;
        size_t base = (size_t)(b * Nn + nq) * QKVC;
        fq[a] = qv[base + qoff + u];
        fv[a] = qv[base + 256 + qoff + u];
    }
    #pragma unroll
    for (int o = 0; o < 9; ++o) {
        float acc = 0.f;
        #pragma unroll
        for (int a = 0; a < 8; ++a) {
            acc += fcw[o * 24 + a] * fq[a]
                 + (fcw[o * 24 + 8 + a] + fcw[o * 24 + 16 + a]) * fv[a];
        }
        Fbuf[(size_t)(b * 144 + (s * 9 + o)) * Nn + n] = acc;
    }
}

// ---------------- conv-attention branch step 2: grouped 3x3 conv (LDS-tiled) ----------------
// block = (b, gi, ytile): stages 9 planes x 18 rows x (64+2 halo) in LDS,
// computes 8 output channels x 16 rows x 64 cols, accumulates into Abuf.
__global__ __launch_bounds__(256) void depconv_kernel(
    const float* __restrict__ Fbuf, const float* __restrict__ dw,
    const float* __restrict__ db, const float* __restrict__ rate2p,
    float* __restrict__ Abuf, int coff)
{
    int blk = blockIdx.x;              // 8*16*4 = 512
    int ytile = blk & 3;
    int gi = (blk >> 2) & 15;
    int b = blk >> 6;
    int y0 = ytile * 16;

    __shared__ float sp[9][18][66];    // [ic][row(y0-1..y0+16)][x+1], halo cols 0,65
    __shared__ float wt[8][81];        // [ocl][ic*9 + ky*3 + kx]
    const int tid = threadIdx.x;

    // stage planes (coalesced rows), zero for out-of-range rows
    for (int i = tid; i < 9 * 18 * 64; i += 256) {
        int xx = i & 63;
        int r  = (i >> 6) % 18;
        int ic = (i >> 6) / 18;
        int yy = y0 + r - 1;
        float v = 0.f;
        if (yy >= 0 && yy < Hh)
            v = Fbuf[(size_t)(b * 144 + gi * 9 + ic) * Nn + yy * 64 + xx];
        sp[ic][r][xx + 1] = v;
    }
    // halo columns
    for (int i = tid; i < 9 * 18; i += 256) {
        int r = i % 18, ic = i / 18;
        sp[ic][r][0] = 0.f;
        sp[ic][r][65] = 0.f;
    }
    // weights
    for (int i = tid; i < 8 * 81; i += 256) {
        int ocl = i / 81, t = i % 81;
        wt[ocl][t] = dw[(gi * 8 + ocl) * 81 + t];
    }
    __syncthreads();

    const int x = tid & 63;
    const int quad = tid >> 6;         // 0..3 -> rows quad*4 .. quad*4+3
    const int ylb = quad * 4;

    float acc[8][4] = {};
    #pragma unroll
    for (int ic = 0; ic < 9; ++ic) {
        float rv[6][3];
        #pragma unroll
        for (int r = 0; r < 6; ++r) {
            rv[r][0] = sp[ic][ylb + r][x];
            rv[r][1] = sp[ic][ylb + r][x + 1];
            rv[r][2] = sp[ic][ylb + r][x + 2];
        }
        #pragma unroll
        for (int ocl = 0; ocl < 8; ++ocl) {
            #pragma unroll
            for (int ky = 0; ky < 3; ++ky) {
                #pragma unroll
                for (int kx = 0; kx < 3; ++kx) {
                    float w = wt[ocl][ic * 9 + ky * 3 + kx];
                    #pragma unroll
                    for (int yl = 0; yl < 4; ++yl)
                        acc[ocl][yl] += w * rv[yl + ky][kx];
                }
            }
        }
    }

    const float r2 = rate2p[0];
    float dbv[8];
    #pragma unroll
    for (int ocl = 0; ocl < 8; ++ocl) dbv[ocl] = db[gi * 8 + ocl];

    #pragma unroll
    for (int yl = 0; yl < 4; ++yl) {
        int n = (y0 + ylb + yl) * 64 + x;
        float* ap = &Abuf[(size_t)(b * Nn + n) * DIMc + coff + gi * 8];
        float4 o0 = *reinterpret_cast<float4*>(&ap[0]);
        float4 o1 = *reinterpret_cast<float4*>(&ap[4]);
        o0.x += r2 * (acc[0][yl] + dbv[0]);
        o0.y += r2 * (acc[1][yl] + dbv[1]);
        o0.z += r2 * (acc[2][yl] + dbv[2]);
        o0.w += r2 * (acc[3][yl] + dbv[3]);
        o1.x += r2 * (acc[4][yl] + dbv[4]);
        o1.y += r2 * (acc[5][yl] + dbv[5]);
        o1.z += r2 * (acc[6][yl] + dbv[6]);
        o1.w += r2 * (acc[7][yl] + dbv[7]);
        *reinterpret_cast<float4*>(&ap[0]) = o0;
        *reinterpret_cast<float4*>(&ap[4]) = o1;
    }
}

// ---------------- cross-shaped window attention (k == v), flash-style ----------------
// 512 blocks: bid<256 horizontal, else vertical. One (b,g,h) tile per block.
__global__ __launch_bounds__(512) void attn_kernel(
    const float* __restrict__ qv, const float* __restrict__ rate1p,
    float* __restrict__ Abuf)
{
    int bid = blockIdx.x;
    bool hor = bid < 256;
    int lb = bid & 255;
    int h = lb & 3;
    int g = (lb >> 2) & 7;
    int b = lb >> 5;
    int half = hor ? 0 : 128;
    int qoff = half + h * 32;
    int kvoff = 256 + qoff;

    __shared__ float kv[512 * 32];   // 64 KB
    int tid = threadIdx.x;

    for (int i = tid; i < 512 * 8; i += 512) {
        int l = i >> 3, d4 = i & 7;
        int n = hor ? (g * 512 + l) : ((l & 63) * 64 + g * 8 + (l >> 6));
        float4 vv = *reinterpret_cast<const float4*>(
            &qv[(size_t)(b * Nn + n) * QKVC + kvoff + d4 * 4]);
        *reinterpret_cast<float4*>(&kv[l * 32 + d4 * 4]) = vv;
    }
    __syncthreads();

    int l = tid;
    int nq = hor ? (g * 512 + l) : ((l & 63) * 64 + g * 8 + (l >> 6));
    const float* qp = &qv[(size_t)(b * Nn + nq) * QKVC + qoff];
    float4 q4[8];
    #pragma unroll
    for (int d4 = 0; d4 < 8; ++d4)
        q4[d4] = *reinterpret_cast<const float4*>(&qp[d4 * 4]);

    float4 acc[8] = {};
    float lsum = 0.f;
    const float scale = 0.17677669529663687f;   // 32^-0.5
    const float M0 = 16.f;                      // fixed shift (exact: softmax shift-invariant)

    for (int k = 0; k < 512; ++k) {
        const float4* kp = reinterpret_cast<const float4*>(&kv[k * 32]);
        float4 kr[8];
        #pragma unroll
        for (int d4 = 0; d4 < 8; ++d4) kr[d4] = kp[d4];
        float s = 0.f;
        #pragma unroll
        for (int d4 = 0; d4 < 8; ++d4)
            s += q4[d4].x * kr[d4].x + q4[d4].y * kr[d4].y
               + q4[d4].z * kr[d4].z + q4[d4].w * kr[d4].w;
        float p = __expf(s * scale - M0);
        lsum += p;
        #pragma unroll
        for (int d4 = 0; d4 < 8; ++d4) {
            acc[d4].x += p * kr[d4].x;
            acc[d4].y += p * kr[d4].y;
            acc[d4].z += p * kr[d4].z;
            acc[d4].w += p * kr[d4].w;
        }
    }

    float inv = rate1p[0] / lsum;
    float* op = &Abuf[(size_t)(b * Nn + nq) * DIMc + qoff];
    #pragma unroll
    for (int d4 = 0; d4 < 8; ++d4) {
        float4 o4;
        o4.x = op[d4 * 4 + 0] + acc[d4].x * inv;
        o4.y = op[d4 * 4 + 1] + acc[d4].y * inv;
        o4.z = op[d4 * 4 + 2] + acc[d4].z * inv;
        o4.w = op[d4 * 4 + 3] + acc[d4].w * inv;
        *reinterpret_cast<float4*>(&op[d4 * 4]) = o4;
    }
}

// ---------------- BatchNorm stats (sum, sumsq per channel) ----------------
__global__ __launch_bounds__(256) void bnstats_kernel(
    const float* __restrict__ Y, float* __restrict__ stats)
{
    int c = threadIdx.x;
    int rows = Mrows / gridDim.x;
    int r0 = blockIdx.x * rows;
    float s = 0.f, s2 = 0.f;
    for (int r = r0; r < r0 + rows; ++r) {
        float v = Y[(size_t)r * DIMc + c];
        s += v; s2 += v * v;
    }
    atomicAdd(&stats[c], s);
    atomicAdd(&stats[256 + c], s2);
}

// ---------------- BatchNorm normalize ----------------
__global__ __launch_bounds__(256) void bnnorm_kernel(
    const float* __restrict__ Y, const float* __restrict__ stats,
    const float* __restrict__ g, const float* __restrict__ bta,
    float* __restrict__ out)
{
    int idx = blockIdx.x * 256 + threadIdx.x;
    int c = idx & 255;
    float mu = stats[c] * (1.f / (float)Mrows);
    float var = stats[256 + c] * (1.f / (float)Mrows) - mu * mu;
    float inv = rsqrtf(var + 1e-5f);
    out[idx] = (Y[idx] - mu) * inv * g[c] + bta[c];
}

// ---------------- launch ----------------
extern "C" void kernel_launch(void* const* d_in, const int* in_sizes, int n_in,
                              void* d_out, int out_size, void* d_ws, size_t ws_size,
                              hipStream_t stream)
{
    const float* x      = (const float*)d_in[0];
    const float* w_qkv  = (const float*)d_in[1];
    const float* b_qkv  = (const float*)d_in[2];
    const float* w_out  = (const float*)d_in[3];
    const float* b_out  = (const float*)d_in[4];
    const float* bn_g   = (const float*)d_in[5];
    const float* bn_b   = (const float*)d_in[6];
    const float* pconv_w = (const float*)d_in[7];
    const float* pconv_b = (const float*)d_in[8];
    const float* fc_w   = (const float*)d_in[9];
    const float* dep_w  = (const float*)d_in[10];
    const float* dep_b  = (const float*)d_in[11];
    const float* rate1  = (const float*)d_in[12];
    const float* rate2  = (const float*)d_in[13];
    float* out = (float*)d_out;

    char* ws = (char*)d_ws;
    float* qv    = (float*)(ws);                        // 32768*512*4 = 64 MB
    float* Abuf  = (float*)(ws + 67108864);             // 32768*256*4 = 32 MB
    float* Fbuf  = (float*)(ws + 100663296);            // 8*144*4096*4 = 18 MB
    float* Ybuf  = (float*)(ws + 100663296);            // aliases Fbuf (Fbuf dead by GEMM2)
    float* stats = (float*)(ws + 134217728);            // 512 floats

    // 1. qv = x @ w_qkv + b_qkv            [32768,256]@[256,512]
    sgemm_kernel<false><<<dim3(4, 256), 256, 0, stream>>>(
        x, w_qkv, b_qkv, qv, Mrows, 512, 256);

    // 2. A = depthwise3x3(hard_swish(v)) + pconv_b
    vconv_kernel<<<(Mrows * 256) / 256, 256, 0, stream>>>(qv, pconv_w, pconv_b, Abuf);

    // 3. conv-attention branch, horizontal then vertical (Fbuf reused)
    fconv_fc_kernel<<<(Bn * 16 * Nn) / 256, 256, 0, stream>>>(qv, fc_w, Fbuf, 0);
    depconv_kernel<<<512, 256, 0, stream>>>(Fbuf, dep_w, dep_b, rate2, Abuf, 0);
    fconv_fc_kernel<<<(Bn * 16 * Nn) / 256, 256, 0, stream>>>(qv, fc_w, Fbuf, 128);
    depconv_kernel<<<512, 256, 0, stream>>>(Fbuf, dep_w, dep_b, rate2, Abuf, 128);

    // 4. cross-shaped window attention, both branches (A += rate1 * o)
    attn_kernel<<<512, 512, 0, stream>>>(qv, rate1, Abuf);

    // 5. Y = hard_swish(A) @ w_out + b_out
    sgemm_kernel<true><<<dim3(2, 256), 256, 0, stream>>>(
        Abuf, w_out, b_out, Ybuf, Mrows, 256, 256);

    // 6. BatchNorm (training mode, biased var)
    hipMemsetAsync(stats, 0, 2 * 256 * sizeof(float), stream);
    bnstats_kernel<<<256, 256, 0, stream>>>(Ybuf, stats);
    bnnorm_kernel<<<(Mrows * 256) / 256, 256, 0, stream>>>(Ybuf, stats, bn_g, bn_b, out);
}

// Round 3
// 458.382 us; speedup vs baseline: 4.4658x; 1.6253x over previous
//
#include <hip/hip_runtime.h>
#include <hip/hip_bf16.h>
#include <math.h>

// ---------------- problem constants (fixed instance) ----------------
constexpr int Bn   = 8;
constexpr int Hh   = 64;
constexpr int Ww   = 64;
constexpr int Nn   = Hh * Ww;      // 4096
constexpr int Mrows = Bn * Nn;     // 32768
constexpr int QKVC = 512;          // qv channels
constexpr int DIMc = 256;

typedef short short8 __attribute__((ext_vector_type(8)));
typedef float f32x16 __attribute__((ext_vector_type(16)));

__device__ __forceinline__ float hswish(float x) {
    float r = fminf(fmaxf(x + 3.f, 0.f), 6.f);
    return x * r * (1.f / 6.f);
}

__device__ __forceinline__ uint32_t pkbf(float a, float b) {
    __hip_bfloat16 x = __float2bfloat16(a), y = __float2bfloat16(b);
    return (uint32_t)__bfloat16_as_ushort(x) | ((uint32_t)__bfloat16_as_ushort(y) << 16);
}

#if __has_builtin(__builtin_amdgcn_permlane32_swap)
typedef int int2v __attribute__((ext_vector_type(2)));
__device__ __forceinline__ void plswap(uint32_t& a, uint32_t& b) {
    int2v r = __builtin_amdgcn_permlane32_swap((int)a, (int)b, false, false);
    a = (uint32_t)r.x; b = (uint32_t)r.y;
}
#else
__device__ __forceinline__ void plswap(uint32_t& a, uint32_t& b) {
    int l = threadIdx.x & 63;
    uint32_t sa = (uint32_t)__shfl_xor((int)a, 32);
    uint32_t sb = (uint32_t)__shfl_xor((int)b, 32);
    uint32_t na = (l < 32) ? a : sb;
    uint32_t nb = (l < 32) ? sa : b;
    a = na; b = nb;
}
#endif

// ---------------- tiled SGEMM: C = act(A) @ B + bias ----------------
template<bool ACT_IN>
__global__ __launch_bounds__(256) void sgemm_kernel(
    const float* __restrict__ A, const float* __restrict__ Bm,
    const float* __restrict__ bias, float* __restrict__ C,
    int Md, int Nd, int Kd)
{
    constexpr int BM = 128, BN = 128, BK = 8, TM = 8, TN = 8;
    __shared__ float As[BK][BM + 4];
    __shared__ float Bs[BK][BN];
    const int tid = threadIdx.x;
    const int tx = tid & 15, ty = tid >> 4;
    const int brow = blockIdx.y * BM;
    const int bcol = blockIdx.x * BN;

    float acc[TM][TN] = {};

    const int arow = tid >> 1;
    const int akq  = (tid & 1) * 4;
    const int bkrow = tid >> 5;
    const int bncol = (tid & 31) * 4;

    for (int k0 = 0; k0 < Kd; k0 += BK) {
        float4 av = *reinterpret_cast<const float4*>(
            &A[(size_t)(brow + arow) * Kd + k0 + akq]);
        if (ACT_IN) {
            av.x = hswish(av.x); av.y = hswish(av.y);
            av.z = hswish(av.z); av.w = hswish(av.w);
        }
        As[akq + 0][arow] = av.x;
        As[akq + 1][arow] = av.y;
        As[akq + 2][arow] = av.z;
        As[akq + 3][arow] = av.w;
        float4 bv = *reinterpret_cast<const float4*>(
            &Bm[(size_t)(k0 + bkrow) * Nd + bcol + bncol]);
        *reinterpret_cast<float4*>(&Bs[bkrow][bncol]) = bv;
        __syncthreads();
        #pragma unroll
        for (int k = 0; k < BK; ++k) {
            float a[TM], b[TN];
            #pragma unroll
            for (int i = 0; i < TM; ++i) a[i] = As[k][ty * TM + i];
            #pragma unroll
            for (int j = 0; j < TN; ++j) b[j] = Bs[k][tx * TN + j];
            #pragma unroll
            for (int i = 0; i < TM; ++i)
                #pragma unroll
                for (int j = 0; j < TN; ++j) acc[i][j] += a[i] * b[j];
        }
        __syncthreads();
    }

    float bj[TN];
    #pragma unroll
    for (int j = 0; j < TN; ++j) bj[j] = bias[bcol + tx * TN + j];
    #pragma unroll
    for (int i = 0; i < TM; ++i) {
        float* crow = &C[(size_t)(brow + ty * TM + i) * Nd + bcol + tx * TN];
        #pragma unroll
        for (int j = 0; j < TN; j += 4) {
            float4 o;
            o.x = acc[i][j + 0] + bj[j + 0];
            o.y = acc[i][j + 1] + bj[j + 1];
            o.z = acc[i][j + 2] + bj[j + 2];
            o.w = acc[i][j + 3] + bj[j + 3];
            *reinterpret_cast<float4*>(&crow[j]) = o;
        }
    }
}

// ---------------- depthwise 3x3 on hard_swish(v): A = v_conv ----------------
__global__ __launch_bounds__(256) void vconv_kernel(
    const float* __restrict__ qv, const float* __restrict__ pw,
    const float* __restrict__ pb, float* __restrict__ Abuf)
{
    int idx = blockIdx.x * 256 + threadIdx.x;
    int c = idx & 255;
    int n = (idx >> 8) & (Nn - 1);
    int b = idx >> 20;
    int x = n & 63, y = n >> 6;
    float sum = pb[c];
    #pragma unroll
    for (int ky = 0; ky < 3; ++ky) {
        int yy = y + ky - 1;
        if (yy >= 0 && yy < Hh) {
            #pragma unroll
            for (int kx = 0; kx < 3; ++kx) {
                int xx = x + kx - 1;
                if (xx >= 0 && xx < Ww) {
                    float v = qv[(size_t)(b * Nn + yy * Ww + xx) * QKVC + 256 + c];
                    sum += hswish(v) * pw[c * 9 + ky * 3 + kx];
                }
            }
        }
    }
    Abuf[(size_t)(b * Nn + n) * DIMc + c] = sum;
}

// ---------------- conv-attention branch step 1: fc over raw-reshaped f ----------------
__global__ __launch_bounds__(256) void fconv_fc_kernel(
    const float* __restrict__ qv, const float* __restrict__ fcw,
    float* __restrict__ Fbuf, int qoff)
{
    int idx = blockIdx.x * 256 + threadIdx.x;
    int n = idx & (Nn - 1);
    int s = (idx >> 12) & 15;
    int b = idx >> 16;
    int t = n >> 7, u = n & 127;
    float fq[8], fv[8];
    #pragma unroll
    for (int a = 0; a < 8; ++a) {
        int nq = (a * 16 + s) * 32 + t;
        size_t base = (size_t)(b * Nn + nq) * QKVC;
        fq[a] = qv[base + qoff + u];
        fv[a] = qv[base + 256 + qoff + u];
    }
    #pragma unroll
    for (int o = 0; o < 9; ++o) {
        float acc = 0.f;
        #pragma unroll
        for (int a = 0; a < 8; ++a) {
            acc += fcw[o * 24 + a] * fq[a]
                 + (fcw[o * 24 + 8 + a] + fcw[o * 24 + 16 + a]) * fv[a];
        }
        Fbuf[(size_t)(b * 144 + (s * 9 + o)) * Nn + n] = acc;
    }
}

// ---------------- conv-attention branch step 2: grouped 3x3 conv (LDS-tiled) ----------------
__global__ __launch_bounds__(256) void depconv_kernel(
    const float* __restrict__ Fbuf, const float* __restrict__ dw,
    const float* __restrict__ db, const float* __restrict__ rate2p,
    float* __restrict__ Abuf, int coff)
{
    int blk = blockIdx.x;
    int ytile = blk & 3;
    int gi = (blk >> 2) & 15;
    int b = blk >> 6;
    int y0 = ytile * 16;

    __shared__ float sp[9][18][66];
    __shared__ float wt[8][81];
    const int tid = threadIdx.x;

    for (int i = tid; i < 9 * 18 * 64; i += 256) {
        int xx = i & 63;
        int r  = (i >> 6) % 18;
        int ic = (i >> 6) / 18;
        int yy = y0 + r - 1;
        float v = 0.f;
        if (yy >= 0 && yy < Hh)
            v = Fbuf[(size_t)(b * 144 + gi * 9 + ic) * Nn + yy * 64 + xx];
        sp[ic][r][xx + 1] = v;
    }
    for (int i = tid; i < 9 * 18; i += 256) {
        int r = i % 18, ic = i / 18;
        sp[ic][r][0] = 0.f;
        sp[ic][r][65] = 0.f;
    }
    for (int i = tid; i < 8 * 81; i += 256) {
        int ocl = i / 81, t = i % 81;
        wt[ocl][t] = dw[(gi * 8 + ocl) * 81 + t];
    }
    __syncthreads();

    const int x = tid & 63;
    const int quad = tid >> 6;
    const int ylb = quad * 4;

    float acc[8][4] = {};
    #pragma unroll
    for (int ic = 0; ic < 9; ++ic) {
        float rv[6][3];
        #pragma unroll
        for (int r = 0; r < 6; ++r) {
            rv[r][0] = sp[ic][ylb + r][x];
            rv[r][1] = sp[ic][ylb + r][x + 1];
            rv[r][2] = sp[ic][ylb + r][x + 2];
        }
        #pragma unroll
        for (int ocl = 0; ocl < 8; ++ocl) {
            #pragma unroll
            for (int ky = 0; ky < 3; ++ky) {
                #pragma unroll
                for (int kx = 0; kx < 3; ++kx) {
                    float w = wt[ocl][ic * 9 + ky * 3 + kx];
                    #pragma unroll
                    for (int yl = 0; yl < 4; ++yl)
                        acc[ocl][yl] += w * rv[yl + ky][kx];
                }
            }
        }
    }

    const float r2 = rate2p[0];
    float dbv[8];
    #pragma unroll
    for (int ocl = 0; ocl < 8; ++ocl) dbv[ocl] = db[gi * 8 + ocl];

    #pragma unroll
    for (int yl = 0; yl < 4; ++yl) {
        int n = (y0 + ylb + yl) * 64 + x;
        float* ap = &Abuf[(size_t)(b * Nn + n) * DIMc + coff + gi * 8];
        float4 o0 = *reinterpret_cast<float4*>(&ap[0]);
        float4 o1 = *reinterpret_cast<float4*>(&ap[4]);
        o0.x += r2 * (acc[0][yl] + dbv[0]);
        o0.y += r2 * (acc[1][yl] + dbv[1]);
        o0.z += r2 * (acc[2][yl] + dbv[2]);
        o0.w += r2 * (acc[3][yl] + dbv[3]);
        o1.x += r2 * (acc[4][yl] + dbv[4]);
        o1.y += r2 * (acc[5][yl] + dbv[5]);
        o1.z += r2 * (acc[6][yl] + dbv[6]);
        o1.w += r2 * (acc[7][yl] + dbv[7]);
        *reinterpret_cast<float4*>(&ap[0]) = o0;
        *reinterpret_cast<float4*>(&ap[4]) = o1;
    }
}

// ---------------- MFMA cross-shaped window attention (k == v) ----------------
// One (b, g, head) window per block; 8 waves x 2 q-tiles of 32 rows.
// S^T = K.Q^T via mfma_32x32x16 (C: col=q=lane&31, row=k=(r&3)+8(r>>2)+4(lane>>5)).
// P^T B-operand for PV rebuilt in-register via cvt_pk + permlane32_swap (T12).
// K LDS: (k,d) at byte k*64 + ((((d>>3)) ^ (k&3))<<4) + (d&7)*2  (granule XOR swizzle)
// VT LDS: (d,k) at byte 32768 + d*1024 + ((k*2) ^ ((d&7)<<4))
__global__ __launch_bounds__(512) void attn_mfma_kernel(
    const float* __restrict__ qv, const float* __restrict__ rate1p,
    float* __restrict__ Abuf)
{
    int bid = blockIdx.x;
    bool hor = bid < 256;
    int lb = bid & 255;
    int hd = lb & 3;
    int g = (lb >> 2) & 7;
    int b = lb >> 5;
    int half = hor ? 0 : 128;
    int qoff = half + hd * 32;
    int kvoff = 256 + qoff;

    __shared__ __align__(16) char smem[65536];
    char* ldsK  = smem;            // 32 KB
    char* ldsVT = smem + 32768;    // 32 KB

    const int tid = threadIdx.x;
    const float QS = 0.17677669529663687f * 1.44269504088896f;  // scale * log2(e)

    // ---- stage K rows + V^T (k == v) ----
    {
        int l = tid;   // token 0..511
        int n = hor ? (g * 512 + l) : ((l & 63) * 64 + g * 8 + (l >> 6));
        const float* kp = &qv[(size_t)(b * Nn + n) * QKVC + kvoff];
        float row[32];
        #pragma unroll
        for (int q4 = 0; q4 < 8; ++q4) {
            float4 v = *reinterpret_cast<const float4*>(&kp[q4 * 4]);
            row[q4 * 4 + 0] = v.x; row[q4 * 4 + 1] = v.y;
            row[q4 * 4 + 2] = v.z; row[q4 * 4 + 3] = v.w;
        }
        uint32_t p32[16];
        ushort us[32];
        #pragma unroll
        for (int d = 0; d < 32; ++d)
            us[d] = __bfloat16_as_ushort(__float2bfloat16(row[d]));
        #pragma unroll
        for (int i = 0; i < 16; ++i)
            p32[i] = (uint32_t)us[2 * i] | ((uint32_t)us[2 * i + 1] << 16);
        #pragma unroll
        for (int gi = 0; gi < 4; ++gi) {
            uint4 w;
            w.x = p32[gi * 4 + 0]; w.y = p32[gi * 4 + 1];
            w.z = p32[gi * 4 + 2]; w.w = p32[gi * 4 + 3];
            *reinterpret_cast<uint4*>(ldsK + l * 64 + ((gi ^ (l & 3)) << 4)) = w;
        }
        #pragma unroll
        for (int d = 0; d < 32; ++d)
            *reinterpret_cast<ushort*>(ldsVT + d * 1024 + ((l * 2) ^ ((d & 7) << 4))) = us[d];
    }
    __syncthreads();

    const int w = tid >> 6;
    const int lane = tid & 63;
    const int qcol = lane & 31;
    const int hh = lane >> 5;      // 0/1 half of wave
    const float r1 = rate1p[0];

    #pragma unroll 1
    for (int qt = 0; qt < 2; ++qt) {
        const int q0 = (w * 2 + qt) * 32;
        const int qrow = q0 + qcol;
        const int nq = hor ? (g * 512 + qrow) : ((qrow & 63) * 64 + g * 8 + (qrow >> 6));

        // Q B-frags (pre-scaled by QS): t=0 -> d 0..15, t=1 -> d 16..31
        short8 qb[2];
        #pragma unroll
        for (int t = 0; t < 2; ++t) {
            const float* qp = &qv[(size_t)(b * Nn + nq) * QKVC + qoff + t * 16 + hh * 8];
            float4 f0 = *reinterpret_cast<const float4*>(&qp[0]);
            float4 f1 = *reinterpret_cast<const float4*>(&qp[4]);
            union { uint32_t u[4]; short8 s; } qa;
            qa.u[0] = pkbf(f0.x * QS, f0.y * QS);
            qa.u[1] = pkbf(f0.z * QS, f0.w * QS);
            qa.u[2] = pkbf(f1.x * QS, f1.y * QS);
            qa.u[3] = pkbf(f1.z * QS, f1.w * QS);
            qb[t] = qa.s;
        }

        f32x16 acc = {0,0,0,0,0,0,0,0,0,0,0,0,0,0,0,0};
        float rs = 0.f;

        for (int s = 0; s < 16; ++s) {
            const int k0 = s * 32;
            const int kr = k0 + qcol;
            const short8 a0 = *reinterpret_cast<const short8*>(
                ldsK + kr * 64 + (((0 + hh) ^ (kr & 3)) << 4));
            const short8 a1 = *reinterpret_cast<const short8*>(
                ldsK + kr * 64 + (((2 + hh) ^ (kr & 3)) << 4));
            f32x16 st = {0,0,0,0,0,0,0,0,0,0,0,0,0,0,0,0};
            st = __builtin_amdgcn_mfma_f32_32x32x16_bf16(a0, qb[0], st, 0, 0, 0);
            st = __builtin_amdgcn_mfma_f32_32x32x16_bf16(a1, qb[1], st, 0, 0, 0);

            float p[16];
            #pragma unroll
            for (int r = 0; r < 16; ++r) p[r] = exp2f(st[r]);
            float s01 = (p[0] + p[1]) + (p[2] + p[3]);
            float s23 = (p[4] + p[5]) + (p[6] + p[7]);
            float s45 = (p[8] + p[9]) + (p[10] + p[11]);
            float s67 = (p[12] + p[13]) + (p[14] + p[15]);
            rs += (s01 + s23) + (s45 + s67);

            uint32_t X[8];
            #pragma unroll
            for (int gg = 0; gg < 4; ++gg) {
                X[2 * gg + 0] = pkbf(p[4 * gg + 0], p[4 * gg + 1]);
                X[2 * gg + 1] = pkbf(p[4 * gg + 2], p[4 * gg + 3]);
            }
            #pragma unroll
            for (int u = 0; u < 2; ++u) {
                uint32_t w0 = X[4 * u + 0], w2 = X[4 * u + 2];
                uint32_t w1 = X[4 * u + 1], w3 = X[4 * u + 3];
                plswap(w0, w2);
                plswap(w1, w3);
                union { uint32_t u4[4]; short8 s; } pf;
                pf.u4[0] = w0; pf.u4[1] = w1; pf.u4[2] = w2; pf.u4[3] = w3;
                const int d = qcol;
                const short8 vf = *reinterpret_cast<const short8*>(
                    ldsVT + d * 1024 + ((k0 * 2 + u * 32 + hh * 16) ^ ((d & 7) << 4)));
                acc = __builtin_amdgcn_mfma_f32_32x32x16_bf16(vf, pf.s, acc, 0, 0, 0);
            }
        }

        float rsf = rs + __shfl_xor(rs, 32);
        float scl = r1 / rsf;
        float* ap = &Abuf[(size_t)(b * Nn + nq) * DIMc + qoff];
        #pragma unroll
        for (int gg = 0; gg < 4; ++gg) {
            int d0 = 8 * gg + 4 * hh;
            float4 o = *reinterpret_cast<float4*>(&ap[d0]);
            o.x += acc[4 * gg + 0] * scl;
            o.y += acc[4 * gg + 1] * scl;
            o.z += acc[4 * gg + 2] * scl;
            o.w += acc[4 * gg + 3] * scl;
            *reinterpret_cast<float4*>(&ap[d0]) = o;
        }
    }
}

// ---------------- BatchNorm stats (sum, sumsq per channel) ----------------
__global__ __launch_bounds__(256) void bnstats_kernel(
    const float* __restrict__ Y, float* __restrict__ stats)
{
    int c = threadIdx.x;
    int rows = Mrows / gridDim.x;
    int r0 = blockIdx.x * rows;
    float s = 0.f, s2 = 0.f;
    for (int r = r0; r < r0 + rows; ++r) {
        float v = Y[(size_t)r * DIMc + c];
        s += v; s2 += v * v;
    }
    atomicAdd(&stats[c], s);
    atomicAdd(&stats[256 + c], s2);
}

// ---------------- BatchNorm normalize ----------------
__global__ __launch_bounds__(256) void bnnorm_kernel(
    const float* __restrict__ Y, const float* __restrict__ stats,
    const float* __restrict__ g, const float* __restrict__ bta,
    float* __restrict__ out)
{
    int idx = blockIdx.x * 256 + threadIdx.x;
    int c = idx & 255;
    float mu = stats[c] * (1.f / (float)Mrows);
    float var = stats[256 + c] * (1.f / (float)Mrows) - mu * mu;
    float inv = rsqrtf(var + 1e-5f);
    out[idx] = (Y[idx] - mu) * inv * g[c] + bta[c];
}

// ---------------- launch ----------------
extern "C" void kernel_launch(void* const* d_in, const int* in_sizes, int n_in,
                              void* d_out, int out_size, void* d_ws, size_t ws_size,
                              hipStream_t stream)
{
    const float* x      = (const float*)d_in[0];
    const float* w_qkv  = (const float*)d_in[1];
    const float* b_qkv  = (const float*)d_in[2];
    const float* w_out  = (const float*)d_in[3];
    const float* b_out  = (const float*)d_in[4];
    const float* bn_g   = (const float*)d_in[5];
    const float* bn_b   = (const float*)d_in[6];
    const float* pconv_w = (const float*)d_in[7];
    const float* pconv_b = (const float*)d_in[8];
    const float* fc_w   = (const float*)d_in[9];
    const float* dep_w  = (const float*)d_in[10];
    const float* dep_b  = (const float*)d_in[11];
    const float* rate1  = (const float*)d_in[12];
    const float* rate2  = (const float*)d_in[13];
    float* out = (float*)d_out;

    char* ws = (char*)d_ws;
    float* qv    = (float*)(ws);                        // 64 MB
    float* Abuf  = (float*)(ws + 67108864);             // 32 MB
    float* Fbuf  = (float*)(ws + 100663296);            // 18 MB
    float* Ybuf  = (float*)(ws + 100663296);            // aliases Fbuf
    float* stats = (float*)(ws + 134217728);            // 512 floats

    // 1. qv = x @ w_qkv + b_qkv
    sgemm_kernel<false><<<dim3(4, 256), 256, 0, stream>>>(
        x, w_qkv, b_qkv, qv, Mrows, 512, 256);

    // 2. A = depthwise3x3(hard_swish(v)) + pconv_b
    vconv_kernel<<<(Mrows * 256) / 256, 256, 0, stream>>>(qv, pconv_w, pconv_b, Abuf);

    // 3. conv-attention branch
    fconv_fc_kernel<<<(Bn * 16 * Nn) / 256, 256, 0, stream>>>(qv, fc_w, Fbuf, 0);
    depconv_kernel<<<512, 256, 0, stream>>>(Fbuf, dep_w, dep_b, rate2, Abuf, 0);
    fconv_fc_kernel<<<(Bn * 16 * Nn) / 256, 256, 0, stream>>>(qv, fc_w, Fbuf, 128);
    depconv_kernel<<<512, 256, 0, stream>>>(Fbuf, dep_w, dep_b, rate2, Abuf, 128);

    // 4. MFMA window attention (A += rate1 * o)
    attn_mfma_kernel<<<512, 512, 0, stream>>>(qv, rate1, Abuf);

    // 5. Y = hard_swish(A) @ w_out + b_out
    sgemm_kernel<true><<<dim3(2, 256), 256, 0, stream>>>(
        Abuf, w_out, b_out, Ybuf, Mrows, 256, 256);

    // 6. BatchNorm
    hipMemsetAsync(stats, 0, 2 * 256 * sizeof(float), stream);
    bnstats_kernel<<<256, 256, 0, stream>>>(Ybuf, stats);
    bnnorm_kernel<<<(Mrows * 256) / 256, 256, 0, stream>>>(Ybuf, stats, bn_g, bn_b, out);
}

// Round 4
// 333.561 us; speedup vs baseline: 6.1369x; 1.3742x over previous
//
#include <hip/hip_runtime.h>
#include <hip/hip_bf16.h>
#include <math.h>

// ---------------- problem constants (fixed instance) ----------------
constexpr int Bn   = 8;
constexpr int Hh   = 64;
constexpr int Ww   = 64;
constexpr int Nn   = Hh * Ww;      // 4096
constexpr int Mrows = Bn * Nn;     // 32768
constexpr int QKVC = 512;          // qv channels
constexpr int DIMc = 256;

typedef short short8 __attribute__((ext_vector_type(8)));
typedef float f32x16 __attribute__((ext_vector_type(16)));
typedef float f32x4 __attribute__((ext_vector_type(4)));

__device__ __forceinline__ float hswish(float x) {
    float r = fminf(fmaxf(x + 3.f, 0.f), 6.f);
    return x * r * (1.f / 6.f);
}

__device__ __forceinline__ ushort bf16u(float f) {
    return __bfloat16_as_ushort(__float2bfloat16(f));
}

__device__ __forceinline__ uint32_t pkbf(float a, float b) {
    return (uint32_t)bf16u(a) | ((uint32_t)bf16u(b) << 16);
}

#if __has_builtin(__builtin_amdgcn_permlane32_swap)
typedef int int2v __attribute__((ext_vector_type(2)));
__device__ __forceinline__ void plswap(uint32_t& a, uint32_t& b) {
    int2v r = __builtin_amdgcn_permlane32_swap((int)a, (int)b, false, false);
    a = (uint32_t)r.x; b = (uint32_t)r.y;
}
#else
__device__ __forceinline__ void plswap(uint32_t& a, uint32_t& b) {
    int l = threadIdx.x & 63;
    uint32_t sa = (uint32_t)__shfl_xor((int)a, 32);
    uint32_t sb = (uint32_t)__shfl_xor((int)b, 32);
    uint32_t na = (l < 32) ? a : sb;
    uint32_t nb = (l < 32) ? sa : b;
    a = na; b = nb;
}
#endif

__device__ __forceinline__ void gload_lds16(const ushort* g, ushort* l) {
    __builtin_amdgcn_global_load_lds(
        (const __attribute__((address_space(1))) unsigned int*)g,
        (__attribute__((address_space(3))) unsigned int*)l, 16, 0, 0);
}

// ---------------- bf16 convert (optionally hard_swish) ----------------
template<bool ACT>
__global__ __launch_bounds__(256) void cvtbf_kernel(
    const float* __restrict__ in, ushort* __restrict__ out)
{
    int i = (blockIdx.x * 256 + threadIdx.x) * 8;
    float4 f0 = *reinterpret_cast<const float4*>(&in[i]);
    float4 f1 = *reinterpret_cast<const float4*>(&in[i + 4]);
    float v[8] = {f0.x, f0.y, f0.z, f0.w, f1.x, f1.y, f1.z, f1.w};
    ushort o[8];
    #pragma unroll
    for (int j = 0; j < 8; ++j) {
        float t = ACT ? hswish(v[j]) : v[j];
        o[j] = bf16u(t);
    }
    *reinterpret_cast<short8*>(&out[i]) = *reinterpret_cast<short8*>(o);
}

// ---------------- weight transpose + bf16 convert: Wt[n][k] = bf16(W[k][n]) ----------------
__global__ __launch_bounds__(256) void wtconv_kernel(
    const float* __restrict__ Wf, ushort* __restrict__ Wt, int K, int N)
{
    int idx = blockIdx.x * 256 + threadIdx.x;   // k fast
    int n = idx / K, k = idx - n * K;
    Wt[idx] = bf16u(Wf[(size_t)k * N + n]);
}

// ---------------- bf16 MFMA GEMM: C = A(bf16)[M,K] @ Bt(bf16)[N,K]^T + bias ----------------
// 128x128 tile, BK=32, 4 waves (2x2 of 64x64), 16x16x32 MFMA.
// LDS layout [r][k] with k-quarter XOR swizzle q' = q ^ (r&3); staged via
// global_load_lds (linear dest, pre-swizzled per-lane global source).
__global__ __launch_bounds__(256) void hgemm_kernel(
    const ushort* __restrict__ A, const ushort* __restrict__ Bt,
    const float* __restrict__ bias, float* __restrict__ C,
    int M, int N, int K)
{
    __shared__ ushort As[128 * 32];
    __shared__ ushort Bs[128 * 32];
    const int tid = threadIdx.x;
    const int w = tid >> 6, l = tid & 63;
    const int brow = blockIdx.y * 128;
    const int bcol = blockIdx.x * 128;
    const int wm = (w >> 1) * 64, wn = (w & 1) * 64;

    f32x4 acc[4][4] = {};

    // staging: chunk c in [0,512) -> lds bytes c*16; row r=c>>2, slot q=c&3
    // global k-quarter for that slot = q ^ (r&3)
    const int c0 = tid, c1 = tid + 256;
    const int r0 = c0 >> 2, q0 = (c0 & 3) ^ (r0 & 3);
    const int r1 = c1 >> 2, q1 = (c1 & 3) ^ (r1 & 3);
    const ushort* a0p = &A[(size_t)(brow + r0) * K + q0 * 8];
    const ushort* a1p = &A[(size_t)(brow + r1) * K + q1 * 8];
    const ushort* b0p = &Bt[(size_t)(bcol + r0) * K + q0 * 8];
    const ushort* b1p = &Bt[(size_t)(bcol + r1) * K + q1 * 8];
    ushort* asw0 = &As[(w * 64) * 8];          // wave-uniform dests
    ushort* asw1 = &As[(256 + w * 64) * 8];
    ushort* bsw0 = &Bs[(w * 64) * 8];
    ushort* bsw1 = &Bs[(256 + w * 64) * 8];

    const int fr = l & 15;                      // frag row/col within 16
    const int qq = ((l >> 4) ^ (l & 3)) * 8;    // swizzled k-quarter on read

    for (int k0 = 0; k0 < K; k0 += 32) {
        gload_lds16(a0p + k0, asw0);
        gload_lds16(a1p + k0, asw1);
        gload_lds16(b0p + k0, bsw0);
        gload_lds16(b1p + k0, bsw1);
        __syncthreads();
        short8 af[4], bf[4];
        #pragma unroll
        for (int i = 0; i < 4; ++i) {
            af[i] = *reinterpret_cast<const short8*>(&As[(wm + i * 16 + fr) * 32 + qq]);
            bf[i] = *reinterpret_cast<const short8*>(&Bs[(wn + i * 16 + fr) * 32 + qq]);
        }
        #pragma unroll
        for (int mi = 0; mi < 4; ++mi)
            #pragma unroll
            for (int ni = 0; ni < 4; ++ni)
                acc[mi][ni] = __builtin_amdgcn_mfma_f32_16x16x32_bf16(
                    af[mi], bf[ni], acc[mi][ni], 0, 0, 0);
        __syncthreads();
    }

    const int cr = l >> 4;   // C: col = lane&15, row = (lane>>4)*4 + reg
    #pragma unroll
    for (int ni = 0; ni < 4; ++ni) {
        int n = bcol + wn + ni * 16 + fr;
        float bv = bias[n];
        #pragma unroll
        for (int mi = 0; mi < 4; ++mi) {
            int m = brow + wm + mi * 16 + cr * 4;
            float* cp = &C[(size_t)m * N + n];
            #pragma unroll
            for (int r = 0; r < 4; ++r)
                cp[(size_t)r * N] = acc[mi][ni][r] + bv;
        }
    }
}

// ---------------- depthwise 3x3 on hard_swish(v): A = v_conv ----------------
__global__ __launch_bounds__(256) void vconv_kernel(
    const float* __restrict__ qv, const float* __restrict__ pw,
    const float* __restrict__ pb, float* __restrict__ Abuf)
{
    int idx = blockIdx.x * 256 + threadIdx.x;
    int c = idx & 255;
    int n = (idx >> 8) & (Nn - 1);
    int b = idx >> 20;
    int x = n & 63, y = n >> 6;
    float sum = pb[c];
    #pragma unroll
    for (int ky = 0; ky < 3; ++ky) {
        int yy = y + ky - 1;
        if (yy >= 0 && yy < Hh) {
            #pragma unroll
            for (int kx = 0; kx < 3; ++kx) {
                int xx = x + kx - 1;
                if (xx >= 0 && xx < Ww) {
                    float v = qv[(size_t)(b * Nn + yy * Ww + xx) * QKVC + 256 + c];
                    sum += hswish(v) * pw[c * 9 + ky * 3 + kx];
                }
            }
        }
    }
    Abuf[(size_t)(b * Nn + n) * DIMc + c] = sum;
}

// ---------------- conv-attention branch step 1: fc over raw-reshaped f ----------------
__global__ __launch_bounds__(256) void fconv_fc_kernel(
    const float* __restrict__ qv, const float* __restrict__ fcw,
    float* __restrict__ Fbuf, int qoff)
{
    int idx = blockIdx.x * 256 + threadIdx.x;
    int n = idx & (Nn - 1);
    int s = (idx >> 12) & 15;
    int b = idx >> 16;
    int t = n >> 7, u = n & 127;
    float fq[8], fv[8];
    #pragma unroll
    for (int a = 0; a < 8; ++a) {
        int nq = (a * 16 + s) * 32 + t;
        size_t base = (size_t)(b * Nn + nq) * QKVC;
        fq[a] = qv[base + qoff + u];
        fv[a] = qv[base + 256 + qoff + u];
    }
    #pragma unroll
    for (int o = 0; o < 9; ++o) {
        float acc = 0.f;
        #pragma unroll
        for (int a = 0; a < 8; ++a) {
            acc += fcw[o * 24 + a] * fq[a]
                 + (fcw[o * 24 + 8 + a] + fcw[o * 24 + 16 + a]) * fv[a];
        }
        Fbuf[(size_t)(b * 144 + (s * 9 + o)) * Nn + n] = acc;
    }
}

// ---------------- conv-attention branch step 2: grouped 3x3 conv (LDS-tiled) ----------------
__global__ __launch_bounds__(256) void depconv_kernel(
    const float* __restrict__ Fbuf, const float* __restrict__ dw,
    const float* __restrict__ db, const float* __restrict__ rate2p,
    float* __restrict__ Abuf, int coff)
{
    int blk = blockIdx.x;
    int ytile = blk & 3;
    int gi = (blk >> 2) & 15;
    int b = blk >> 6;
    int y0 = ytile * 16;

    __shared__ float sp[9][18][66];
    __shared__ float wt[8][81];
    const int tid = threadIdx.x;

    for (int i = tid; i < 9 * 18 * 64; i += 256) {
        int xx = i & 63;
        int r  = (i >> 6) % 18;
        int ic = (i >> 6) / 18;
        int yy = y0 + r - 1;
        float v = 0.f;
        if (yy >= 0 && yy < Hh)
            v = Fbuf[(size_t)(b * 144 + gi * 9 + ic) * Nn + yy * 64 + xx];
        sp[ic][r][xx + 1] = v;
    }
    for (int i = tid; i < 9 * 18; i += 256) {
        int r = i % 18, ic = i / 18;
        sp[ic][r][0] = 0.f;
        sp[ic][r][65] = 0.f;
    }
    for (int i = tid; i < 8 * 81; i += 256) {
        int ocl = i / 81, t = i % 81;
        wt[ocl][t] = dw[(gi * 8 + ocl) * 81 + t];
    }
    __syncthreads();

    const int x = tid & 63;
    const int quad = tid >> 6;
    const int ylb = quad * 4;

    float acc[8][4] = {};
    #pragma unroll
    for (int ic = 0; ic < 9; ++ic) {
        float rv[6][3];
        #pragma unroll
        for (int r = 0; r < 6; ++r) {
            rv[r][0] = sp[ic][ylb + r][x];
            rv[r][1] = sp[ic][ylb + r][x + 1];
            rv[r][2] = sp[ic][ylb + r][x + 2];
        }
        #pragma unroll
        for (int ocl = 0; ocl < 8; ++ocl) {
            #pragma unroll
            for (int ky = 0; ky < 3; ++ky) {
                #pragma unroll
                for (int kx = 0; kx < 3; ++kx) {
                    float w = wt[ocl][ic * 9 + ky * 3 + kx];
                    #pragma unroll
                    for (int yl = 0; yl < 4; ++yl)
                        acc[ocl][yl] += w * rv[yl + ky][kx];
                }
            }
        }
    }

    const float r2 = rate2p[0];
    float dbv[8];
    #pragma unroll
    for (int ocl = 0; ocl < 8; ++ocl) dbv[ocl] = db[gi * 8 + ocl];

    #pragma unroll
    for (int yl = 0; yl < 4; ++yl) {
        int n = (y0 + ylb + yl) * 64 + x;
        float* ap = &Abuf[(size_t)(b * Nn + n) * DIMc + coff + gi * 8];
        float4 o0 = *reinterpret_cast<float4*>(&ap[0]);
        float4 o1 = *reinterpret_cast<float4*>(&ap[4]);
        o0.x += r2 * (acc[0][yl] + dbv[0]);
        o0.y += r2 * (acc[1][yl] + dbv[1]);
        o0.z += r2 * (acc[2][yl] + dbv[2]);
        o0.w += r2 * (acc[3][yl] + dbv[3]);
        o1.x += r2 * (acc[4][yl] + dbv[4]);
        o1.y += r2 * (acc[5][yl] + dbv[5]);
        o1.z += r2 * (acc[6][yl] + dbv[6]);
        o1.w += r2 * (acc[7][yl] + dbv[7]);
        *reinterpret_cast<float4*>(&ap[0]) = o0;
        *reinterpret_cast<float4*>(&ap[4]) = o1;
    }
}

// ---------------- MFMA cross-shaped window attention (k == v) ----------------
__global__ __launch_bounds__(512) void attn_mfma_kernel(
    const float* __restrict__ qv, const float* __restrict__ rate1p,
    float* __restrict__ Abuf)
{
    int bid = blockIdx.x;
    bool hor = bid < 256;
    int lb = bid & 255;
    int hd = lb & 3;
    int g = (lb >> 2) & 7;
    int b = lb >> 5;
    int half = hor ? 0 : 128;
    int qoff = half + hd * 32;
    int kvoff = 256 + qoff;

    __shared__ __align__(16) char smem[65536];
    char* ldsK  = smem;            // 32 KB
    char* ldsVT = smem + 32768;    // 32 KB

    const int tid = threadIdx.x;
    const float QS = 0.17677669529663687f * 1.44269504088896f;  // scale * log2(e)

    {
        int l = tid;
        int n = hor ? (g * 512 + l) : ((l & 63) * 64 + g * 8 + (l >> 6));
        const float* kp = &qv[(size_t)(b * Nn + n) * QKVC + kvoff];
        float row[32];
        #pragma unroll
        for (int q4 = 0; q4 < 8; ++q4) {
            float4 v = *reinterpret_cast<const float4*>(&kp[q4 * 4]);
            row[q4 * 4 + 0] = v.x; row[q4 * 4 + 1] = v.y;
            row[q4 * 4 + 2] = v.z; row[q4 * 4 + 3] = v.w;
        }
        uint32_t p32[16];
        ushort us[32];
        #pragma unroll
        for (int d = 0; d < 32; ++d)
            us[d] = __bfloat16_as_ushort(__float2bfloat16(row[d]));
        #pragma unroll
        for (int i = 0; i < 16; ++i)
            p32[i] = (uint32_t)us[2 * i] | ((uint32_t)us[2 * i + 1] << 16);
        #pragma unroll
        for (int gi = 0; gi < 4; ++gi) {
            uint4 w;
            w.x = p32[gi * 4 + 0]; w.y = p32[gi * 4 + 1];
            w.z = p32[gi * 4 + 2]; w.w = p32[gi * 4 + 3];
            *reinterpret_cast<uint4*>(ldsK + l * 64 + ((gi ^ (l & 3)) << 4)) = w;
        }
        #pragma unroll
        for (int d = 0; d < 32; ++d)
            *reinterpret_cast<ushort*>(ldsVT + d * 1024 + ((l * 2) ^ ((d & 7) << 4))) = us[d];
    }
    __syncthreads();

    const int w = tid >> 6;
    const int lane = tid & 63;
    const int qcol = lane & 31;
    const int hh = lane >> 5;
    const float r1 = rate1p[0];

    #pragma unroll 1
    for (int qt = 0; qt < 2; ++qt) {
        const int q0 = (w * 2 + qt) * 32;
        const int qrow = q0 + qcol;
        const int nq = hor ? (g * 512 + qrow) : ((qrow & 63) * 64 + g * 8 + (qrow >> 6));

        short8 qb[2];
        #pragma unroll
        for (int t = 0; t < 2; ++t) {
            const float* qp = &qv[(size_t)(b * Nn + nq) * QKVC + qoff + t * 16 + hh * 8];
            float4 f0 = *reinterpret_cast<const float4*>(&qp[0]);
            float4 f1 = *reinterpret_cast<const float4*>(&qp[4]);
            union { uint32_t u[4]; short8 s; } qa;
            qa.u[0] = pkbf(f0.x * QS, f0.y * QS);
            qa.u[1] = pkbf(f0.z * QS, f0.w * QS);
            qa.u[2] = pkbf(f1.x * QS, f1.y * QS);
            qa.u[3] = pkbf(f1.z * QS, f1.w * QS);
            qb[t] = qa.s;
        }

        f32x16 acc = {0,0,0,0,0,0,0,0,0,0,0,0,0,0,0,0};
        float rs = 0.f;

        for (int s = 0; s < 16; ++s) {
            const int k0 = s * 32;
            const int kr = k0 + qcol;
            const short8 a0 = *reinterpret_cast<const short8*>(
                ldsK + kr * 64 + (((0 + hh) ^ (kr & 3)) << 4));
            const short8 a1 = *reinterpret_cast<const short8*>(
                ldsK + kr * 64 + (((2 + hh) ^ (kr & 3)) << 4));
            f32x16 st = {0,0,0,0,0,0,0,0,0,0,0,0,0,0,0,0};
            st = __builtin_amdgcn_mfma_f32_32x32x16_bf16(a0, qb[0], st, 0, 0, 0);
            st = __builtin_amdgcn_mfma_f32_32x32x16_bf16(a1, qb[1], st, 0, 0, 0);

            float p[16];
            #pragma unroll
            for (int r = 0; r < 16; ++r) p[r] = exp2f(st[r]);
            float s01 = (p[0] + p[1]) + (p[2] + p[3]);
            float s23 = (p[4] + p[5]) + (p[6] + p[7]);
            float s45 = (p[8] + p[9]) + (p[10] + p[11]);
            float s67 = (p[12] + p[13]) + (p[14] + p[15]);
            rs += (s01 + s23) + (s45 + s67);

            uint32_t X[8];
            #pragma unroll
            for (int gg = 0; gg < 4; ++gg) {
                X[2 * gg + 0] = pkbf(p[4 * gg + 0], p[4 * gg + 1]);
                X[2 * gg + 1] = pkbf(p[4 * gg + 2], p[4 * gg + 3]);
            }
            #pragma unroll
            for (int u = 0; u < 2; ++u) {
                uint32_t w0 = X[4 * u + 0], w2 = X[4 * u + 2];
                uint32_t w1 = X[4 * u + 1], w3 = X[4 * u + 3];
                plswap(w0, w2);
                plswap(w1, w3);
                union { uint32_t u4[4]; short8 s; } pf;
                pf.u4[0] = w0; pf.u4[1] = w1; pf.u4[2] = w2; pf.u4[3] = w3;
                const int d = qcol;
                const short8 vf = *reinterpret_cast<const short8*>(
                    ldsVT + d * 1024 + ((k0 * 2 + u * 32 + hh * 16) ^ ((d & 7) << 4)));
                acc = __builtin_amdgcn_mfma_f32_32x32x16_bf16(vf, pf.s, acc, 0, 0, 0);
            }
        }

        float rsf = rs + __shfl_xor(rs, 32);
        float scl = r1 / rsf;
        float* ap = &Abuf[(size_t)(b * Nn + nq) * DIMc + qoff];
        #pragma unroll
        for (int gg = 0; gg < 4; ++gg) {
            int d0 = 8 * gg + 4 * hh;
            float4 o = *reinterpret_cast<float4*>(&ap[d0]);
            o.x += acc[4 * gg + 0] * scl;
            o.y += acc[4 * gg + 1] * scl;
            o.z += acc[4 * gg + 2] * scl;
            o.w += acc[4 * gg + 3] * scl;
            *reinterpret_cast<float4*>(&ap[d0]) = o;
        }
    }
}

// ---------------- BatchNorm stats (sum, sumsq per channel) ----------------
__global__ __launch_bounds__(256) void bnstats_kernel(
    const float* __restrict__ Y, float* __restrict__ stats)
{
    int c = threadIdx.x;
    int rows = Mrows / gridDim.x;
    int r0 = blockIdx.x * rows;
    float s = 0.f, s2 = 0.f;
    for (int r = r0; r < r0 + rows; ++r) {
        float v = Y[(size_t)r * DIMc + c];
        s += v; s2 += v * v;
    }
    atomicAdd(&stats[c], s);
    atomicAdd(&stats[256 + c], s2);
}

// ---------------- BatchNorm normalize ----------------
__global__ __launch_bounds__(256) void bnnorm_kernel(
    const float* __restrict__ Y, const float* __restrict__ stats,
    const float* __restrict__ g, const float* __restrict__ bta,
    float* __restrict__ out)
{
    int idx = blockIdx.x * 256 + threadIdx.x;
    int c = idx & 255;
    float mu = stats[c] * (1.f / (float)Mrows);
    float var = stats[256 + c] * (1.f / (float)Mrows) - mu * mu;
    float inv = rsqrtf(var + 1e-5f);
    out[idx] = (Y[idx] - mu) * inv * g[c] + bta[c];
}

// ---------------- launch ----------------
extern "C" void kernel_launch(void* const* d_in, const int* in_sizes, int n_in,
                              void* d_out, int out_size, void* d_ws, size_t ws_size,
                              hipStream_t stream)
{
    const float* x      = (const float*)d_in[0];
    const float* w_qkv  = (const float*)d_in[1];
    const float* b_qkv  = (const float*)d_in[2];
    const float* w_out  = (const float*)d_in[3];
    const float* b_out  = (const float*)d_in[4];
    const float* bn_g   = (const float*)d_in[5];
    const float* bn_b   = (const float*)d_in[6];
    const float* pconv_w = (const float*)d_in[7];
    const float* pconv_b = (const float*)d_in[8];
    const float* fc_w   = (const float*)d_in[9];
    const float* dep_w  = (const float*)d_in[10];
    const float* dep_b  = (const float*)d_in[11];
    const float* rate1  = (const float*)d_in[12];
    const float* rate2  = (const float*)d_in[13];
    float* out = (float*)d_out;

    char* ws = (char*)d_ws;
    float*  qv    = (float*)(ws);                            // 64 MB [0,64M)
    float*  Abuf  = (float*)(ws + (64u << 20));              // 32 MB
    float*  Fbuf  = (float*)(ws + (96u << 20));              // 18.9 MB
    float*  Ybuf  = (float*)(ws + (96u << 20));              // 32 MB (Fbuf dead by GEMM2)
    float*  stats = (float*)(ws + (128u << 20));             // 2 KB
    ushort* xb    = (ushort*)(ws + (64u << 20));             // 16 MB, aliases Abuf (dead before vconv)
    ushort* Hb    = (ushort*)(ws);                           // 16 MB, aliases qv (dead after attn)
    ushort* Wt1   = (ushort*)(ws + (128u << 20) + 4096);     // 256 KB
    ushort* Wt2   = (ushort*)(ws + (128u << 20) + 4096 + (256u << 10)); // 128 KB

    // 0. precision prep: bf16 copies (weights transposed to [N][K])
    wtconv_kernel<<<(512 * 256) / 256, 256, 0, stream>>>(w_qkv, Wt1, 256, 512);
    wtconv_kernel<<<(256 * 256) / 256, 256, 0, stream>>>(w_out, Wt2, 256, 256);
    cvtbf_kernel<false><<<(Mrows * 256 / 8) / 256, 256, 0, stream>>>(x, xb);

    // 1. qv = x @ w_qkv + b_qkv   (bf16 MFMA)
    hgemm_kernel<<<dim3(4, 256), 256, 0, stream>>>(xb, Wt1, b_qkv, qv, Mrows, 512, 256);

    // 2. A = depthwise3x3(hard_swish(v)) + pconv_b
    vconv_kernel<<<(Mrows * 256) / 256, 256, 0, stream>>>(qv, pconv_w, pconv_b, Abuf);

    // 3. conv-attention branch
    fconv_fc_kernel<<<(Bn * 16 * Nn) / 256, 256, 0, stream>>>(qv, fc_w, Fbuf, 0);
    depconv_kernel<<<512, 256, 0, stream>>>(Fbuf, dep_w, dep_b, rate2, Abuf, 0);
    fconv_fc_kernel<<<(Bn * 16 * Nn) / 256, 256, 0, stream>>>(qv, fc_w, Fbuf, 128);
    depconv_kernel<<<512, 256, 0, stream>>>(Fbuf, dep_w, dep_b, rate2, Abuf, 128);

    // 4. MFMA window attention (A += rate1 * o)
    attn_mfma_kernel<<<512, 512, 0, stream>>>(qv, rate1, Abuf);

    // 5. Y = hard_swish(A) @ w_out + b_out   (bf16 MFMA; hswish in pre-pass)
    cvtbf_kernel<true><<<(Mrows * 256 / 8) / 256, 256, 0, stream>>>(Abuf, Hb);
    hgemm_kernel<<<dim3(2, 256), 256, 0, stream>>>(Hb, Wt2, b_out, Ybuf, Mrows, 256, 256);

    // 6. BatchNorm
    hipMemsetAsync(stats, 0, 2 * 256 * sizeof(float), stream);
    bnstats_kernel<<<256, 256, 0, stream>>>(Ybuf, stats);
    bnnorm_kernel<<<(Mrows * 256) / 256, 256, 0, stream>>>(Ybuf, stats, bn_g, bn_b, out);
}

// Round 5
// 306.401 us; speedup vs baseline: 6.6809x; 1.0886x over previous
//
#include <hip/hip_runtime.h>
#include <hip/hip_bf16.h>
#include <math.h>

// ---------------- problem constants (fixed instance) ----------------
constexpr int Bn   = 8;
constexpr int Hh   = 64;
constexpr int Ww   = 64;
constexpr int Nn   = Hh * Ww;      // 4096
constexpr int Mrows = Bn * Nn;     // 32768
constexpr int QKVC = 512;          // qv channels
constexpr int DIMc = 256;

typedef short short8 __attribute__((ext_vector_type(8)));
typedef float f32x16 __attribute__((ext_vector_type(16)));
typedef float f32x4 __attribute__((ext_vector_type(4)));

__device__ __forceinline__ float hswish(float x) {
    float r = fminf(fmaxf(x + 3.f, 0.f), 6.f);
    return x * r * (1.f / 6.f);
}

__device__ __forceinline__ ushort bf16u(float f) {
    return __bfloat16_as_ushort(__float2bfloat16(f));
}

__device__ __forceinline__ uint32_t pkbf(float a, float b) {
    return (uint32_t)bf16u(a) | ((uint32_t)bf16u(b) << 16);
}

#if __has_builtin(__builtin_amdgcn_permlane32_swap)
typedef int int2v __attribute__((ext_vector_type(2)));
__device__ __forceinline__ void plswap(uint32_t& a, uint32_t& b) {
    int2v r = __builtin_amdgcn_permlane32_swap((int)a, (int)b, false, false);
    a = (uint32_t)r.x; b = (uint32_t)r.y;
}
#else
__device__ __forceinline__ void plswap(uint32_t& a, uint32_t& b) {
    int l = threadIdx.x & 63;
    uint32_t sa = (uint32_t)__shfl_xor((int)a, 32);
    uint32_t sb = (uint32_t)__shfl_xor((int)b, 32);
    uint32_t na = (l < 32) ? a : sb;
    uint32_t nb = (l < 32) ? sa : b;
    a = na; b = nb;
}
#endif

__device__ __forceinline__ void gload_lds16(const ushort* g, ushort* l) {
    __builtin_amdgcn_global_load_lds(
        (const __attribute__((address_space(1))) unsigned int*)g,
        (__attribute__((address_space(3))) unsigned int*)l, 16, 0, 0);
}

// ---------------- bf16 convert (optionally hard_swish) ----------------
template<bool ACT>
__global__ __launch_bounds__(256) void cvtbf_kernel(
    const float* __restrict__ in, ushort* __restrict__ out)
{
    int i = (blockIdx.x * 256 + threadIdx.x) * 8;
    float4 f0 = *reinterpret_cast<const float4*>(&in[i]);
    float4 f1 = *reinterpret_cast<const float4*>(&in[i + 4]);
    float v[8] = {f0.x, f0.y, f0.z, f0.w, f1.x, f1.y, f1.z, f1.w};
    ushort o[8];
    #pragma unroll
    for (int j = 0; j < 8; ++j) {
        float t = ACT ? hswish(v[j]) : v[j];
        o[j] = bf16u(t);
    }
    *reinterpret_cast<short8*>(&out[i]) = *reinterpret_cast<short8*>(o);
}

// ---------------- weight transpose + bf16 convert: Wt[n][k] = bf16(W[k][n]) ----------------
__global__ __launch_bounds__(256) void wtconv_kernel(
    const float* __restrict__ Wf, ushort* __restrict__ Wt, int K, int N)
{
    int idx = blockIdx.x * 256 + threadIdx.x;   // k fast
    int n = idx / K, k = idx - n * K;
    Wt[idx] = bf16u(Wf[(size_t)k * N + n]);
}

// ---------------- effective conv weights: compose fc (24->9) with dep 3x3 ----------------
// Weff[gi][oc][a][k][{q,v}]: q = sum_ic dw[oc][ic][k]*fcw[ic][a],
//                            v = sum_ic dw[oc][ic][k]*(fcw[ic][8+a]+fcw[ic][16+a])
__global__ __launch_bounds__(256) void weff_kernel(
    const float* __restrict__ dw, const float* __restrict__ fcw,
    float* __restrict__ Weff)
{
    int idx = blockIdx.x * 256 + threadIdx.x;   // 16*8*8*9 = 9216
    int k = idx % 9;
    int a = (idx / 9) & 7;
    int oc = (idx / 72) & 7;
    int gi = idx / 576;
    float q = 0.f, v = 0.f;
    const float* dwp = &dw[(gi * 8 + oc) * 81 + k];
    #pragma unroll
    for (int ic = 0; ic < 9; ++ic) {
        float d = dwp[ic * 9];
        q += d * fcw[ic * 24 + a];
        v += d * (fcw[ic * 24 + 8 + a] + fcw[ic * 24 + 16 + a]);
    }
    Weff[idx * 2]     = q;
    Weff[idx * 2 + 1] = v;
}

// ---------------- bf16 MFMA GEMM: C = A(bf16)[M,K] @ Bt(bf16)[N,K]^T + bias ----------------
__global__ __launch_bounds__(256) void hgemm_kernel(
    const ushort* __restrict__ A, const ushort* __restrict__ Bt,
    const float* __restrict__ bias, float* __restrict__ C,
    int M, int N, int K)
{
    __shared__ ushort As[128 * 32];
    __shared__ ushort Bs[128 * 32];
    const int tid = threadIdx.x;
    const int w = tid >> 6, l = tid & 63;
    const int brow = blockIdx.y * 128;
    const int bcol = blockIdx.x * 128;
    const int wm = (w >> 1) * 64, wn = (w & 1) * 64;

    f32x4 acc[4][4] = {};

    const int c0 = tid, c1 = tid + 256;
    const int r0 = c0 >> 2, q0 = (c0 & 3) ^ (r0 & 3);
    const int r1 = c1 >> 2, q1 = (c1 & 3) ^ (r1 & 3);
    const ushort* a0p = &A[(size_t)(brow + r0) * K + q0 * 8];
    const ushort* a1p = &A[(size_t)(brow + r1) * K + q1 * 8];
    const ushort* b0p = &Bt[(size_t)(bcol + r0) * K + q0 * 8];
    const ushort* b1p = &Bt[(size_t)(bcol + r1) * K + q1 * 8];
    ushort* asw0 = &As[(w * 64) * 8];
    ushort* asw1 = &As[(256 + w * 64) * 8];
    ushort* bsw0 = &Bs[(w * 64) * 8];
    ushort* bsw1 = &Bs[(256 + w * 64) * 8];

    const int fr = l & 15;
    const int qq = ((l >> 4) ^ (l & 3)) * 8;

    for (int k0 = 0; k0 < K; k0 += 32) {
        gload_lds16(a0p + k0, asw0);
        gload_lds16(a1p + k0, asw1);
        gload_lds16(b0p + k0, bsw0);
        gload_lds16(b1p + k0, bsw1);
        __syncthreads();
        short8 af[4], bf[4];
        #pragma unroll
        for (int i = 0; i < 4; ++i) {
            af[i] = *reinterpret_cast<const short8*>(&As[(wm + i * 16 + fr) * 32 + qq]);
            bf[i] = *reinterpret_cast<const short8*>(&Bs[(wn + i * 16 + fr) * 32 + qq]);
        }
        #pragma unroll
        for (int mi = 0; mi < 4; ++mi)
            #pragma unroll
            for (int ni = 0; ni < 4; ++ni)
                acc[mi][ni] = __builtin_amdgcn_mfma_f32_16x16x32_bf16(
                    af[mi], bf[ni], acc[mi][ni], 0, 0, 0);
        __syncthreads();
    }

    const int cr = l >> 4;
    #pragma unroll
    for (int ni = 0; ni < 4; ++ni) {
        int n = bcol + wn + ni * 16 + fr;
        float bv = bias[n];
        #pragma unroll
        for (int mi = 0; mi < 4; ++mi) {
            int m = brow + wm + mi * 16 + cr * 4;
            float* cp = &C[(size_t)m * N + n];
            #pragma unroll
            for (int r = 0; r < 4; ++r)
                cp[(size_t)r * N] = acc[mi][ni][r] + bv;
        }
    }
}

// ---------------- depthwise 3x3 on hard_swish(v): A = v_conv ----------------
__global__ __launch_bounds__(256) void vconv_kernel(
    const float* __restrict__ qv, const float* __restrict__ pw,
    const float* __restrict__ pb, float* __restrict__ Abuf)
{
    int idx = blockIdx.x * 256 + threadIdx.x;
    int c = idx & 255;
    int n = (idx >> 8) & (Nn - 1);
    int b = idx >> 20;
    int x = n & 63, y = n >> 6;
    float sum = pb[c];
    #pragma unroll
    for (int ky = 0; ky < 3; ++ky) {
        int yy = y + ky - 1;
        if (yy >= 0 && yy < Hh) {
            #pragma unroll
            for (int kx = 0; kx < 3; ++kx) {
                int xx = x + kx - 1;
                if (xx >= 0 && xx < Ww) {
                    float v = qv[(size_t)(b * Nn + yy * Ww + xx) * QKVC + 256 + c];
                    sum += hswish(v) * pw[c * 9 + ky * 3 + kx];
                }
            }
        }
    }
    Abuf[(size_t)(b * Nn + n) * DIMc + c] = sum;
}

// ---------------- fused conv-attention branch (fc + grouped 3x3, both branches) ----------------
// blk = ((branch*8 + b)*16 + gi)*8 + ytile; 8-row y-tile, 8 output channels.
// Reads qv directly via the raw-reshape map:
//   plane(a, s=gi) at (y,x) = qv[b][(a*16+gi)*32 + (y>>1)][qoff + (y&1)*64 + x]
__global__ __launch_bounds__(256) void convbranch_kernel(
    const float* __restrict__ qv, const float* __restrict__ Weff,
    const float* __restrict__ db, const float* __restrict__ rate2p,
    float* __restrict__ Abuf)
{
    int blk = blockIdx.x;              // 2048
    int ytile = blk & 7;
    int gi = (blk >> 3) & 15;
    int b = (blk >> 7) & 7;
    int branch = blk >> 10;
    int y0 = ytile * 8;
    int qoff = branch * 128;
    int coff = branch * 128;

    __shared__ float sq[8][10][66];
    __shared__ float sv[8][10][66];
    __shared__ float wqv[8][8][9][2];   // [oc][a][k][{q,v}] — matches Weff[gi] layout
    const int tid = threadIdx.x;

    // stage inputs (zero halo / out-of-range)
    for (int i = tid; i < 8 * 10 * 66; i += 256) {
        int xp = i % 66;
        int rr = (i / 66) % 10;
        int a = i / 660;
        int x = xp - 1;
        int y = y0 + rr - 1;
        float qvl = 0.f, vvl = 0.f;
        if (x >= 0 && x < 64 && y >= 0 && y < 64) {
            int token = (a * 16 + gi) * 32 + (y >> 1);
            int chan = (y & 1) * 64 + x;
            const float* p = &qv[(size_t)(b * Nn + token) * QKVC + qoff + chan];
            qvl = p[0];
            vvl = p[256];
        }
        sq[a][rr][xp] = qvl;
        sv[a][rr][xp] = vvl;
    }
    const float* wsrc = &Weff[gi * 1152];
    for (int i = tid; i < 1152; i += 256)
        ((float*)wqv)[i] = wsrc[i];
    __syncthreads();

    const int x = tid & 63;
    const int oc0 = (tid >> 6) * 2;    // wave-uniform

    float acc[2][8] = {};              // [ocl][row]
    #pragma unroll 1
    for (int a = 0; a < 8; ++a) {
        float iq[10][3], iv[10][3];
        #pragma unroll
        for (int rr = 0; rr < 10; ++rr)
            #pragma unroll
            for (int c = 0; c < 3; ++c) {
                iq[rr][c] = sq[a][rr][x + c];
                iv[rr][c] = sv[a][rr][x + c];
            }
        #pragma unroll
        for (int ocl = 0; ocl < 2; ++ocl) {
            #pragma unroll
            for (int ky = 0; ky < 3; ++ky)
                #pragma unroll
                for (int kx = 0; kx < 3; ++kx) {
                    float2 w = *reinterpret_cast<const float2*>(
                        &wqv[oc0 + ocl][a][ky * 3 + kx][0]);
                    #pragma unroll
                    for (int row = 0; row < 8; ++row)
                        acc[ocl][row] += w.x * iq[row + ky][kx]
                                       + w.y * iv[row + ky][kx];
                }
        }
    }

    // transpose through LDS for coalesced RMW
    __syncthreads();
    float* so = (float*)sq;            // 512 px * 8 oc = 16 KB
    const float r2 = rate2p[0];
    float d0 = db[gi * 8 + oc0], d1 = db[gi * 8 + oc0 + 1];
    #pragma unroll
    for (int row = 0; row < 8; ++row) {
        so[(row * 64 + x) * 8 + oc0]     = r2 * (acc[0][row] + d0);
        so[(row * 64 + x) * 8 + oc0 + 1] = r2 * (acc[1][row] + d1);
    }
    __syncthreads();
    for (int i = tid; i < 2048; i += 256) {
        int px = i >> 2, sl = (i & 3) * 2;
        int n = (y0 + (px >> 6)) * 64 + (px & 63);
        float* ap = &Abuf[(size_t)(b * Nn + n) * DIMc + coff + gi * 8 + sl];
        float2 cur = *reinterpret_cast<const float2*>(ap);
        float2 add = *reinterpret_cast<const float2*>(&so[px * 8 + sl]);
        cur.x += add.x; cur.y += add.y;
        *reinterpret_cast<float2*>(ap) = cur;
    }
}

// ---------------- MFMA cross-shaped window attention (k == v) ----------------
__global__ __launch_bounds__(512) void attn_mfma_kernel(
    const float* __restrict__ qv, const float* __restrict__ rate1p,
    float* __restrict__ Abuf)
{
    int bid = blockIdx.x;
    bool hor = bid < 256;
    int lb = bid & 255;
    int hd = lb & 3;
    int g = (lb >> 2) & 7;
    int b = lb >> 5;
    int half = hor ? 0 : 128;
    int qoff = half + hd * 32;
    int kvoff = 256 + qoff;

    __shared__ __align__(16) char smem[65536];
    char* ldsK  = smem;            // 32 KB
    char* ldsVT = smem + 32768;    // 32 KB

    const int tid = threadIdx.x;
    const float QS = 0.17677669529663687f * 1.44269504088896f;  // scale * log2(e)

    {
        int l = tid;
        int n = hor ? (g * 512 + l) : ((l & 63) * 64 + g * 8 + (l >> 6));
        const float* kp = &qv[(size_t)(b * Nn + n) * QKVC + kvoff];
        float row[32];
        #pragma unroll
        for (int q4 = 0; q4 < 8; ++q4) {
            float4 v = *reinterpret_cast<const float4*>(&kp[q4 * 4]);
            row[q4 * 4 + 0] = v.x; row[q4 * 4 + 1] = v.y;
            row[q4 * 4 + 2] = v.z; row[q4 * 4 + 3] = v.w;
        }
        uint32_t p32[16];
        ushort us[32];
        #pragma unroll
        for (int d = 0; d < 32; ++d)
            us[d] = __bfloat16_as_ushort(__float2bfloat16(row[d]));
        #pragma unroll
        for (int i = 0; i < 16; ++i)
            p32[i] = (uint32_t)us[2 * i] | ((uint32_t)us[2 * i + 1] << 16);
        #pragma unroll
        for (int gi = 0; gi < 4; ++gi) {
            uint4 w;
            w.x = p32[gi * 4 + 0]; w.y = p32[gi * 4 + 1];
            w.z = p32[gi * 4 + 2]; w.w = p32[gi * 4 + 3];
            *reinterpret_cast<uint4*>(ldsK + l * 64 + ((gi ^ (l & 3)) << 4)) = w;
        }
        #pragma unroll
        for (int d = 0; d < 32; ++d)
            *reinterpret_cast<ushort*>(ldsVT + d * 1024 + ((l * 2) ^ ((d & 7) << 4))) = us[d];
    }
    __syncthreads();

    const int w = tid >> 6;
    const int lane = tid & 63;
    const int qcol = lane & 31;
    const int hh = lane >> 5;
    const float r1 = rate1p[0];

    #pragma unroll 1
    for (int qt = 0; qt < 2; ++qt) {
        const int q0 = (w * 2 + qt) * 32;
        const int qrow = q0 + qcol;
        const int nq = hor ? (g * 512 + qrow) : ((qrow & 63) * 64 + g * 8 + (qrow >> 6));

        short8 qb[2];
        #pragma unroll
        for (int t = 0; t < 2; ++t) {
            const float* qp = &qv[(size_t)(b * Nn + nq) * QKVC + qoff + t * 16 + hh * 8];
            float4 f0 = *reinterpret_cast<const float4*>(&qp[0]);
            float4 f1 = *reinterpret_cast<const float4*>(&qp[4]);
            union { uint32_t u[4]; short8 s; } qa;
            qa.u[0] = pkbf(f0.x * QS, f0.y * QS);
            qa.u[1] = pkbf(f0.z * QS, f0.w * QS);
            qa.u[2] = pkbf(f1.x * QS, f1.y * QS);
            qa.u[3] = pkbf(f1.z * QS, f1.w * QS);
            qb[t] = qa.s;
        }

        f32x16 acc = {0,0,0,0,0,0,0,0,0,0,0,0,0,0,0,0};
        float rs = 0.f;

        for (int s = 0; s < 16; ++s) {
            const int k0 = s * 32;
            const int kr = k0 + qcol;
            const short8 a0 = *reinterpret_cast<const short8*>(
                ldsK + kr * 64 + (((0 + hh) ^ (kr & 3)) << 4));
            const short8 a1 = *reinterpret_cast<const short8*>(
                ldsK + kr * 64 + (((2 + hh) ^ (kr & 3)) << 4));
            f32x16 st = {0,0,0,0,0,0,0,0,0,0,0,0,0,0,0,0};
            st = __builtin_amdgcn_mfma_f32_32x32x16_bf16(a0, qb[0], st, 0, 0, 0);
            st = __builtin_amdgcn_mfma_f32_32x32x16_bf16(a1, qb[1], st, 0, 0, 0);

            float p[16];
            #pragma unroll
            for (int r = 0; r < 16; ++r) p[r] = exp2f(st[r]);
            float s01 = (p[0] + p[1]) + (p[2] + p[3]);
            float s23 = (p[4] + p[5]) + (p[6] + p[7]);
            float s45 = (p[8] + p[9]) + (p[10] + p[11]);
            float s67 = (p[12] + p[13]) + (p[14] + p[15]);
            rs += (s01 + s23) + (s45 + s67);

            uint32_t X[8];
            #pragma unroll
            for (int gg = 0; gg < 4; ++gg) {
                X[2 * gg + 0] = pkbf(p[4 * gg + 0], p[4 * gg + 1]);
                X[2 * gg + 1] = pkbf(p[4 * gg + 2], p[4 * gg + 3]);
            }
            #pragma unroll
            for (int u = 0; u < 2; ++u) {
                uint32_t w0 = X[4 * u + 0], w2 = X[4 * u + 2];
                uint32_t w1 = X[4 * u + 1], w3 = X[4 * u + 3];
                plswap(w0, w2);
                plswap(w1, w3);
                union { uint32_t u4[4]; short8 s; } pf;
                pf.u4[0] = w0; pf.u4[1] = w1; pf.u4[2] = w2; pf.u4[3] = w3;
                const int d = qcol;
                const short8 vf = *reinterpret_cast<const short8*>(
                    ldsVT + d * 1024 + ((k0 * 2 + u * 32 + hh * 16) ^ ((d & 7) << 4)));
                acc = __builtin_amdgcn_mfma_f32_32x32x16_bf16(vf, pf.s, acc, 0, 0, 0);
            }
        }

        float rsf = rs + __shfl_xor(rs, 32);
        float scl = r1 / rsf;
        float* ap = &Abuf[(size_t)(b * Nn + nq) * DIMc + qoff];
        #pragma unroll
        for (int gg = 0; gg < 4; ++gg) {
            int d0 = 8 * gg + 4 * hh;
            float4 o = *reinterpret_cast<float4*>(&ap[d0]);
            o.x += acc[4 * gg + 0] * scl;
            o.y += acc[4 * gg + 1] * scl;
            o.z += acc[4 * gg + 2] * scl;
            o.w += acc[4 * gg + 3] * scl;
            *reinterpret_cast<float4*>(&ap[d0]) = o;
        }
    }
}

// ---------------- BatchNorm stats (sum, sumsq per channel) ----------------
__global__ __launch_bounds__(256) void bnstats_kernel(
    const float* __restrict__ Y, float* __restrict__ stats)
{
    int c = threadIdx.x;
    int rows = Mrows / gridDim.x;
    int r0 = blockIdx.x * rows;
    float s = 0.f, s2 = 0.f;
    for (int r = r0; r < r0 + rows; ++r) {
        float v = Y[(size_t)r * DIMc + c];
        s += v; s2 += v * v;
    }
    atomicAdd(&stats[c], s);
    atomicAdd(&stats[256 + c], s2);
}

// ---------------- BatchNorm normalize ----------------
__global__ __launch_bounds__(256) void bnnorm_kernel(
    const float* __restrict__ Y, const float* __restrict__ stats,
    const float* __restrict__ g, const float* __restrict__ bta,
    float* __restrict__ out)
{
    int idx = blockIdx.x * 256 + threadIdx.x;
    int c = idx & 255;
    float mu = stats[c] * (1.f / (float)Mrows);
    float var = stats[256 + c] * (1.f / (float)Mrows) - mu * mu;
    float inv = rsqrtf(var + 1e-5f);
    out[idx] = (Y[idx] - mu) * inv * g[c] + bta[c];
}

// ---------------- launch ----------------
extern "C" void kernel_launch(void* const* d_in, const int* in_sizes, int n_in,
                              void* d_out, int out_size, void* d_ws, size_t ws_size,
                              hipStream_t stream)
{
    const float* x      = (const float*)d_in[0];
    const float* w_qkv  = (const float*)d_in[1];
    const float* b_qkv  = (const float*)d_in[2];
    const float* w_out  = (const float*)d_in[3];
    const float* b_out  = (const float*)d_in[4];
    const float* bn_g   = (const float*)d_in[5];
    const float* bn_b   = (const float*)d_in[6];
    const float* pconv_w = (const float*)d_in[7];
    const float* pconv_b = (const float*)d_in[8];
    const float* fc_w   = (const float*)d_in[9];
    const float* dep_w  = (const float*)d_in[10];
    const float* dep_b  = (const float*)d_in[11];
    const float* rate1  = (const float*)d_in[12];
    const float* rate2  = (const float*)d_in[13];
    float* out = (float*)d_out;

    char* ws = (char*)d_ws;
    float*  qv    = (float*)(ws);                            // 64 MB [0,64M)
    float*  Abuf  = (float*)(ws + (64u << 20));              // 32 MB
    float*  Ybuf  = (float*)(ws + (96u << 20));              // 32 MB
    float*  stats = (float*)(ws + (128u << 20));             // 2 KB
    ushort* xb    = (ushort*)(ws + (64u << 20));             // 16 MB, aliases Abuf (dead before vconv)
    ushort* Hb    = (ushort*)(ws);                           // 16 MB, aliases qv (dead after attn)
    ushort* Wt1   = (ushort*)(ws + (128u << 20) + 4096);     // 256 KB
    ushort* Wt2   = (ushort*)(ws + (128u << 20) + 4096 + (256u << 10)); // 128 KB
    float*  Weff  = (float*)(ws + (128u << 20) + 4096 + (384u << 10));  // 74 KB

    // 0. precision prep + composed conv weights
    wtconv_kernel<<<(512 * 256) / 256, 256, 0, stream>>>(w_qkv, Wt1, 256, 512);
    wtconv_kernel<<<(256 * 256) / 256, 256, 0, stream>>>(w_out, Wt2, 256, 256);
    weff_kernel<<<36, 256, 0, stream>>>(dep_w, fc_w, Weff);
    cvtbf_kernel<false><<<(Mrows * 256 / 8) / 256, 256, 0, stream>>>(x, xb);

    // 1. qv = x @ w_qkv + b_qkv   (bf16 MFMA)
    hgemm_kernel<<<dim3(4, 256), 256, 0, stream>>>(xb, Wt1, b_qkv, qv, Mrows, 512, 256);

    // 2. A = depthwise3x3(hard_swish(v)) + pconv_b
    vconv_kernel<<<(Mrows * 256) / 256, 256, 0, stream>>>(qv, pconv_w, pconv_b, Abuf);

    // 3. fused conv-attention branch (both branches, fc composed into weights)
    convbranch_kernel<<<2048, 256, 0, stream>>>(qv, Weff, dep_b, rate2, Abuf);

    // 4. MFMA window attention (A += rate1 * o)
    attn_mfma_kernel<<<512, 512, 0, stream>>>(qv, rate1, Abuf);

    // 5. Y = hard_swish(A) @ w_out + b_out   (bf16 MFMA; hswish in pre-pass)
    cvtbf_kernel<true><<<(Mrows * 256 / 8) / 256, 256, 0, stream>>>(Abuf, Hb);
    hgemm_kernel<<<dim3(2, 256), 256, 0, stream>>>(Hb, Wt2, b_out, Ybuf, Mrows, 256, 256);

    // 6. BatchNorm
    hipMemsetAsync(stats, 0, 2 * 256 * sizeof(float), stream);
    bnstats_kernel<<<256, 256, 0, stream>>>(Ybuf, stats);
    bnnorm_kernel<<<(Mrows * 256) / 256, 256, 0, stream>>>(Ybuf, stats, bn_g, bn_b, out);
}

// Round 6
// 265.150 us; speedup vs baseline: 7.7203x; 1.1556x over previous
//
#include <hip/hip_runtime.h>
#include <hip/hip_bf16.h>
#include <math.h>

// ---------------- problem constants (fixed instance) ----------------
constexpr int Bn   = 8;
constexpr int Hh   = 64;
constexpr int Ww   = 64;
constexpr int Nn   = Hh * Ww;      // 4096
constexpr int Mrows = Bn * Nn;     // 32768
constexpr int QKVC = 512;          // qv channels
constexpr int DIMc = 256;

typedef short short8 __attribute__((ext_vector_type(8)));
typedef float f32x16 __attribute__((ext_vector_type(16)));
typedef float f32x4 __attribute__((ext_vector_type(4)));

__device__ __forceinline__ float hswish(float x) {
    float r = fminf(fmaxf(x + 3.f, 0.f), 6.f);
    return x * r * (1.f / 6.f);
}

__device__ __forceinline__ ushort bf16u(float f) {
    return __bfloat16_as_ushort(__float2bfloat16(f));
}

__device__ __forceinline__ uint32_t pkbf(float a, float b) {
    return (uint32_t)bf16u(a) | ((uint32_t)bf16u(b) << 16);
}

__device__ __forceinline__ float bflo(uint32_t p) {
    union { uint32_t u; float f; } c; c.u = p << 16; return c.f;
}
__device__ __forceinline__ float bfhi(uint32_t p) {
    union { uint32_t u; float f; } c; c.u = p & 0xFFFF0000u; return c.f;
}

#if __has_builtin(__builtin_amdgcn_permlane32_swap)
typedef int int2v __attribute__((ext_vector_type(2)));
__device__ __forceinline__ void plswap(uint32_t& a, uint32_t& b) {
    int2v r = __builtin_amdgcn_permlane32_swap((int)a, (int)b, false, false);
    a = (uint32_t)r.x; b = (uint32_t)r.y;
}
#else
__device__ __forceinline__ void plswap(uint32_t& a, uint32_t& b) {
    int l = threadIdx.x & 63;
    uint32_t sa = (uint32_t)__shfl_xor((int)a, 32);
    uint32_t sb = (uint32_t)__shfl_xor((int)b, 32);
    uint32_t na = (l < 32) ? a : sb;
    uint32_t nb = (l < 32) ? sa : b;
    a = na; b = nb;
}
#endif

__device__ __forceinline__ void gload_lds16(const ushort* g, ushort* l) {
    __builtin_amdgcn_global_load_lds(
        (const __attribute__((address_space(1))) unsigned int*)g,
        (__attribute__((address_space(3))) unsigned int*)l, 16, 0, 0);
}

// ---------------- bf16 convert: xb = bf16(x) ----------------
__global__ __launch_bounds__(256) void cvtbf_kernel(
    const float* __restrict__ in, ushort* __restrict__ out)
{
    int i = (blockIdx.x * 256 + threadIdx.x) * 8;
    float4 f0 = *reinterpret_cast<const float4*>(&in[i]);
    float4 f1 = *reinterpret_cast<const float4*>(&in[i + 4]);
    float v[8] = {f0.x, f0.y, f0.z, f0.w, f1.x, f1.y, f1.z, f1.w};
    ushort o[8];
    #pragma unroll
    for (int j = 0; j < 8; ++j) o[j] = bf16u(v[j]);
    *reinterpret_cast<short8*>(&out[i]) = *reinterpret_cast<short8*>(o);
}

// ---------------- weight transpose + bf16 convert: Wt[n][k] = bf16(W[k][n]) ----------------
__global__ __launch_bounds__(256) void wtconv_kernel(
    const float* __restrict__ Wf, ushort* __restrict__ Wt, int K, int N)
{
    int idx = blockIdx.x * 256 + threadIdx.x;   // k fast
    int n = idx / K, k = idx - n * K;
    Wt[idx] = bf16u(Wf[(size_t)k * N + n]);
}

// ---------------- effective conv weights: compose fc (24->9) with dep 3x3 ----------------
__global__ __launch_bounds__(256) void weff_kernel(
    const float* __restrict__ dw, const float* __restrict__ fcw,
    float* __restrict__ Weff)
{
    int idx = blockIdx.x * 256 + threadIdx.x;   // 16*8*8*9 = 9216
    if (idx >= 9216) return;
    int k = idx % 9;
    int a = (idx / 9) & 7;
    int oc = (idx / 72) & 7;
    int gi = idx / 576;
    float q = 0.f, v = 0.f;
    const float* dwp = &dw[(gi * 8 + oc) * 81 + k];
    #pragma unroll
    for (int ic = 0; ic < 9; ++ic) {
        float d = dwp[ic * 9];
        q += d * fcw[ic * 24 + a];
        v += d * (fcw[ic * 24 + 8 + a] + fcw[ic * 24 + 16 + a]);
    }
    Weff[idx * 2]     = q;
    Weff[idx * 2 + 1] = v;
}

// ---------------- bf16 MFMA GEMM: C = A[M,K] @ Bt[N,K]^T + bias ----------------
// OBF: write bf16 output; STATS: accumulate per-column sum/sumsq into stats.
template<bool OBF, bool STATS>
__global__ __launch_bounds__(256) void hgemm_kernel(
    const ushort* __restrict__ A, const ushort* __restrict__ Bt,
    const float* __restrict__ bias, void* __restrict__ Cv,
    float* __restrict__ stats, int M, int N, int K)
{
    __shared__ ushort As[128 * 32];
    __shared__ ushort Bs[128 * 32];
    const int tid = threadIdx.x;
    const int w = tid >> 6, l = tid & 63;
    const int brow = blockIdx.y * 128;
    const int bcol = blockIdx.x * 128;
    const int wm = (w >> 1) * 64, wn = (w & 1) * 64;

    f32x4 acc[4][4] = {};

    const int c0 = tid, c1 = tid + 256;
    const int r0 = c0 >> 2, q0 = (c0 & 3) ^ (r0 & 3);
    const int r1 = c1 >> 2, q1 = (c1 & 3) ^ (r1 & 3);
    const ushort* a0p = &A[(size_t)(brow + r0) * K + q0 * 8];
    const ushort* a1p = &A[(size_t)(brow + r1) * K + q1 * 8];
    const ushort* b0p = &Bt[(size_t)(bcol + r0) * K + q0 * 8];
    const ushort* b1p = &Bt[(size_t)(bcol + r1) * K + q1 * 8];
    ushort* asw0 = &As[(w * 64) * 8];
    ushort* asw1 = &As[(256 + w * 64) * 8];
    ushort* bsw0 = &Bs[(w * 64) * 8];
    ushort* bsw1 = &Bs[(256 + w * 64) * 8];

    const int fr = l & 15;
    const int qq = ((l >> 4) ^ (l & 3)) * 8;

    for (int k0 = 0; k0 < K; k0 += 32) {
        gload_lds16(a0p + k0, asw0);
        gload_lds16(a1p + k0, asw1);
        gload_lds16(b0p + k0, bsw0);
        gload_lds16(b1p + k0, bsw1);
        __syncthreads();
        short8 af[4], bf[4];
        #pragma unroll
        for (int i = 0; i < 4; ++i) {
            af[i] = *reinterpret_cast<const short8*>(&As[(wm + i * 16 + fr) * 32 + qq]);
            bf[i] = *reinterpret_cast<const short8*>(&Bs[(wn + i * 16 + fr) * 32 + qq]);
        }
        #pragma unroll
        for (int mi = 0; mi < 4; ++mi)
            #pragma unroll
            for (int ni = 0; ni < 4; ++ni)
                acc[mi][ni] = __builtin_amdgcn_mfma_f32_16x16x32_bf16(
                    af[mi], bf[ni], acc[mi][ni], 0, 0, 0);
        __syncthreads();
    }

    const int cr = l >> 4;
    #pragma unroll
    for (int ni = 0; ni < 4; ++ni) {
        int n = bcol + wn + ni * 16 + fr;
        float bv = bias[n];
        float s1 = 0.f, s2 = 0.f;
        #pragma unroll
        for (int mi = 0; mi < 4; ++mi) {
            int m = brow + wm + mi * 16 + cr * 4;
            #pragma unroll
            for (int r = 0; r < 4; ++r) {
                float val = acc[mi][ni][r] + bv;
                if (OBF)
                    ((ushort*)Cv)[(size_t)(m + r) * N + n] = bf16u(val);
                else
                    ((float*)Cv)[(size_t)(m + r) * N + n] = val;
                if (STATS) { s1 += val; s2 += val * val; }
            }
        }
        if (STATS) {
            s1 += __shfl_xor(s1, 16); s2 += __shfl_xor(s2, 16);
            s1 += __shfl_xor(s1, 32); s2 += __shfl_xor(s2, 32);
            if (cr == 0) {
                atomicAdd(&stats[n], s1);
                atomicAdd(&stats[256 + n], s2);
            }
        }
    }
}

// ---------------- depthwise 3x3 on hard_swish(v): A = v_conv (bf16 in, 2 ch/thread) ----------------
__global__ __launch_bounds__(256) void vconv_kernel(
    const ushort* __restrict__ qvb, const float* __restrict__ pw,
    const float* __restrict__ pb, float* __restrict__ Abuf)
{
    int idx = blockIdx.x * 256 + threadIdx.x;   // Mrows*128
    int c2 = idx & 127;
    int n = (idx >> 7) & (Nn - 1);
    int b = idx >> 19;
    int x = n & 63, y = n >> 6;
    int ch = c2 * 2;
    float s0 = pb[ch], s1 = pb[ch + 1];
    float w0[9], w1[9];
    #pragma unroll
    for (int k = 0; k < 9; ++k) { w0[k] = pw[ch * 9 + k]; w1[k] = pw[ch * 9 + 9 + k]; }
    #pragma unroll
    for (int ky = 0; ky < 3; ++ky) {
        int yy = y + ky - 1;
        if (yy >= 0 && yy < Hh) {
            #pragma unroll
            for (int kx = 0; kx < 3; ++kx) {
                int xx = x + kx - 1;
                if (xx >= 0 && xx < Ww) {
                    uint32_t pk = *reinterpret_cast<const uint32_t*>(
                        &qvb[(size_t)(b * Nn + yy * Ww + xx) * QKVC + 256 + ch]);
                    s0 += hswish(bflo(pk)) * w0[ky * 3 + kx];
                    s1 += hswish(bfhi(pk)) * w1[ky * 3 + kx];
                }
            }
        }
    }
    float2 o; o.x = s0; o.y = s1;
    *reinterpret_cast<float2*>(&Abuf[(size_t)(b * Nn + n) * DIMc + ch]) = o;
}

// ---------------- fused conv-attention branch (fc + grouped 3x3, both branches) ----------------
// q|v packed per u32 in LDS; output transpose at stride 9 (conflict-free).
__global__ __launch_bounds__(256) void convbranch_kernel(
    const ushort* __restrict__ qvb, const float* __restrict__ Weff,
    const float* __restrict__ db, const float* __restrict__ rate2p,
    float* __restrict__ Abuf)
{
    int blk = blockIdx.x;              // 2048
    int ytile = blk & 7;
    int gi = (blk >> 3) & 15;
    int b = (blk >> 7) & 7;
    int branch = blk >> 10;
    int y0 = ytile * 8;
    int qoff = branch * 128;
    int coff = branch * 128;

    __shared__ uint32_t sqv[8][10][66];   // 21.1 KB, q lo | v hi
    __shared__ float wqv[8][8][9][2];     // 4.6 KB
    const int tid = threadIdx.x;

    for (int i = tid; i < 8 * 10 * 66; i += 256) {
        int xp = i % 66;
        int rr = (i / 66) % 10;
        int a = i / 660;
        int x = xp - 1;
        int y = y0 + rr - 1;
        uint32_t pk = 0;
        if (x >= 0 && x < 64 && y >= 0 && y < 64) {
            int token = (a * 16 + gi) * 32 + (y >> 1);
            int chan = (y & 1) * 64 + x;
            const ushort* p = &qvb[(size_t)(b * Nn + token) * QKVC + qoff + chan];
            pk = (uint32_t)p[0] | ((uint32_t)p[256] << 16);
        }
        sqv[a][rr][xp] = pk;
    }
    const float* wsrc = &Weff[gi * 1152];
    for (int i = tid; i < 1152; i += 256)
        ((float*)wqv)[i] = wsrc[i];
    __syncthreads();

    const int x = tid & 63;
    const int oc0 = (tid >> 6) * 2;    // wave-uniform

    float acc[2][8] = {};
    #pragma unroll 1
    for (int a = 0; a < 8; ++a) {
        float iq[10][3], iv[10][3];
        #pragma unroll
        for (int rr = 0; rr < 10; ++rr)
            #pragma unroll
            for (int c = 0; c < 3; ++c) {
                uint32_t pk = sqv[a][rr][x + c];
                iq[rr][c] = bflo(pk);
                iv[rr][c] = bfhi(pk);
            }
        #pragma unroll
        for (int ocl = 0; ocl < 2; ++ocl) {
            #pragma unroll
            for (int ky = 0; ky < 3; ++ky)
                #pragma unroll
                for (int kx = 0; kx < 3; ++kx) {
                    float2 w = *reinterpret_cast<const float2*>(
                        &wqv[oc0 + ocl][a][ky * 3 + kx][0]);
                    #pragma unroll
                    for (int row = 0; row < 8; ++row)
                        acc[ocl][row] += w.x * iq[row + ky][kx]
                                       + w.y * iv[row + ky][kx];
                }
        }
    }

    __syncthreads();
    float* so = (float*)sqv;           // 512 px * stride 9 = 18.4 KB
    const float r2 = rate2p[0];
    float d0 = db[gi * 8 + oc0], d1 = db[gi * 8 + oc0 + 1];
    #pragma unroll
    for (int row = 0; row < 8; ++row) {
        int base = (row * 64 + x) * 9;
        so[base + oc0]     = r2 * (acc[0][row] + d0);
        so[base + oc0 + 1] = r2 * (acc[1][row] + d1);
    }
    __syncthreads();
    for (int i = tid; i < 4096; i += 256) {
        int px = i >> 3, sl = i & 7;
        int n = (y0 + (px >> 6)) * 64 + (px & 63);
        float* ap = &Abuf[(size_t)(b * Nn + n) * DIMc + coff + gi * 8 + sl];
        *ap += so[px * 9 + sl];
    }
}

// ---------------- MFMA cross-shaped window attention (k == v, bf16 input) ----------------
// Epilogue fused: Hb = bf16(hswish(Abuf + rate1 * o))  (attn is last writer of each slice)
__global__ __launch_bounds__(512) void attn_mfma_kernel(
    const ushort* __restrict__ qvb, const float* __restrict__ rate1p,
    const float* __restrict__ Abuf, ushort* __restrict__ Hb)
{
    int bid = blockIdx.x;
    bool hor = bid < 256;
    int lb = bid & 255;
    int hd = lb & 3;
    int g = (lb >> 2) & 7;
    int b = lb >> 5;
    int half = hor ? 0 : 128;
    int qoff = half + hd * 32;
    int kvoff = 256 + qoff;

    __shared__ __align__(16) char smem[65536];
    char* ldsK  = smem;            // 32 KB
    char* ldsVT = smem + 32768;    // 32 KB

    const int tid = threadIdx.x;
    const float QS = 0.17677669529663687f * 1.44269504088896f;  // scale * log2(e)

    {
        int l = tid;
        int n = hor ? (g * 512 + l) : ((l & 63) * 64 + g * 8 + (l >> 6));
        const ushort* kp = &qvb[(size_t)(b * Nn + n) * QKVC + kvoff];
        uint4 wv[4];
        #pragma unroll
        for (int j = 0; j < 4; ++j)
            wv[j] = *reinterpret_cast<const uint4*>(&kp[j * 8]);
        uint32_t p32[16];
        #pragma unroll
        for (int j = 0; j < 4; ++j) {
            p32[j * 4 + 0] = wv[j].x; p32[j * 4 + 1] = wv[j].y;
            p32[j * 4 + 2] = wv[j].z; p32[j * 4 + 3] = wv[j].w;
        }
        #pragma unroll
        for (int gi = 0; gi < 4; ++gi) {
            uint4 w;
            w.x = p32[gi * 4 + 0]; w.y = p32[gi * 4 + 1];
            w.z = p32[gi * 4 + 2]; w.w = p32[gi * 4 + 3];
            *reinterpret_cast<uint4*>(ldsK + l * 64 + ((gi ^ (l & 3)) << 4)) = w;
        }
        #pragma unroll
        for (int d = 0; d < 32; ++d) {
            ushort us = (ushort)((p32[d >> 1] >> ((d & 1) * 16)) & 0xffff);
            *reinterpret_cast<ushort*>(ldsVT + d * 1024 + ((l * 2) ^ ((d & 7) << 4))) = us;
        }
    }
    __syncthreads();

    const int w = tid >> 6;
    const int lane = tid & 63;
    const int qcol = lane & 31;
    const int hh = lane >> 5;
    const float r1 = rate1p[0];

    #pragma unroll 1
    for (int qt = 0; qt < 2; ++qt) {
        const int q0 = (w * 2 + qt) * 32;
        const int qrow = q0 + qcol;
        const int nq = hor ? (g * 512 + qrow) : ((qrow & 63) * 64 + g * 8 + (qrow >> 6));

        short8 qb[2];
        #pragma unroll
        for (int t = 0; t < 2; ++t) {
            const ushort* qp = &qvb[(size_t)(b * Nn + nq) * QKVC + qoff + t * 16 + hh * 8];
            qb[t] = *reinterpret_cast<const short8*>(qp);
        }

        f32x16 acc = {0,0,0,0,0,0,0,0,0,0,0,0,0,0,0,0};
        float rs = 0.f;

        for (int s = 0; s < 16; ++s) {
            const int k0 = s * 32;
            const int kr = k0 + qcol;
            const short8 a0 = *reinterpret_cast<const short8*>(
                ldsK + kr * 64 + (((0 + hh) ^ (kr & 3)) << 4));
            const short8 a1 = *reinterpret_cast<const short8*>(
                ldsK + kr * 64 + (((2 + hh) ^ (kr & 3)) << 4));
            f32x16 st = {0,0,0,0,0,0,0,0,0,0,0,0,0,0,0,0};
            st = __builtin_amdgcn_mfma_f32_32x32x16_bf16(a0, qb[0], st, 0, 0, 0);
            st = __builtin_amdgcn_mfma_f32_32x32x16_bf16(a1, qb[1], st, 0, 0, 0);

            float p[16];
            #pragma unroll
            for (int r = 0; r < 16; ++r) p[r] = exp2f(st[r] * QS);
            float s01 = (p[0] + p[1]) + (p[2] + p[3]);
            float s23 = (p[4] + p[5]) + (p[6] + p[7]);
            float s45 = (p[8] + p[9]) + (p[10] + p[11]);
            float s67 = (p[12] + p[13]) + (p[14] + p[15]);
            rs += (s01 + s23) + (s45 + s67);

            uint32_t X[8];
            #pragma unroll
            for (int gg = 0; gg < 4; ++gg) {
                X[2 * gg + 0] = pkbf(p[4 * gg + 0], p[4 * gg + 1]);
                X[2 * gg + 1] = pkbf(p[4 * gg + 2], p[4 * gg + 3]);
            }
            #pragma unroll
            for (int u = 0; u < 2; ++u) {
                uint32_t w0 = X[4 * u + 0], w2 = X[4 * u + 2];
                uint32_t w1 = X[4 * u + 1], w3 = X[4 * u + 3];
                plswap(w0, w2);
                plswap(w1, w3);
                union { uint32_t u4[4]; short8 s; } pf;
                pf.u4[0] = w0; pf.u4[1] = w1; pf.u4[2] = w2; pf.u4[3] = w3;
                const int d = qcol;
                const short8 vf = *reinterpret_cast<const short8*>(
                    ldsVT + d * 1024 + ((k0 * 2 + u * 32 + hh * 16) ^ ((d & 7) << 4)));
                acc = __builtin_amdgcn_mfma_f32_32x32x16_bf16(vf, pf.s, acc, 0, 0, 0);
            }
        }

        float rsf = rs + __shfl_xor(rs, 32);
        float scl = r1 / rsf;
        const float* ap = &Abuf[(size_t)(b * Nn + nq) * DIMc + qoff];
        ushort* hp = &Hb[(size_t)(b * Nn + nq) * DIMc + qoff];
        #pragma unroll
        for (int gg = 0; gg < 4; ++gg) {
            int d0 = 8 * gg + 4 * hh;
            float4 o = *reinterpret_cast<const float4*>(&ap[d0]);
            float v0 = hswish(o.x + acc[4 * gg + 0] * scl);
            float v1 = hswish(o.y + acc[4 * gg + 1] * scl);
            float v2 = hswish(o.z + acc[4 * gg + 2] * scl);
            float v3 = hswish(o.w + acc[4 * gg + 3] * scl);
            uint2 pk; pk.x = pkbf(v0, v1); pk.y = pkbf(v2, v3);
            *reinterpret_cast<uint2*>(&hp[d0]) = pk;
        }
    }
}

// ---------------- BatchNorm normalize ----------------
__global__ __launch_bounds__(256) void bnnorm_kernel(
    const float* __restrict__ Y, const float* __restrict__ stats,
    const float* __restrict__ g, const float* __restrict__ bta,
    float* __restrict__ out)
{
    int idx = blockIdx.x * 256 + threadIdx.x;
    int c = idx & 255;
    float mu = stats[c] * (1.f / (float)Mrows);
    float var = stats[256 + c] * (1.f / (float)Mrows) - mu * mu;
    float inv = rsqrtf(var + 1e-5f);
    out[idx] = (Y[idx] - mu) * inv * g[c] + bta[c];
}

// ---------------- launch ----------------
extern "C" void kernel_launch(void* const* d_in, const int* in_sizes, int n_in,
                              void* d_out, int out_size, void* d_ws, size_t ws_size,
                              hipStream_t stream)
{
    const float* x      = (const float*)d_in[0];
    const float* w_qkv  = (const float*)d_in[1];
    const float* b_qkv  = (const float*)d_in[2];
    const float* w_out  = (const float*)d_in[3];
    const float* b_out  = (const float*)d_in[4];
    const float* bn_g   = (const float*)d_in[5];
    const float* bn_b   = (const float*)d_in[6];
    const float* pconv_w = (const float*)d_in[7];
    const float* pconv_b = (const float*)d_in[8];
    const float* fc_w   = (const float*)d_in[9];
    const float* dep_w  = (const float*)d_in[10];
    const float* dep_b  = (const float*)d_in[11];
    const float* rate1  = (const float*)d_in[12];
    const float* rate2  = (const float*)d_in[13];
    float* out = (float*)d_out;

    char* ws = (char*)d_ws;
    ushort* qvb   = (ushort*)(ws);                           // 32 MB [0,32M)
    ushort* Hb    = (ushort*)(ws + (32u << 20));             // 16 MB [32M,48M)
    ushort* xb    = (ushort*)(ws + (64u << 20));             // 16 MB, aliases Abuf head
    float*  Abuf  = (float*)(ws + (64u << 20));              // 32 MB [64M,96M)
    float*  Ybuf  = (float*)(ws + (96u << 20));              // 32 MB [96M,128M)
    float*  stats = (float*)(ws + (128u << 20));             // 2 KB
    ushort* Wt1   = (ushort*)(ws + (128u << 20) + 4096);     // 256 KB
    ushort* Wt2   = (ushort*)(ws + (128u << 20) + 4096 + (256u << 10)); // 128 KB
    float*  Weff  = (float*)(ws + (128u << 20) + 4096 + (384u << 10));  // 74 KB

    // 0. prep: bf16 weights (transposed), composed conv weights, bf16 x
    wtconv_kernel<<<(512 * 256) / 256, 256, 0, stream>>>(w_qkv, Wt1, 256, 512);
    wtconv_kernel<<<(256 * 256) / 256, 256, 0, stream>>>(w_out, Wt2, 256, 256);
    weff_kernel<<<36, 256, 0, stream>>>(dep_w, fc_w, Weff);
    cvtbf_kernel<<<(Mrows * 256 / 8) / 256, 256, 0, stream>>>(x, xb);

    // 1. qvb = bf16(x @ w_qkv + b_qkv)
    hgemm_kernel<true, false><<<dim3(4, 256), 256, 0, stream>>>(
        xb, Wt1, b_qkv, qvb, nullptr, Mrows, 512, 256);

    // 2. A = depthwise3x3(hard_swish(v)) + pconv_b
    vconv_kernel<<<(Mrows * 128) / 256, 256, 0, stream>>>(qvb, pconv_w, pconv_b, Abuf);

    // 3. fused conv-attention branch (A += rate2 * out_conv, both branches)
    convbranch_kernel<<<2048, 256, 0, stream>>>(qvb, Weff, dep_b, rate2, Abuf);

    // 4. MFMA window attention; epilogue writes Hb = bf16(hswish(A + rate1*o))
    attn_mfma_kernel<<<512, 512, 0, stream>>>(qvb, rate1, Abuf, Hb);

    // 5. Y = Hb @ w_out + b_out, with fused BN stats
    hipMemsetAsync(stats, 0, 2 * 256 * sizeof(float), stream);
    hgemm_kernel<false, true><<<dim3(2, 256), 256, 0, stream>>>(
        Hb, Wt2, b_out, Ybuf, stats, Mrows, 256, 256);

    // 6. BatchNorm normalize
    bnnorm_kernel<<<(Mrows * 256) / 256, 256, 0, stream>>>(Ybuf, stats, bn_g, bn_b, out);
}

// Round 7
// 231.516 us; speedup vs baseline: 8.8419x; 1.1453x over previous
//
#include <hip/hip_runtime.h>
#include <hip/hip_bf16.h>
#include <math.h>

// ---------------- problem constants (fixed instance) ----------------
constexpr int Bn   = 8;
constexpr int Hh   = 64;
constexpr int Ww   = 64;
constexpr int Nn   = Hh * Ww;      // 4096
constexpr int Mrows = Bn * Nn;     // 32768
constexpr int QKVC = 512;          // qv channels
constexpr int DIMc = 256;

typedef short short8 __attribute__((ext_vector_type(8)));
typedef float f32x16 __attribute__((ext_vector_type(16)));
typedef float f32x4 __attribute__((ext_vector_type(4)));

__device__ __forceinline__ float hswish(float x) {
    float r = fminf(fmaxf(x + 3.f, 0.f), 6.f);
    return x * r * (1.f / 6.f);
}

__device__ __forceinline__ ushort bf16u(float f) {
    return __bfloat16_as_ushort(__float2bfloat16(f));
}

__device__ __forceinline__ uint32_t pkbf(float a, float b) {
    return (uint32_t)bf16u(a) | ((uint32_t)bf16u(b) << 16);
}

// packed bf16 dot2: c += a.lo*b.lo + a.hi*b.hi   (v_dot2_f32_bf16, CDNA3/4)
__device__ __forceinline__ float dot2bf(uint32_t a, uint32_t b, float c) {
    asm("v_dot2_f32_bf16 %0, %1, %2, %0" : "+v"(c) : "v"(a), "v"(b));
    return c;
}

__device__ __forceinline__ float bflo(uint32_t p) {
    union { uint32_t u; float f; } c; c.u = p << 16; return c.f;
}
__device__ __forceinline__ float bfhi(uint32_t p) {
    union { uint32_t u; float f; } c; c.u = p & 0xFFFF0000u; return c.f;
}

#if __has_builtin(__builtin_amdgcn_permlane32_swap)
typedef int int2v __attribute__((ext_vector_type(2)));
__device__ __forceinline__ void plswap(uint32_t& a, uint32_t& b) {
    int2v r = __builtin_amdgcn_permlane32_swap((int)a, (int)b, false, false);
    a = (uint32_t)r.x; b = (uint32_t)r.y;
}
#else
__device__ __forceinline__ void plswap(uint32_t& a, uint32_t& b) {
    int l = threadIdx.x & 63;
    uint32_t sa = (uint32_t)__shfl_xor((int)a, 32);
    uint32_t sb = (uint32_t)__shfl_xor((int)b, 32);
    uint32_t na = (l < 32) ? a : sb;
    uint32_t nb = (l < 32) ? sa : b;
    a = na; b = nb;
}
#endif

__device__ __forceinline__ void gload_lds16(const ushort* g, ushort* l) {
    __builtin_amdgcn_global_load_lds(
        (const __attribute__((address_space(1))) unsigned int*)g,
        (__attribute__((address_space(3))) unsigned int*)l, 16, 0, 0);
}

// ---------------- bf16 convert: xb = bf16(x) ----------------
__global__ __launch_bounds__(256) void cvtbf_kernel(
    const float* __restrict__ in, ushort* __restrict__ out)
{
    int i = (blockIdx.x * 256 + threadIdx.x) * 8;
    float4 f0 = *reinterpret_cast<const float4*>(&in[i]);
    float4 f1 = *reinterpret_cast<const float4*>(&in[i + 4]);
    float v[8] = {f0.x, f0.y, f0.z, f0.w, f1.x, f1.y, f1.z, f1.w};
    ushort o[8];
    #pragma unroll
    for (int j = 0; j < 8; ++j) o[j] = bf16u(v[j]);
    *reinterpret_cast<short8*>(&out[i]) = *reinterpret_cast<short8*>(o);
}

// ---------------- weight transpose + bf16 convert: Wt[n][k] = bf16(W[k][n]) ----------------
__global__ __launch_bounds__(256) void wtconv_kernel(
    const float* __restrict__ Wf, ushort* __restrict__ Wt, int K, int N)
{
    int idx = blockIdx.x * 256 + threadIdx.x;   // k fast
    int n = idx / K, k = idx - n * K;
    Wt[idx] = bf16u(Wf[(size_t)k * N + n]);
}

// ---------------- effective conv weights, packed bf16 (q|v) ----------------
// Wp[((gi*8+oc)*8+a)*9+k] = pack(q,v):
//   q = sum_ic dw[oc][ic][k]*fcw[ic][a],  v = sum_ic dw[oc][ic][k]*(fcw[ic][8+a]+fcw[ic][16+a])
__global__ __launch_bounds__(256) void weff_kernel(
    const float* __restrict__ dw, const float* __restrict__ fcw,
    uint32_t* __restrict__ Wp)
{
    int idx = blockIdx.x * 256 + threadIdx.x;   // 9216
    if (idx >= 9216) return;
    int k = idx % 9;
    int a = (idx / 9) & 7;
    int oc = (idx / 72) & 7;
    int gi = idx / 576;
    float q = 0.f, v = 0.f;
    const float* dwp = &dw[(gi * 8 + oc) * 81 + k];
    #pragma unroll
    for (int ic = 0; ic < 9; ++ic) {
        float d = dwp[ic * 9];
        q += d * fcw[ic * 24 + a];
        v += d * (fcw[ic * 24 + 8 + a] + fcw[ic * 24 + 16 + a]);
    }
    Wp[idx] = pkbf(q, v);
}

// ---------------- bf16 MFMA GEMM: C = A[M,K] @ Bt[N,K]^T + bias ----------------
template<bool OBF, bool STATS>
__global__ __launch_bounds__(256) void hgemm_kernel(
    const ushort* __restrict__ A, const ushort* __restrict__ Bt,
    const float* __restrict__ bias, void* __restrict__ Cv,
    float* __restrict__ stats, int M, int N, int K)
{
    __shared__ ushort As[128 * 32];
    __shared__ ushort Bs[128 * 32];
    const int tid = threadIdx.x;
    const int w = tid >> 6, l = tid & 63;
    const int brow = blockIdx.y * 128;
    const int bcol = blockIdx.x * 128;
    const int wm = (w >> 1) * 64, wn = (w & 1) * 64;

    f32x4 acc[4][4] = {};

    const int c0 = tid, c1 = tid + 256;
    const int r0 = c0 >> 2, q0 = (c0 & 3) ^ (r0 & 3);
    const int r1 = c1 >> 2, q1 = (c1 & 3) ^ (r1 & 3);
    const ushort* a0p = &A[(size_t)(brow + r0) * K + q0 * 8];
    const ushort* a1p = &A[(size_t)(brow + r1) * K + q1 * 8];
    const ushort* b0p = &Bt[(size_t)(bcol + r0) * K + q0 * 8];
    const ushort* b1p = &Bt[(size_t)(bcol + r1) * K + q1 * 8];
    ushort* asw0 = &As[(w * 64) * 8];
    ushort* asw1 = &As[(256 + w * 64) * 8];
    ushort* bsw0 = &Bs[(w * 64) * 8];
    ushort* bsw1 = &Bs[(256 + w * 64) * 8];

    const int fr = l & 15;
    const int qq = ((l >> 4) ^ (l & 3)) * 8;

    for (int k0 = 0; k0 < K; k0 += 32) {
        gload_lds16(a0p + k0, asw0);
        gload_lds16(a1p + k0, asw1);
        gload_lds16(b0p + k0, bsw0);
        gload_lds16(b1p + k0, bsw1);
        __syncthreads();
        short8 af[4], bf[4];
        #pragma unroll
        for (int i = 0; i < 4; ++i) {
            af[i] = *reinterpret_cast<const short8*>(&As[(wm + i * 16 + fr) * 32 + qq]);
            bf[i] = *reinterpret_cast<const short8*>(&Bs[(wn + i * 16 + fr) * 32 + qq]);
        }
        #pragma unroll
        for (int mi = 0; mi < 4; ++mi)
            #pragma unroll
            for (int ni = 0; ni < 4; ++ni)
                acc[mi][ni] = __builtin_amdgcn_mfma_f32_16x16x32_bf16(
                    af[mi], bf[ni], acc[mi][ni], 0, 0, 0);
        __syncthreads();
    }

    const int cr = l >> 4;
    #pragma unroll
    for (int ni = 0; ni < 4; ++ni) {
        int n = bcol + wn + ni * 16 + fr;
        float bv = bias[n];
        float s1 = 0.f, s2 = 0.f;
        #pragma unroll
        for (int mi = 0; mi < 4; ++mi) {
            int m = brow + wm + mi * 16 + cr * 4;
            #pragma unroll
            for (int r = 0; r < 4; ++r) {
                float val = acc[mi][ni][r] + bv;
                if (OBF)
                    ((ushort*)Cv)[(size_t)(m + r) * N + n] = bf16u(val);
                else
                    ((float*)Cv)[(size_t)(m + r) * N + n] = val;
                if (STATS) { s1 += val; s2 += val * val; }
            }
        }
        if (STATS) {
            s1 += __shfl_xor(s1, 16); s2 += __shfl_xor(s2, 16);
            s1 += __shfl_xor(s1, 32); s2 += __shfl_xor(s2, 32);
            if (cr == 0) {
                atomicAdd(&stats[n], s1);
                atomicAdd(&stats[256 + n], s2);
            }
        }
    }
}

// ---------------- depthwise 3x3 on hard_swish(v): A = v_conv (bf16 in, 2 ch/thread) ----------------
__global__ __launch_bounds__(256) void vconv_kernel(
    const ushort* __restrict__ qvb, const float* __restrict__ pw,
    const float* __restrict__ pb, float* __restrict__ Abuf)
{
    int idx = blockIdx.x * 256 + threadIdx.x;   // Mrows*128
    int c2 = idx & 127;
    int n = (idx >> 7) & (Nn - 1);
    int b = idx >> 19;
    int x = n & 63, y = n >> 6;
    int ch = c2 * 2;
    float s0 = pb[ch], s1 = pb[ch + 1];
    float w0[9], w1[9];
    #pragma unroll
    for (int k = 0; k < 9; ++k) { w0[k] = pw[ch * 9 + k]; w1[k] = pw[ch * 9 + 9 + k]; }
    #pragma unroll
    for (int ky = 0; ky < 3; ++ky) {
        int yy = y + ky - 1;
        if (yy >= 0 && yy < Hh) {
            #pragma unroll
            for (int kx = 0; kx < 3; ++kx) {
                int xx = x + kx - 1;
                if (xx >= 0 && xx < Ww) {
                    uint32_t pk = *reinterpret_cast<const uint32_t*>(
                        &qvb[(size_t)(b * Nn + yy * Ww + xx) * QKVC + 256 + ch]);
                    s0 += hswish(bflo(pk)) * w0[ky * 3 + kx];
                    s1 += hswish(bfhi(pk)) * w1[ky * 3 + kx];
                }
            }
        }
    }
    float2 o; o.x = s0; o.y = s1;
    *reinterpret_cast<float2*>(&Abuf[(size_t)(b * Nn + n) * DIMc + ch]) = o;
}

// ---------------- fused conv-attention branch: packed-bf16 dot2 version ----------------
// 1024 blocks = (branch, b, gi, ytile16); 256 threads = 64x * 2rowhalf * 2ocquad.
// Each thread: 4 oc x 8 rows; inputs q|v packed u32 in LDS; weights packed bf16.
__global__ __launch_bounds__(256) void convbranch_kernel(
    const ushort* __restrict__ qvb, const uint32_t* __restrict__ Wp,
    const float* __restrict__ db, const float* __restrict__ rate2p,
    float* __restrict__ Abuf)
{
    int blk = blockIdx.x;              // 1024
    int ytile = blk & 3;
    int gi = (blk >> 2) & 15;
    int b = (blk >> 6) & 7;
    int branch = blk >> 9;
    int y0 = ytile * 16;
    int qoff = branch * 128;
    int coff = branch * 128;

    __shared__ uint32_t sqv[8][18][66];   // 38.0 KB, q lo | v hi
    __shared__ uint32_t wpk[8][8][9];     // 2.3 KB [oc][a][k]
    const int tid = threadIdx.x;

    for (int i = tid; i < 8 * 18 * 66; i += 256) {
        int xp = i % 66;
        int t2 = i / 66;
        int rr = t2 % 18;
        int a = t2 / 18;
        int x = xp - 1;
        int y = y0 + rr - 1;
        uint32_t pk = 0;
        if ((unsigned)x < 64u && (unsigned)y < 64u) {
            int token = (a * 16 + gi) * 32 + (y >> 1);
            int chan = (y & 1) * 64 + x;
            const ushort* p = &qvb[(size_t)(b * Nn + token) * QKVC + qoff + chan];
            pk = (uint32_t)p[0] | ((uint32_t)p[256] << 16);
        }
        sqv[a][rr][xp] = pk;
    }
    for (int i = tid; i < 576; i += 256)
        ((uint32_t*)wpk)[i] = Wp[gi * 576 + i];
    __syncthreads();

    const int x = tid & 63;
    const int w = tid >> 6;
    const int rh = (w & 1) * 8;        // row-half base within 16-row tile
    const int oc0 = (w >> 1) * 4;      // 4 oc per thread

    float acc[4][8] = {};
    #pragma unroll 1
    for (int a = 0; a < 8; ++a) {
        uint32_t ipk[10][3];
        #pragma unroll
        for (int rr = 0; rr < 10; ++rr) {
            const uint32_t* rp = &sqv[a][rh + rr][x];
            ipk[rr][0] = rp[0]; ipk[rr][1] = rp[1]; ipk[rr][2] = rp[2];
        }
        #pragma unroll
        for (int ocl = 0; ocl < 4; ++ocl) {
            #pragma unroll
            for (int ky = 0; ky < 3; ++ky)
                #pragma unroll
                for (int kx = 0; kx < 3; ++kx) {
                    uint32_t wv = wpk[oc0 + ocl][a][ky * 3 + kx];
                    #pragma unroll
                    for (int row = 0; row < 8; ++row)
                        acc[ocl][row] = dot2bf(ipk[row + ky][kx], wv, acc[ocl][row]);
                }
        }
    }

    // transpose through LDS (stride 9, conflict-free), then coalesced RMW
    __syncthreads();
    float* so = (float*)sqv;           // 1024 px * 9 = 36.9 KB (fits in sqv)
    const float r2 = rate2p[0];
    float dbv[4];
    #pragma unroll
    for (int j = 0; j < 4; ++j) dbv[j] = db[gi * 8 + oc0 + j];
    #pragma unroll
    for (int row = 0; row < 8; ++row) {
        int px = (rh + row) * 64 + x;
        #pragma unroll
        for (int j = 0; j < 4; ++j)
            so[px * 9 + oc0 + j] = r2 * (acc[j][row] + dbv[j]);
    }
    __syncthreads();
    for (int i = tid; i < 8192; i += 256) {
        int px = i >> 3, sl = i & 7;
        int n = (y0 + (px >> 6)) * 64 + (px & 63);
        Abuf[(size_t)(b * Nn + n) * DIMc + coff + gi * 8 + sl] += so[px * 9 + sl];
    }
}

// ---------------- MFMA cross-shaped window attention (k == v, bf16 input) ----------------
// Epilogue fused: Hb = bf16(hswish(Abuf + rate1 * o))
__global__ __launch_bounds__(512) void attn_mfma_kernel(
    const ushort* __restrict__ qvb, const float* __restrict__ rate1p,
    const float* __restrict__ Abuf, ushort* __restrict__ Hb)
{
    int bid = blockIdx.x;
    bool hor = bid < 256;
    int lb = bid & 255;
    int hd = lb & 3;
    int g = (lb >> 2) & 7;
    int b = lb >> 5;
    int half = hor ? 0 : 128;
    int qoff = half + hd * 32;
    int kvoff = 256 + qoff;

    __shared__ __align__(16) char smem[65536];
    char* ldsK  = smem;            // 32 KB
    char* ldsVT = smem + 32768;    // 32 KB

    const int tid = threadIdx.x;
    const float QS = 0.17677669529663687f * 1.44269504088896f;  // scale * log2(e)

    {
        int l = tid;
        int n = hor ? (g * 512 + l) : ((l & 63) * 64 + g * 8 + (l >> 6));
        const ushort* kp = &qvb[(size_t)(b * Nn + n) * QKVC + kvoff];
        uint4 wv[4];
        #pragma unroll
        for (int j = 0; j < 4; ++j)
            wv[j] = *reinterpret_cast<const uint4*>(&kp[j * 8]);
        uint32_t p32[16];
        #pragma unroll
        for (int j = 0; j < 4; ++j) {
            p32[j * 4 + 0] = wv[j].x; p32[j * 4 + 1] = wv[j].y;
            p32[j * 4 + 2] = wv[j].z; p32[j * 4 + 3] = wv[j].w;
        }
        #pragma unroll
        for (int gi = 0; gi < 4; ++gi) {
            uint4 w;
            w.x = p32[gi * 4 + 0]; w.y = p32[gi * 4 + 1];
            w.z = p32[gi * 4 + 2]; w.w = p32[gi * 4 + 3];
            *reinterpret_cast<uint4*>(ldsK + l * 64 + ((gi ^ (l & 3)) << 4)) = w;
        }
        #pragma unroll
        for (int d = 0; d < 32; ++d) {
            ushort us = (ushort)((p32[d >> 1] >> ((d & 1) * 16)) & 0xffff);
            *reinterpret_cast<ushort*>(ldsVT + d * 1024 + ((l * 2) ^ ((d & 7) << 4))) = us;
        }
    }
    __syncthreads();

    const int w = tid >> 6;
    const int lane = tid & 63;
    const int qcol = lane & 31;
    const int hh = lane >> 5;
    const float r1 = rate1p[0];

    #pragma unroll 1
    for (int qt = 0; qt < 2; ++qt) {
        const int q0 = (w * 2 + qt) * 32;
        const int qrow = q0 + qcol;
        const int nq = hor ? (g * 512 + qrow) : ((qrow & 63) * 64 + g * 8 + (qrow >> 6));

        short8 qb[2];
        #pragma unroll
        for (int t = 0; t < 2; ++t) {
            const ushort* qp = &qvb[(size_t)(b * Nn + nq) * QKVC + qoff + t * 16 + hh * 8];
            qb[t] = *reinterpret_cast<const short8*>(qp);
        }

        f32x16 acc = {0,0,0,0,0,0,0,0,0,0,0,0,0,0,0,0};
        float rs = 0.f;

        for (int s = 0; s < 16; ++s) {
            const int k0 = s * 32;
            const int kr = k0 + qcol;
            const short8 a0 = *reinterpret_cast<const short8*>(
                ldsK + kr * 64 + (((0 + hh) ^ (kr & 3)) << 4));
            const short8 a1 = *reinterpret_cast<const short8*>(
                ldsK + kr * 64 + (((2 + hh) ^ (kr & 3)) << 4));
            f32x16 st = {0,0,0,0,0,0,0,0,0,0,0,0,0,0,0,0};
            st = __builtin_amdgcn_mfma_f32_32x32x16_bf16(a0, qb[0], st, 0, 0, 0);
            st = __builtin_amdgcn_mfma_f32_32x32x16_bf16(a1, qb[1], st, 0, 0, 0);

            float p[16];
            #pragma unroll
            for (int r = 0; r < 16; ++r) p[r] = exp2f(st[r] * QS);
            float s01 = (p[0] + p[1]) + (p[2] + p[3]);
            float s23 = (p[4] + p[5]) + (p[6] + p[7]);
            float s45 = (p[8] + p[9]) + (p[10] + p[11]);
            float s67 = (p[12] + p[13]) + (p[14] + p[15]);
            rs += (s01 + s23) + (s45 + s67);

            uint32_t X[8];
            #pragma unroll
            for (int gg = 0; gg < 4; ++gg) {
                X[2 * gg + 0] = pkbf(p[4 * gg + 0], p[4 * gg + 1]);
                X[2 * gg + 1] = pkbf(p[4 * gg + 2], p[4 * gg + 3]);
            }
            #pragma unroll
            for (int u = 0; u < 2; ++u) {
                uint32_t w0 = X[4 * u + 0], w2 = X[4 * u + 2];
                uint32_t w1 = X[4 * u + 1], w3 = X[4 * u + 3];
                plswap(w0, w2);
                plswap(w1, w3);
                union { uint32_t u4[4]; short8 s; } pf;
                pf.u4[0] = w0; pf.u4[1] = w1; pf.u4[2] = w2; pf.u4[3] = w3;
                const int d = qcol;
                const short8 vf = *reinterpret_cast<const short8*>(
                    ldsVT + d * 1024 + ((k0 * 2 + u * 32 + hh * 16) ^ ((d & 7) << 4)));
                acc = __builtin_amdgcn_mfma_f32_32x32x16_bf16(vf, pf.s, acc, 0, 0, 0);
            }
        }

        float rsf = rs + __shfl_xor(rs, 32);
        float scl = r1 / rsf;
        const float* ap = &Abuf[(size_t)(b * Nn + nq) * DIMc + qoff];
        ushort* hp = &Hb[(size_t)(b * Nn + nq) * DIMc + qoff];
        #pragma unroll
        for (int gg = 0; gg < 4; ++gg) {
            int d0 = 8 * gg + 4 * hh;
            float4 o = *reinterpret_cast<const float4*>(&ap[d0]);
            float v0 = hswish(o.x + acc[4 * gg + 0] * scl);
            float v1 = hswish(o.y + acc[4 * gg + 1] * scl);
            float v2 = hswish(o.z + acc[4 * gg + 2] * scl);
            float v3 = hswish(o.w + acc[4 * gg + 3] * scl);
            uint2 pk; pk.x = pkbf(v0, v1); pk.y = pkbf(v2, v3);
            *reinterpret_cast<uint2*>(&hp[d0]) = pk;
        }
    }
}

// ---------------- BatchNorm normalize ----------------
__global__ __launch_bounds__(256) void bnnorm_kernel(
    const float* __restrict__ Y, const float* __restrict__ stats,
    const float* __restrict__ g, const float* __restrict__ bta,
    float* __restrict__ out)
{
    int idx = blockIdx.x * 256 + threadIdx.x;
    int c = idx & 255;
    float mu = stats[c] * (1.f / (float)Mrows);
    float var = stats[256 + c] * (1.f / (float)Mrows) - mu * mu;
    float inv = rsqrtf(var + 1e-5f);
    out[idx] = (Y[idx] - mu) * inv * g[c] + bta[c];
}

// ---------------- launch ----------------
extern "C" void kernel_launch(void* const* d_in, const int* in_sizes, int n_in,
                              void* d_out, int out_size, void* d_ws, size_t ws_size,
                              hipStream_t stream)
{
    const float* x      = (const float*)d_in[0];
    const float* w_qkv  = (const float*)d_in[1];
    const float* b_qkv  = (const float*)d_in[2];
    const float* w_out  = (const float*)d_in[3];
    const float* b_out  = (const float*)d_in[4];
    const float* bn_g   = (const float*)d_in[5];
    const float* bn_b   = (const float*)d_in[6];
    const float* pconv_w = (const float*)d_in[7];
    const float* pconv_b = (const float*)d_in[8];
    const float* fc_w   = (const float*)d_in[9];
    const float* dep_w  = (const float*)d_in[10];
    const float* dep_b  = (const float*)d_in[11];
    const float* rate1  = (const float*)d_in[12];
    const float* rate2  = (const float*)d_in[13];
    float* out = (float*)d_out;

    char* ws = (char*)d_ws;
    ushort* qvb   = (ushort*)(ws);                           // 32 MB [0,32M)
    ushort* Hb    = (ushort*)(ws + (32u << 20));             // 16 MB [32M,48M)
    ushort* xb    = (ushort*)(ws + (64u << 20));             // 16 MB, aliases Abuf head
    float*  Abuf  = (float*)(ws + (64u << 20));              // 32 MB [64M,96M)
    float*  Ybuf  = (float*)(ws + (96u << 20));              // 32 MB [96M,128M)
    float*  stats = (float*)(ws + (128u << 20));             // 2 KB
    ushort* Wt1   = (ushort*)(ws + (128u << 20) + 4096);     // 256 KB
    ushort* Wt2   = (ushort*)(ws + (128u << 20) + 4096 + (256u << 10)); // 128 KB
    uint32_t* Wp  = (uint32_t*)(ws + (128u << 20) + 4096 + (384u << 10)); // 36 KB

    // 0. prep: bf16 weights (transposed), packed composed conv weights, bf16 x
    wtconv_kernel<<<(512 * 256) / 256, 256, 0, stream>>>(w_qkv, Wt1, 256, 512);
    wtconv_kernel<<<(256 * 256) / 256, 256, 0, stream>>>(w_out, Wt2, 256, 256);
    weff_kernel<<<36, 256, 0, stream>>>(dep_w, fc_w, Wp);
    cvtbf_kernel<<<(Mrows * 256 / 8) / 256, 256, 0, stream>>>(x, xb);

    // 1. qvb = bf16(x @ w_qkv + b_qkv)
    hgemm_kernel<true, false><<<dim3(4, 256), 256, 0, stream>>>(
        xb, Wt1, b_qkv, qvb, nullptr, Mrows, 512, 256);

    // 2. A = depthwise3x3(hard_swish(v)) + pconv_b
    vconv_kernel<<<(Mrows * 128) / 256, 256, 0, stream>>>(qvb, pconv_w, pconv_b, Abuf);

    // 3. fused conv-attention branch (A += rate2 * out_conv, both branches)
    convbranch_kernel<<<1024, 256, 0, stream>>>(qvb, Wp, dep_b, rate2, Abuf);

    // 4. MFMA window attention; epilogue writes Hb = bf16(hswish(A + rate1*o))
    attn_mfma_kernel<<<512, 512, 0, stream>>>(qvb, rate1, Abuf, Hb);

    // 5. Y = Hb @ w_out + b_out, with fused BN stats
    hipMemsetAsync(stats, 0, 2 * 256 * sizeof(float), stream);
    hgemm_kernel<false, true><<<dim3(2, 256), 256, 0, stream>>>(
        Hb, Wt2, b_out, Ybuf, stats, Mrows, 256, 256);

    // 6. BatchNorm normalize
    bnnorm_kernel<<<(Mrows * 256) / 256, 256, 0, stream>>>(Ybuf, stats, bn_g, bn_b, out);
}

// Round 9
// 200.874 us; speedup vs baseline: 10.1907x; 1.1525x over previous
//
#include <hip/hip_runtime.h>
#include <hip/hip_bf16.h>
#include <math.h>

// ---------------- problem constants (fixed instance) ----------------
constexpr int Bn   = 8;
constexpr int Hh   = 64;
constexpr int Ww   = 64;
constexpr int Nn   = Hh * Ww;      // 4096
constexpr int Mrows = Bn * Nn;     // 32768
constexpr int QKVC = 512;          // qv channels
constexpr int DIMc = 256;

typedef short short8 __attribute__((ext_vector_type(8)));
typedef float f32x16 __attribute__((ext_vector_type(16)));
typedef float f32x4 __attribute__((ext_vector_type(4)));

__device__ __forceinline__ float hswish(float x) {
    float r = fminf(fmaxf(x + 3.f, 0.f), 6.f);
    return x * r * (1.f / 6.f);
}

__device__ __forceinline__ ushort bf16u(float f) {
    return __bfloat16_as_ushort(__float2bfloat16(f));
}

__device__ __forceinline__ uint32_t pkbf(float a, float b) {
    return (uint32_t)bf16u(a) | ((uint32_t)bf16u(b) << 16);
}

// packed bf16 dot2: c += a.lo*b.lo + a.hi*b.hi   (v_dot2_f32_bf16, CDNA3/4)
__device__ __forceinline__ float dot2bf(uint32_t a, uint32_t b, float c) {
    asm("v_dot2_f32_bf16 %0, %1, %2, %0" : "+v"(c) : "v"(a), "v"(b));
    return c;
}

__device__ __forceinline__ float bflo(uint32_t p) {
    union { uint32_t u; float f; } c; c.u = p << 16; return c.f;
}
__device__ __forceinline__ float bfhi(uint32_t p) {
    union { uint32_t u; float f; } c; c.u = p & 0xFFFF0000u; return c.f;
}

#if __has_builtin(__builtin_amdgcn_permlane32_swap)
typedef int int2v __attribute__((ext_vector_type(2)));
__device__ __forceinline__ void plswap(uint32_t& a, uint32_t& b) {
    int2v r = __builtin_amdgcn_permlane32_swap((int)a, (int)b, false, false);
    a = (uint32_t)r.x; b = (uint32_t)r.y;
}
#else
__device__ __forceinline__ void plswap(uint32_t& a, uint32_t& b) {
    int l = threadIdx.x & 63;
    uint32_t sa = (uint32_t)__shfl_xor((int)a, 32);
    uint32_t sb = (uint32_t)__shfl_xor((int)b, 32);
    uint32_t na = (l < 32) ? a : sb;
    uint32_t nb = (l < 32) ? sa : b;
    a = na; b = nb;
}
#endif

__device__ __forceinline__ void gload_lds16(const ushort* g, ushort* l) {
    __builtin_amdgcn_global_load_lds(
        (const __attribute__((address_space(1))) unsigned int*)g,
        (__attribute__((address_space(3))) unsigned int*)l, 16, 0, 0);
}

// ---------------- bf16 convert: xb = bf16(x) ----------------
__global__ __launch_bounds__(256) void cvtbf_kernel(
    const float* __restrict__ in, ushort* __restrict__ out)
{
    int i = (blockIdx.x * 256 + threadIdx.x) * 8;
    float4 f0 = *reinterpret_cast<const float4*>(&in[i]);
    float4 f1 = *reinterpret_cast<const float4*>(&in[i + 4]);
    float v[8] = {f0.x, f0.y, f0.z, f0.w, f1.x, f1.y, f1.z, f1.w};
    ushort o[8];
    #pragma unroll
    for (int j = 0; j < 8; ++j) o[j] = bf16u(v[j]);
    *reinterpret_cast<short8*>(&out[i]) = *reinterpret_cast<short8*>(o);
}

// ---------------- weight transpose + bf16 convert: Wt[n][k] = bf16(W[k][n]) ----------------
__global__ __launch_bounds__(256) void wtconv_kernel(
    const float* __restrict__ Wf, ushort* __restrict__ Wt, int K, int N)
{
    int idx = blockIdx.x * 256 + threadIdx.x;   // k fast
    int n = idx / K, k = idx - n * K;
    Wt[idx] = bf16u(Wf[(size_t)k * N + n]);
}

// ---------------- effective conv weights, packed bf16 (q|v) ----------------
__global__ __launch_bounds__(256) void weff_kernel(
    const float* __restrict__ dw, const float* __restrict__ fcw,
    uint32_t* __restrict__ Wp)
{
    int idx = blockIdx.x * 256 + threadIdx.x;   // 9216
    if (idx >= 9216) return;
    int k = idx % 9;
    int a = (idx / 9) & 7;
    int oc = (idx / 72) & 7;
    int gi = idx / 576;
    float q = 0.f, v = 0.f;
    const float* dwp = &dw[(gi * 8 + oc) * 81 + k];
    #pragma unroll
    for (int ic = 0; ic < 9; ++ic) {
        float d = dwp[ic * 9];
        q += d * fcw[ic * 24 + a];
        v += d * (fcw[ic * 24 + 8 + a] + fcw[ic * 24 + 16 + a]);
    }
    Wp[idx] = pkbf(q, v);
}

// ---------------- bf16 MFMA GEMM: C = A[M,K] @ Bt[N,K]^T + bias ----------------
template<bool OBF, bool STATS>
__global__ __launch_bounds__(256) void hgemm_kernel(
    const ushort* __restrict__ A, const ushort* __restrict__ Bt,
    const float* __restrict__ bias, void* __restrict__ Cv,
    float* __restrict__ stats, int M, int N, int K)
{
    __shared__ ushort As[128 * 32];
    __shared__ ushort Bs[128 * 32];
    const int tid = threadIdx.x;
    const int w = tid >> 6, l = tid & 63;
    const int brow = blockIdx.y * 128;
    const int bcol = blockIdx.x * 128;
    const int wm = (w >> 1) * 64, wn = (w & 1) * 64;

    f32x4 acc[4][4] = {};

    const int c0 = tid, c1 = tid + 256;
    const int r0 = c0 >> 2, q0 = (c0 & 3) ^ (r0 & 3);
    const int r1 = c1 >> 2, q1 = (c1 & 3) ^ (r1 & 3);
    const ushort* a0p = &A[(size_t)(brow + r0) * K + q0 * 8];
    const ushort* a1p = &A[(size_t)(brow + r1) * K + q1 * 8];
    const ushort* b0p = &Bt[(size_t)(bcol + r0) * K + q0 * 8];
    const ushort* b1p = &Bt[(size_t)(bcol + r1) * K + q1 * 8];
    ushort* asw0 = &As[(w * 64) * 8];
    ushort* asw1 = &As[(256 + w * 64) * 8];
    ushort* bsw0 = &Bs[(w * 64) * 8];
    ushort* bsw1 = &Bs[(256 + w * 64) * 8];

    const int fr = l & 15;
    const int qq = ((l >> 4) ^ (l & 3)) * 8;

    for (int k0 = 0; k0 < K; k0 += 32) {
        gload_lds16(a0p + k0, asw0);
        gload_lds16(a1p + k0, asw1);
        gload_lds16(b0p + k0, bsw0);
        gload_lds16(b1p + k0, bsw1);
        __syncthreads();
        short8 af[4], bf[4];
        #pragma unroll
        for (int i = 0; i < 4; ++i) {
            af[i] = *reinterpret_cast<const short8*>(&As[(wm + i * 16 + fr) * 32 + qq]);
            bf[i] = *reinterpret_cast<const short8*>(&Bs[(wn + i * 16 + fr) * 32 + qq]);
        }
        #pragma unroll
        for (int mi = 0; mi < 4; ++mi)
            #pragma unroll
            for (int ni = 0; ni < 4; ++ni)
                acc[mi][ni] = __builtin_amdgcn_mfma_f32_16x16x32_bf16(
                    af[mi], bf[ni], acc[mi][ni], 0, 0, 0);
        __syncthreads();
    }

    const int cr = l >> 4;
    #pragma unroll
    for (int ni = 0; ni < 4; ++ni) {
        int n = bcol + wn + ni * 16 + fr;
        float bv = bias[n];
        float s1 = 0.f, s2 = 0.f;
        #pragma unroll
        for (int mi = 0; mi < 4; ++mi) {
            int m = brow + wm + mi * 16 + cr * 4;
            #pragma unroll
            for (int r = 0; r < 4; ++r) {
                float val = acc[mi][ni][r] + bv;
                if (OBF)
                    ((ushort*)Cv)[(size_t)(m + r) * N + n] = bf16u(val);
                else
                    ((float*)Cv)[(size_t)(m + r) * N + n] = val;
                if (STATS) { s1 += val; s2 += val * val; }
            }
        }
        if (STATS) {
            s1 += __shfl_xor(s1, 16); s2 += __shfl_xor(s2, 16);
            s1 += __shfl_xor(s1, 32); s2 += __shfl_xor(s2, 32);
            if (cr == 0) {
                atomicAdd(&stats[n], s1);
                atomicAdd(&stats[256 + n], s2);
            }
        }
    }
}

// ---------------- depthwise 3x3 on hard_swish(v): Abuf(bf16) += v_conv ----------------
// RMW, channel-fast lanes: fully coalesced on both qvb and Abuf.
__global__ __launch_bounds__(256) void vconv_kernel(
    const ushort* __restrict__ qvb, const float* __restrict__ pw,
    const float* __restrict__ pb, ushort* __restrict__ Abuf)
{
    int idx = blockIdx.x * 256 + threadIdx.x;   // Mrows*128
    int c2 = idx & 127;
    int n = (idx >> 7) & (Nn - 1);
    int b = idx >> 19;
    int x = n & 63, y = n >> 6;
    int ch = c2 * 2;
    float s0 = pb[ch], s1 = pb[ch + 1];
    float w0[9], w1[9];
    #pragma unroll
    for (int k = 0; k < 9; ++k) { w0[k] = pw[ch * 9 + k]; w1[k] = pw[ch * 9 + 9 + k]; }
    #pragma unroll
    for (int ky = 0; ky < 3; ++ky) {
        int yy = y + ky - 1;
        if (yy >= 0 && yy < Hh) {
            #pragma unroll
            for (int kx = 0; kx < 3; ++kx) {
                int xx = x + kx - 1;
                if (xx >= 0 && xx < Ww) {
                    uint32_t pk = *reinterpret_cast<const uint32_t*>(
                        &qvb[(size_t)(b * Nn + yy * Ww + xx) * QKVC + 256 + ch]);
                    s0 += hswish(bflo(pk)) * w0[ky * 3 + kx];
                    s1 += hswish(bfhi(pk)) * w1[ky * 3 + kx];
                }
            }
        }
    }
    uint32_t* ap = reinterpret_cast<uint32_t*>(&Abuf[(size_t)(b * Nn + n) * DIMc + ch]);
    uint32_t cur = *ap;
    *ap = pkbf(bflo(cur) + s0, bfhi(cur) + s1);
}

// ---------------- fused conv-attention branch v4: FIRST writer of Abuf(bf16) ----------------
// 2048 blocks = (branch, b, gi, ytile8); 256 threads = 64x * 2rowhalf * 2ocquad.
// Counter-carried staging, u32 global loads (2 px), ds_write_b64, stride-68 rows.
__global__ __launch_bounds__(256) void convbranch_kernel(
    const ushort* __restrict__ qvb, const uint32_t* __restrict__ Wp,
    const float* __restrict__ db, const float* __restrict__ rate2p,
    ushort* __restrict__ Abuf)
{
    int blk = blockIdx.x;              // 2048
    int ytile = blk & 7;               // bits 0-2
    int gi = (blk >> 3) & 15;          // bits 3-6
    int b = (blk >> 7) & 7;            // bits 7-9   (FIXED: was >>6, overlapped gi)
    int branch = blk >> 10;            // bit 10
    int y0 = ytile * 8;
    int qoff = branch * 128;
    int coff = branch * 128;

    __shared__ uint32_t sqv[8][10][68];   // 21.25 KB; cols: halo@1, data 2..65, halo@66
    __shared__ uint32_t wpk[8][8][9];     // 2.25 KB [oc][a][k]
    const int tid = threadIdx.x;

    // zero x-halo columns (always outside image)
    if (tid < 160) {
        int r = tid >> 1;
        int col = 1 + (tid & 1) * 65;
        sqv[r / 10][r % 10][col] = 0;
    }
    // stage: 80 rows of 64 px; 8 rows/iter; lane covers 2 px via u32 loads
    {
        const int x2 = (tid & 31) * 2;
        int rr = tid >> 5;             // 0..7
        int a = 0;
        const size_t bbase = (size_t)(b * Nn) * QKVC + qoff;
        #pragma unroll
        for (int it = 0; it < 10; ++it) {
            int y = y0 + rr - 1;
            uint32_t lo = 0, hi = 0;
            if ((unsigned)y < 64u) {
                int token = (a * 16 + gi) * 32 + (y >> 1);
                size_t base = bbase + (size_t)token * QKVC + (y & 1) * 64 + x2;
                uint32_t q = *reinterpret_cast<const uint32_t*>(&qvb[base]);
                uint32_t v = *reinterpret_cast<const uint32_t*>(&qvb[base + 256]);
                lo = (q & 0xffffu) | (v << 16);
                hi = (q >> 16) | (v & 0xffff0000u);
            }
            uint2 wv; wv.x = lo; wv.y = hi;
            *reinterpret_cast<uint2*>(&sqv[a][rr][2 + x2]) = wv;
            rr += 8;
            if (rr >= 10) { rr -= 10; a += 1; }
        }
    }
    for (int i = tid; i < 576; i += 256)
        ((uint32_t*)wpk)[i] = Wp[gi * 576 + i];
    __syncthreads();

    const int x = tid & 63;
    const int w = tid >> 6;
    const int rh = (w & 1) * 4;        // row base within 8-row tile
    const int oc0 = (w >> 1) * 4;      // 4 oc per thread

    float acc[4][4] = {};              // [ocl][row]
    #pragma unroll 1
    for (int a = 0; a < 8; ++a) {
        uint32_t ipk[6][3];
        #pragma unroll
        for (int j = 0; j < 6; ++j) {
            const uint32_t* rp = &sqv[a][rh + j][1 + x];
            ipk[j][0] = rp[0]; ipk[j][1] = rp[1]; ipk[j][2] = rp[2];
        }
        #pragma unroll
        for (int ocl = 0; ocl < 4; ++ocl) {
            #pragma unroll
            for (int ky = 0; ky < 3; ++ky)
                #pragma unroll
                for (int kx = 0; kx < 3; ++kx) {
                    uint32_t wv = wpk[oc0 + ocl][a][ky * 3 + kx];
                    #pragma unroll
                    for (int ro = 0; ro < 4; ++ro)
                        acc[ocl][ro] = dot2bf(ipk[ro + ky][kx], wv, acc[ocl][ro]);
                }
        }
    }

    // epilogue: scale+bias, pack bf16, direct store (first writer, no RMW)
    const float r2 = rate2p[0];
    float dbv[4];
    #pragma unroll
    for (int j = 0; j < 4; ++j) dbv[j] = db[gi * 8 + oc0 + j];
    #pragma unroll
    for (int ro = 0; ro < 4; ++ro) {
        int n = (y0 + rh + ro) * 64 + x;
        uint2 pk;
        pk.x = pkbf(r2 * (acc[0][ro] + dbv[0]), r2 * (acc[1][ro] + dbv[1]));
        pk.y = pkbf(r2 * (acc[2][ro] + dbv[2]), r2 * (acc[3][ro] + dbv[3]));
        *reinterpret_cast<uint2*>(
            &Abuf[(size_t)(b * Nn + n) * DIMc + coff + gi * 8 + oc0]) = pk;
    }
}

// ---------------- MFMA cross-shaped window attention (k == v, bf16 input) ----------------
// Epilogue fused: Hb = bf16(hswish(Abuf(bf16) + rate1 * o))
__global__ __launch_bounds__(512) void attn_mfma_kernel(
    const ushort* __restrict__ qvb, const float* __restrict__ rate1p,
    const ushort* __restrict__ Abuf, ushort* __restrict__ Hb)
{
    int bid = blockIdx.x;
    bool hor = bid < 256;
    int lb = bid & 255;
    int hd = lb & 3;
    int g = (lb >> 2) & 7;
    int b = lb >> 5;
    int half = hor ? 0 : 128;
    int qoff = half + hd * 32;
    int kvoff = 256 + qoff;

    __shared__ __align__(16) char smem[65536];
    char* ldsK  = smem;            // 32 KB
    char* ldsVT = smem + 32768;    // 32 KB

    const int tid = threadIdx.x;
    const float QS = 0.17677669529663687f * 1.44269504088896f;  // scale * log2(e)

    {
        int l = tid;
        int n = hor ? (g * 512 + l) : ((l & 63) * 64 + g * 8 + (l >> 6));
        const ushort* kp = &qvb[(size_t)(b * Nn + n) * QKVC + kvoff];
        uint4 wv[4];
        #pragma unroll
        for (int j = 0; j < 4; ++j)
            wv[j] = *reinterpret_cast<const uint4*>(&kp[j * 8]);
        uint32_t p32[16];
        #pragma unroll
        for (int j = 0; j < 4; ++j) {
            p32[j * 4 + 0] = wv[j].x; p32[j * 4 + 1] = wv[j].y;
            p32[j * 4 + 2] = wv[j].z; p32[j * 4 + 3] = wv[j].w;
        }
        #pragma unroll
        for (int gi = 0; gi < 4; ++gi) {
            uint4 w;
            w.x = p32[gi * 4 + 0]; w.y = p32[gi * 4 + 1];
            w.z = p32[gi * 4 + 2]; w.w = p32[gi * 4 + 3];
            *reinterpret_cast<uint4*>(ldsK + l * 64 + ((gi ^ (l & 3)) << 4)) = w;
        }
        #pragma unroll
        for (int d = 0; d < 32; ++d) {
            ushort us = (ushort)((p32[d >> 1] >> ((d & 1) * 16)) & 0xffff);
            *reinterpret_cast<ushort*>(ldsVT + d * 1024 + ((l * 2) ^ ((d & 7) << 4))) = us;
        }
    }
    __syncthreads();

    const int w = tid >> 6;
    const int lane = tid & 63;
    const int qcol = lane & 31;
    const int hh = lane >> 5;
    const float r1 = rate1p[0];

    #pragma unroll 1
    for (int qt = 0; qt < 2; ++qt) {
        const int q0 = (w * 2 + qt) * 32;
        const int qrow = q0 + qcol;
        const int nq = hor ? (g * 512 + qrow) : ((qrow & 63) * 64 + g * 8 + (qrow >> 6));

        short8 qb[2];
        #pragma unroll
        for (int t = 0; t < 2; ++t) {
            const ushort* qp = &qvb[(size_t)(b * Nn + nq) * QKVC + qoff + t * 16 + hh * 8];
            qb[t] = *reinterpret_cast<const short8*>(qp);
        }

        f32x16 acc = {0,0,0,0,0,0,0,0,0,0,0,0,0,0,0,0};
        float rs = 0.f;

        for (int s = 0; s < 16; ++s) {
            const int k0 = s * 32;
            const int kr = k0 + qcol;
            const short8 a0 = *reinterpret_cast<const short8*>(
                ldsK + kr * 64 + (((0 + hh) ^ (kr & 3)) << 4));
            const short8 a1 = *reinterpret_cast<const short8*>(
                ldsK + kr * 64 + (((2 + hh) ^ (kr & 3)) << 4));
            f32x16 st = {0,0,0,0,0,0,0,0,0,0,0,0,0,0,0,0};
            st = __builtin_amdgcn_mfma_f32_32x32x16_bf16(a0, qb[0], st, 0, 0, 0);
            st = __builtin_amdgcn_mfma_f32_32x32x16_bf16(a1, qb[1], st, 0, 0, 0);

            float p[16];
            #pragma unroll
            for (int r = 0; r < 16; ++r) p[r] = exp2f(st[r] * QS);
            float s01 = (p[0] + p[1]) + (p[2] + p[3]);
            float s23 = (p[4] + p[5]) + (p[6] + p[7]);
            float s45 = (p[8] + p[9]) + (p[10] + p[11]);
            float s67 = (p[12] + p[13]) + (p[14] + p[15]);
            rs += (s01 + s23) + (s45 + s67);

            uint32_t X[8];
            #pragma unroll
            for (int gg = 0; gg < 4; ++gg) {
                X[2 * gg + 0] = pkbf(p[4 * gg + 0], p[4 * gg + 1]);
                X[2 * gg + 1] = pkbf(p[4 * gg + 2], p[4 * gg + 3]);
            }
            #pragma unroll
            for (int u = 0; u < 2; ++u) {
                uint32_t w0 = X[4 * u + 0], w2 = X[4 * u + 2];
                uint32_t w1 = X[4 * u + 1], w3 = X[4 * u + 3];
                plswap(w0, w2);
                plswap(w1, w3);
                union { uint32_t u4[4]; short8 s; } pf;
                pf.u4[0] = w0; pf.u4[1] = w1; pf.u4[2] = w2; pf.u4[3] = w3;
                const int d = qcol;
                const short8 vf = *reinterpret_cast<const short8*>(
                    ldsVT + d * 1024 + ((k0 * 2 + u * 32 + hh * 16) ^ ((d & 7) << 4)));
                acc = __builtin_amdgcn_mfma_f32_32x32x16_bf16(vf, pf.s, acc, 0, 0, 0);
            }
        }

        float rsf = rs + __shfl_xor(rs, 32);
        float scl = r1 / rsf;
        const ushort* ap = &Abuf[(size_t)(b * Nn + nq) * DIMc + qoff];
        ushort* hp = &Hb[(size_t)(b * Nn + nq) * DIMc + qoff];
        #pragma unroll
        for (int gg = 0; gg < 4; ++gg) {
            int d0 = 8 * gg + 4 * hh;
            uint2 av = *reinterpret_cast<const uint2*>(&ap[d0]);
            float v0 = hswish(bflo(av.x) + acc[4 * gg + 0] * scl);
            float v1 = hswish(bfhi(av.x) + acc[4 * gg + 1] * scl);
            float v2 = hswish(bflo(av.y) + acc[4 * gg + 2] * scl);
            float v3 = hswish(bfhi(av.y) + acc[4 * gg + 3] * scl);
            uint2 pk; pk.x = pkbf(v0, v1); pk.y = pkbf(v2, v3);
            *reinterpret_cast<uint2*>(&hp[d0]) = pk;
        }
    }
}

// ---------------- BatchNorm normalize (x4 vectorized) ----------------
__global__ __launch_bounds__(256) void bnnorm_kernel(
    const float* __restrict__ Y, const float* __restrict__ stats,
    const float* __restrict__ g, const float* __restrict__ bta,
    float* __restrict__ out)
{
    int i4 = (blockIdx.x * 256 + threadIdx.x) * 4;
    int c = i4 & 255;
    float4 y = *reinterpret_cast<const float4*>(&Y[i4]);
    float4 mu = *reinterpret_cast<const float4*>(&stats[c]);
    float4 s2 = *reinterpret_cast<const float4*>(&stats[256 + c]);
    float4 gg = *reinterpret_cast<const float4*>(&g[c]);
    float4 bb = *reinterpret_cast<const float4*>(&bta[c]);
    const float inv_m = 1.f / (float)Mrows;
    float4 o;
    {
        float m = mu.x * inv_m, v = s2.x * inv_m - m * m;
        o.x = (y.x - m) * rsqrtf(v + 1e-5f) * gg.x + bb.x;
        m = mu.y * inv_m; v = s2.y * inv_m - m * m;
        o.y = (y.y - m) * rsqrtf(v + 1e-5f) * gg.y + bb.y;
        m = mu.z * inv_m; v = s2.z * inv_m - m * m;
        o.z = (y.z - m) * rsqrtf(v + 1e-5f) * gg.z + bb.z;
        m = mu.w * inv_m; v = s2.w * inv_m - m * m;
        o.w = (y.w - m) * rsqrtf(v + 1e-5f) * gg.w + bb.w;
    }
    *reinterpret_cast<float4*>(&out[i4]) = o;
}

// ---------------- launch ----------------
extern "C" void kernel_launch(void* const* d_in, const int* in_sizes, int n_in,
                              void* d_out, int out_size, void* d_ws, size_t ws_size,
                              hipStream_t stream)
{
    const float* x      = (const float*)d_in[0];
    const float* w_qkv  = (const float*)d_in[1];
    const float* b_qkv  = (const float*)d_in[2];
    const float* w_out  = (const float*)d_in[3];
    const float* b_out  = (const float*)d_in[4];
    const float* bn_g   = (const float*)d_in[5];
    const float* bn_b   = (const float*)d_in[6];
    const float* pconv_w = (const float*)d_in[7];
    const float* pconv_b = (const float*)d_in[8];
    const float* fc_w   = (const float*)d_in[9];
    const float* dep_w  = (const float*)d_in[10];
    const float* dep_b  = (const float*)d_in[11];
    const float* rate1  = (const float*)d_in[12];
    const float* rate2  = (const float*)d_in[13];
    float* out = (float*)d_out;

    char* ws = (char*)d_ws;
    ushort* qvb   = (ushort*)(ws);                           // 32 MB [0,32M)
    ushort* Hb    = (ushort*)(ws + (32u << 20));             // 16 MB [32M,48M)
    ushort* Abuf  = (ushort*)(ws + (48u << 20));             // 16 MB [48M,64M)
    ushort* xb    = (ushort*)(ws + (64u << 20));             // 16 MB [64M,80M)
    float*  Ybuf  = (float*)(ws + (96u << 20));              // 32 MB [96M,128M)
    float*  stats = (float*)(ws + (128u << 20));             // 2 KB
    ushort* Wt1   = (ushort*)(ws + (128u << 20) + 4096);     // 256 KB
    ushort* Wt2   = (ushort*)(ws + (128u << 20) + 4096 + (256u << 10)); // 128 KB
    uint32_t* Wp  = (uint32_t*)(ws + (128u << 20) + 4096 + (384u << 10)); // 36 KB

    // 0. prep: bf16 weights (transposed), packed composed conv weights, bf16 x
    wtconv_kernel<<<(512 * 256) / 256, 256, 0, stream>>>(w_qkv, Wt1, 256, 512);
    wtconv_kernel<<<(256 * 256) / 256, 256, 0, stream>>>(w_out, Wt2, 256, 256);
    weff_kernel<<<36, 256, 0, stream>>>(dep_w, fc_w, Wp);
    cvtbf_kernel<<<(Mrows * 256 / 8) / 256, 256, 0, stream>>>(x, xb);

    // 1. qvb = bf16(x @ w_qkv + b_qkv)
    hgemm_kernel<true, false><<<dim3(4, 256), 256, 0, stream>>>(
        xb, Wt1, b_qkv, qvb, nullptr, Mrows, 512, 256);

    // 2. Abuf = rate2 * out_conv  (first writer, pure store)
    convbranch_kernel<<<2048, 256, 0, stream>>>(qvb, Wp, dep_b, rate2, Abuf);

    // 3. Abuf += v_conv  (coalesced bf16 RMW)
    vconv_kernel<<<(Mrows * 128) / 256, 256, 0, stream>>>(qvb, pconv_w, pconv_b, Abuf);

    // 4. MFMA window attention; epilogue writes Hb = bf16(hswish(A + rate1*o))
    attn_mfma_kernel<<<512, 512, 0, stream>>>(qvb, rate1, Abuf, Hb);

    // 5. Y = Hb @ w_out + b_out, with fused BN stats
    hipMemsetAsync(stats, 0, 2 * 256 * sizeof(float), stream);
    hgemm_kernel<false, true><<<dim3(2, 256), 256, 0, stream>>>(
        Hb, Wt2, b_out, Ybuf, stats, Mrows, 256, 256);

    // 6. BatchNorm normalize
    bnnorm_kernel<<<(Mrows * 256 / 4) / 256, 256, 0, stream>>>(Ybuf, stats, bn_g, bn_b, out);
}

// Round 10
// 193.254 us; speedup vs baseline: 10.5925x; 1.0394x over previous
//
#include <hip/hip_runtime.h>
#include <hip/hip_bf16.h>
#include <math.h>

// ---------------- problem constants (fixed instance) ----------------
constexpr int Bn   = 8;
constexpr int Hh   = 64;
constexpr int Ww   = 64;
constexpr int Nn   = Hh * Ww;      // 4096
constexpr int Mrows = Bn * Nn;     // 32768
constexpr int QKVC = 512;          // qv channels
constexpr int DIMc = 256;

typedef short short8 __attribute__((ext_vector_type(8)));
typedef float f32x16 __attribute__((ext_vector_type(16)));
typedef float f32x4 __attribute__((ext_vector_type(4)));

__device__ __forceinline__ float hswish(float x) {
    float r = fminf(fmaxf(x + 3.f, 0.f), 6.f);
    return x * r * (1.f / 6.f);
}

__device__ __forceinline__ ushort bf16u(float f) {
    return __bfloat16_as_ushort(__float2bfloat16(f));
}

__device__ __forceinline__ uint32_t pkbf(float a, float b) {
    return (uint32_t)bf16u(a) | ((uint32_t)bf16u(b) << 16);
}

// HW packed bf16 convert (RNE): lo=cvt(a), hi=cvt(b) — no builtin, asm only
__device__ __forceinline__ uint32_t cvtpk(float a, float b) {
    uint32_t r;
    asm("v_cvt_pk_bf16_f32 %0, %1, %2" : "=v"(r) : "v"(a), "v"(b));
    return r;
}

// packed bf16 dot2: c += a.lo*b.lo + a.hi*b.hi   (v_dot2_f32_bf16, CDNA3/4)
__device__ __forceinline__ float dot2bf(uint32_t a, uint32_t b, float c) {
    asm("v_dot2_f32_bf16 %0, %1, %2, %0" : "+v"(c) : "v"(a), "v"(b));
    return c;
}

__device__ __forceinline__ float bflo(uint32_t p) {
    union { uint32_t u; float f; } c; c.u = p << 16; return c.f;
}
__device__ __forceinline__ float bfhi(uint32_t p) {
    union { uint32_t u; float f; } c; c.u = p & 0xFFFF0000u; return c.f;
}

#if __has_builtin(__builtin_amdgcn_permlane32_swap)
typedef int int2v __attribute__((ext_vector_type(2)));
__device__ __forceinline__ void plswap(uint32_t& a, uint32_t& b) {
    int2v r = __builtin_amdgcn_permlane32_swap((int)a, (int)b, false, false);
    a = (uint32_t)r.x; b = (uint32_t)r.y;
}
#else
__device__ __forceinline__ void plswap(uint32_t& a, uint32_t& b) {
    int l = threadIdx.x & 63;
    uint32_t sa = (uint32_t)__shfl_xor((int)a, 32);
    uint32_t sb = (uint32_t)__shfl_xor((int)b, 32);
    uint32_t na = (l < 32) ? a : sb;
    uint32_t nb = (l < 32) ? sa : b;
    a = na; b = nb;
}
#endif

__device__ __forceinline__ void gload_lds16(const ushort* g, ushort* l) {
    __builtin_amdgcn_global_load_lds(
        (const __attribute__((address_space(1))) unsigned int*)g,
        (__attribute__((address_space(3))) unsigned int*)l, 16, 0, 0);
}

// ---------------- bf16 convert: xb = bf16(x) ----------------
__global__ __launch_bounds__(256) void cvtbf_kernel(
    const float* __restrict__ in, ushort* __restrict__ out)
{
    int i = (blockIdx.x * 256 + threadIdx.x) * 8;
    float4 f0 = *reinterpret_cast<const float4*>(&in[i]);
    float4 f1 = *reinterpret_cast<const float4*>(&in[i + 4]);
    float v[8] = {f0.x, f0.y, f0.z, f0.w, f1.x, f1.y, f1.z, f1.w};
    ushort o[8];
    #pragma unroll
    for (int j = 0; j < 8; ++j) o[j] = bf16u(v[j]);
    *reinterpret_cast<short8*>(&out[i]) = *reinterpret_cast<short8*>(o);
}

// ---------------- weight transpose + bf16 convert: Wt[n][k] = bf16(W[k][n]) ----------------
__global__ __launch_bounds__(256) void wtconv_kernel(
    const float* __restrict__ Wf, ushort* __restrict__ Wt, int K, int N)
{
    int idx = blockIdx.x * 256 + threadIdx.x;   // k fast
    int n = idx / K, k = idx - n * K;
    Wt[idx] = bf16u(Wf[(size_t)k * N + n]);
}

// ---------------- effective conv weights, packed bf16 (q|v) ----------------
__global__ __launch_bounds__(256) void weff_kernel(
    const float* __restrict__ dw, const float* __restrict__ fcw,
    uint32_t* __restrict__ Wp)
{
    int idx = blockIdx.x * 256 + threadIdx.x;   // 9216
    if (idx >= 9216) return;
    int k = idx % 9;
    int a = (idx / 9) & 7;
    int oc = (idx / 72) & 7;
    int gi = idx / 576;
    float q = 0.f, v = 0.f;
    const float* dwp = &dw[(gi * 8 + oc) * 81 + k];
    #pragma unroll
    for (int ic = 0; ic < 9; ++ic) {
        float d = dwp[ic * 9];
        q += d * fcw[ic * 24 + a];
        v += d * (fcw[ic * 24 + 8 + a] + fcw[ic * 24 + 16 + a]);
    }
    Wp[idx] = pkbf(q, v);
}

// ---------------- bf16 MFMA GEMM: C = A[M,K] @ Bt[N,K]^T + bias ----------------
template<bool OBF, bool STATS>
__global__ __launch_bounds__(256) void hgemm_kernel(
    const ushort* __restrict__ A, const ushort* __restrict__ Bt,
    const float* __restrict__ bias, void* __restrict__ Cv,
    float* __restrict__ stats, int M, int N, int K)
{
    __shared__ ushort As[128 * 32];
    __shared__ ushort Bs[128 * 32];
    const int tid = threadIdx.x;
    const int w = tid >> 6, l = tid & 63;
    const int brow = blockIdx.y * 128;
    const int bcol = blockIdx.x * 128;
    const int wm = (w >> 1) * 64, wn = (w & 1) * 64;

    f32x4 acc[4][4] = {};

    const int c0 = tid, c1 = tid + 256;
    const int r0 = c0 >> 2, q0 = (c0 & 3) ^ (r0 & 3);
    const int r1 = c1 >> 2, q1 = (c1 & 3) ^ (r1 & 3);
    const ushort* a0p = &A[(size_t)(brow + r0) * K + q0 * 8];
    const ushort* a1p = &A[(size_t)(brow + r1) * K + q1 * 8];
    const ushort* b0p = &Bt[(size_t)(bcol + r0) * K + q0 * 8];
    const ushort* b1p = &Bt[(size_t)(bcol + r1) * K + q1 * 8];
    ushort* asw0 = &As[(w * 64) * 8];
    ushort* asw1 = &As[(256 + w * 64) * 8];
    ushort* bsw0 = &Bs[(w * 64) * 8];
    ushort* bsw1 = &Bs[(256 + w * 64) * 8];

    const int fr = l & 15;
    const int qq = ((l >> 4) ^ (l & 3)) * 8;

    for (int k0 = 0; k0 < K; k0 += 32) {
        gload_lds16(a0p + k0, asw0);
        gload_lds16(a1p + k0, asw1);
        gload_lds16(b0p + k0, bsw0);
        gload_lds16(b1p + k0, bsw1);
        __syncthreads();
        short8 af[4], bf[4];
        #pragma unroll
        for (int i = 0; i < 4; ++i) {
            af[i] = *reinterpret_cast<const short8*>(&As[(wm + i * 16 + fr) * 32 + qq]);
            bf[i] = *reinterpret_cast<const short8*>(&Bs[(wn + i * 16 + fr) * 32 + qq]);
        }
        #pragma unroll
        for (int mi = 0; mi < 4; ++mi)
            #pragma unroll
            for (int ni = 0; ni < 4; ++ni)
                acc[mi][ni] = __builtin_amdgcn_mfma_f32_16x16x32_bf16(
                    af[mi], bf[ni], acc[mi][ni], 0, 0, 0);
        __syncthreads();
    }

    const int cr = l >> 4;
    #pragma unroll
    for (int ni = 0; ni < 4; ++ni) {
        int n = bcol + wn + ni * 16 + fr;
        float bv = bias[n];
        float s1 = 0.f, s2 = 0.f;
        #pragma unroll
        for (int mi = 0; mi < 4; ++mi) {
            int m = brow + wm + mi * 16 + cr * 4;
            #pragma unroll
            for (int r = 0; r < 4; ++r) {
                float val = acc[mi][ni][r] + bv;
                if (OBF)
                    ((ushort*)Cv)[(size_t)(m + r) * N + n] = bf16u(val);
                else
                    ((float*)Cv)[(size_t)(m + r) * N + n] = val;
                if (STATS) { s1 += val; s2 += val * val; }
            }
        }
        if (STATS) {
            s1 += __shfl_xor(s1, 16); s2 += __shfl_xor(s2, 16);
            s1 += __shfl_xor(s1, 32); s2 += __shfl_xor(s2, 32);
            if (cr == 0) {
                atomicAdd(&stats[n], s1);
                atomicAdd(&stats[256 + n], s2);
            }
        }
    }
}

// ---------------- depthwise 3x3 on hard_swish(v): Abuf(bf16) += v_conv ----------------
__global__ __launch_bounds__(256) void vconv_kernel(
    const ushort* __restrict__ qvb, const float* __restrict__ pw,
    const float* __restrict__ pb, ushort* __restrict__ Abuf)
{
    int idx = blockIdx.x * 256 + threadIdx.x;   // Mrows*128
    int c2 = idx & 127;
    int n = (idx >> 7) & (Nn - 1);
    int b = idx >> 19;
    int x = n & 63, y = n >> 6;
    int ch = c2 * 2;
    float s0 = pb[ch], s1 = pb[ch + 1];
    float w0[9], w1[9];
    #pragma unroll
    for (int k = 0; k < 9; ++k) { w0[k] = pw[ch * 9 + k]; w1[k] = pw[ch * 9 + 9 + k]; }
    #pragma unroll
    for (int ky = 0; ky < 3; ++ky) {
        int yy = y + ky - 1;
        if (yy >= 0 && yy < Hh) {
            #pragma unroll
            for (int kx = 0; kx < 3; ++kx) {
                int xx = x + kx - 1;
                if (xx >= 0 && xx < Ww) {
                    uint32_t pk = *reinterpret_cast<const uint32_t*>(
                        &qvb[(size_t)(b * Nn + yy * Ww + xx) * QKVC + 256 + ch]);
                    s0 += hswish(bflo(pk)) * w0[ky * 3 + kx];
                    s1 += hswish(bfhi(pk)) * w1[ky * 3 + kx];
                }
            }
        }
    }
    uint32_t* ap = reinterpret_cast<uint32_t*>(&Abuf[(size_t)(b * Nn + n) * DIMc + ch]);
    uint32_t cur = *ap;
    *ap = pkbf(bflo(cur) + s0, bfhi(cur) + s1);
}

// ---------------- fused conv-attention branch v4: FIRST writer of Abuf(bf16) ----------------
__global__ __launch_bounds__(256) void convbranch_kernel(
    const ushort* __restrict__ qvb, const uint32_t* __restrict__ Wp,
    const float* __restrict__ db, const float* __restrict__ rate2p,
    ushort* __restrict__ Abuf)
{
    int blk = blockIdx.x;              // 2048
    int ytile = blk & 7;               // bits 0-2
    int gi = (blk >> 3) & 15;          // bits 3-6
    int b = (blk >> 7) & 7;            // bits 7-9
    int branch = blk >> 10;            // bit 10
    int y0 = ytile * 8;
    int qoff = branch * 128;
    int coff = branch * 128;

    __shared__ uint32_t sqv[8][10][68];   // 21.25 KB; cols: halo@1, data 2..65, halo@66
    __shared__ uint32_t wpk[8][8][9];     // 2.25 KB [oc][a][k]
    const int tid = threadIdx.x;

    if (tid < 160) {
        int r = tid >> 1;
        int col = 1 + (tid & 1) * 65;
        sqv[r / 10][r % 10][col] = 0;
    }
    {
        const int x2 = (tid & 31) * 2;
        int rr = tid >> 5;             // 0..7
        int a = 0;
        const size_t bbase = (size_t)(b * Nn) * QKVC + qoff;
        #pragma unroll
        for (int it = 0; it < 10; ++it) {
            int y = y0 + rr - 1;
            uint32_t lo = 0, hi = 0;
            if ((unsigned)y < 64u) {
                int token = (a * 16 + gi) * 32 + (y >> 1);
                size_t base = bbase + (size_t)token * QKVC + (y & 1) * 64 + x2;
                uint32_t q = *reinterpret_cast<const uint32_t*>(&qvb[base]);
                uint32_t v = *reinterpret_cast<const uint32_t*>(&qvb[base + 256]);
                lo = (q & 0xffffu) | (v << 16);
                hi = (q >> 16) | (v & 0xffff0000u);
            }
            uint2 wv; wv.x = lo; wv.y = hi;
            *reinterpret_cast<uint2*>(&sqv[a][rr][2 + x2]) = wv;
            rr += 8;
            if (rr >= 10) { rr -= 10; a += 1; }
        }
    }
    for (int i = tid; i < 576; i += 256)
        ((uint32_t*)wpk)[i] = Wp[gi * 576 + i];
    __syncthreads();

    const int x = tid & 63;
    const int w = tid >> 6;
    const int rh = (w & 1) * 4;
    const int oc0 = (w >> 1) * 4;

    float acc[4][4] = {};
    #pragma unroll 1
    for (int a = 0; a < 8; ++a) {
        uint32_t ipk[6][3];
        #pragma unroll
        for (int j = 0; j < 6; ++j) {
            const uint32_t* rp = &sqv[a][rh + j][1 + x];
            ipk[j][0] = rp[0]; ipk[j][1] = rp[1]; ipk[j][2] = rp[2];
        }
        #pragma unroll
        for (int ocl = 0; ocl < 4; ++ocl) {
            #pragma unroll
            for (int ky = 0; ky < 3; ++ky)
                #pragma unroll
                for (int kx = 0; kx < 3; ++kx) {
                    uint32_t wv = wpk[oc0 + ocl][a][ky * 3 + kx];
                    #pragma unroll
                    for (int ro = 0; ro < 4; ++ro)
                        acc[ocl][ro] = dot2bf(ipk[ro + ky][kx], wv, acc[ocl][ro]);
                }
        }
    }

    const float r2 = rate2p[0];
    float dbv[4];
    #pragma unroll
    for (int j = 0; j < 4; ++j) dbv[j] = db[gi * 8 + oc0 + j];
    #pragma unroll
    for (int ro = 0; ro < 4; ++ro) {
        int n = (y0 + rh + ro) * 64 + x;
        uint2 pk;
        pk.x = pkbf(r2 * (acc[0][ro] + dbv[0]), r2 * (acc[1][ro] + dbv[1]));
        pk.y = pkbf(r2 * (acc[2][ro] + dbv[2]), r2 * (acc[3][ro] + dbv[3]));
        *reinterpret_cast<uint2*>(
            &Abuf[(size_t)(b * Nn + n) * DIMc + coff + gi * 8 + oc0]) = pk;
    }
}

// ---------------- MFMA cross-shaped window attention (k == v, bf16 input) ----------------
// K LDS: paired-row layout — rows (2p,2p+1) share a 128B line; 16B chunk
//   c = (k&1)*4 + g, swizzled c ^= (p&7)  → conflict-free b128 read/write.
// VT LDS: [d][token] bf16, byte (tok*2)^((d&7)<<4); staged as u32 via DPP pair-exchange.
// Epilogue fused: Hb = bf16(hswish(Abuf(bf16) + rate1 * o))
__global__ __launch_bounds__(512) void attn_mfma_kernel(
    const ushort* __restrict__ qvb, const float* __restrict__ rate1p,
    const ushort* __restrict__ Abuf, ushort* __restrict__ Hb)
{
    int bid = blockIdx.x;
    bool hor = bid < 256;
    int lb = bid & 255;
    int hd = lb & 3;
    int g = (lb >> 2) & 7;
    int b = lb >> 5;
    int half = hor ? 0 : 128;
    int qoff = half + hd * 32;
    int kvoff = 256 + qoff;

    __shared__ __align__(16) char smem[65536];
    char* ldsK  = smem;            // 32 KB (512 rows x 64B, paired-line layout)
    char* ldsVT = smem + 32768;    // 32 KB

    const int tid = threadIdx.x;
    const float QS = 0.17677669529663687f * 1.44269504088896f;  // scale * log2(e)

    {
        int l = tid;
        int n = hor ? (g * 512 + l) : ((l & 63) * 64 + g * 8 + (l >> 6));
        const ushort* kp = &qvb[(size_t)(b * Nn + n) * QKVC + kvoff];
        uint32_t p32[16];
        #pragma unroll
        for (int j = 0; j < 4; ++j) {
            uint4 wv = *reinterpret_cast<const uint4*>(&kp[j * 8]);
            p32[j * 4 + 0] = wv.x; p32[j * 4 + 1] = wv.y;
            p32[j * 4 + 2] = wv.z; p32[j * 4 + 3] = wv.w;
        }
        // K: paired-row 8-slot swizzle
        const int kpair = l >> 1, hf = l & 1;
        #pragma unroll
        for (int gc = 0; gc < 4; ++gc) {
            int cp = (hf * 4 + gc) ^ (kpair & 7);
            uint4 w;
            w.x = p32[gc * 4 + 0]; w.y = p32[gc * 4 + 1];
            w.z = p32[gc * 4 + 2]; w.w = p32[gc * 4 + 3];
            *reinterpret_cast<uint4*>(ldsK + kpair * 128 + cp * 16) = w;
        }
        // VT: u32 writes (2 tokens/word) via DPP lane-pair exchange
        #pragma unroll
        for (int j = 0; j < 16; ++j) {
            uint32_t other = (uint32_t)__shfl_xor((int)p32[j], 1);
            uint32_t pk = hf ? ((other >> 16) | (p32[j] & 0xffff0000u))
                             : ((p32[j] & 0xffffu) | (other << 16));
            int d = 2 * j + hf;
            *reinterpret_cast<uint32_t*>(
                ldsVT + d * 1024 + ((kpair * 4) ^ ((d & 7) << 4))) = pk;
        }
    }
    __syncthreads();

    const int w = tid >> 6;
    const int lane = tid & 63;
    const int qcol = lane & 31;
    const int hh = lane >> 5;
    const float r1 = rate1p[0];
    const f32x16 fz = {0,0,0,0,0,0,0,0,0,0,0,0,0,0,0,0};

    // constant K-read bases: row kr = s*32+qcol -> kpair = s*16+(qcol>>1),
    // slot = ((qcol&1)*4 + g) ^ ((qcol>>1)&7)  (s*16 ≡ 0 mod 8)
    const int kp0 = qcol >> 1;
    const char* pK = ldsK + kp0 * 128;
    const int ca0 = ((((qcol & 1) * 4) + hh) ^ (kp0 & 7)) * 16;
    const int ca1 = ((((qcol & 1) * 4) + 2 + hh) ^ (kp0 & 7)) * 16;
    const int dvt = qcol;
    const char* pVT = ldsVT + dvt * 1024;
    const int vtx = (hh * 16) ^ ((dvt & 7) << 4);

    #pragma unroll 1
    for (int qt = 0; qt < 2; ++qt) {
        const int q0 = (w * 2 + qt) * 32;
        const int qrow = q0 + qcol;
        const int nq = hor ? (g * 512 + qrow) : ((qrow & 63) * 64 + g * 8 + (qrow >> 6));

        // Q B-frags, pre-scaled by QS (unpack-mul-cvt_pk once per qt)
        short8 qs[2];
        #pragma unroll
        for (int t = 0; t < 2; ++t) {
            const ushort* qp = &qvb[(size_t)(b * Nn + nq) * QKVC + qoff + t * 16 + hh * 8];
            uint4 raw = *reinterpret_cast<const uint4*>(qp);
            union { uint32_t u[4]; short8 s; } qa;
            qa.u[0] = cvtpk(bflo(raw.x) * QS, bfhi(raw.x) * QS);
            qa.u[1] = cvtpk(bflo(raw.y) * QS, bfhi(raw.y) * QS);
            qa.u[2] = cvtpk(bflo(raw.z) * QS, bfhi(raw.z) * QS);
            qa.u[3] = cvtpk(bflo(raw.w) * QS, bfhi(raw.w) * QS);
            qs[t] = qa.s;
        }

        f32x16 acc = fz;
        float rs = 0.f;

        for (int s = 0; s < 16; ++s) {
            const short8 a0 = *reinterpret_cast<const short8*>(pK + s * 2048 + ca0);
            const short8 a1 = *reinterpret_cast<const short8*>(pK + s * 2048 + ca1);
            f32x16 st = __builtin_amdgcn_mfma_f32_32x32x16_bf16(a0, qs[0], fz, 0, 0, 0);
            st = __builtin_amdgcn_mfma_f32_32x32x16_bf16(a1, qs[1], st, 0, 0, 0);

            float p[16];
            #pragma unroll
            for (int r = 0; r < 16; ++r) p[r] = exp2f(st[r]);
            float s01 = (p[0] + p[1]) + (p[2] + p[3]);
            float s23 = (p[4] + p[5]) + (p[6] + p[7]);
            float s45 = (p[8] + p[9]) + (p[10] + p[11]);
            float s67 = (p[12] + p[13]) + (p[14] + p[15]);
            rs += (s01 + s23) + (s45 + s67);

            uint32_t X[8];
            #pragma unroll
            for (int gg = 0; gg < 4; ++gg) {
                X[2 * gg + 0] = cvtpk(p[4 * gg + 0], p[4 * gg + 1]);
                X[2 * gg + 1] = cvtpk(p[4 * gg + 2], p[4 * gg + 3]);
            }
            const int k0 = s * 32;
            #pragma unroll
            for (int u = 0; u < 2; ++u) {
                uint32_t w0 = X[4 * u + 0], w2 = X[4 * u + 2];
                uint32_t w1 = X[4 * u + 1], w3 = X[4 * u + 3];
                plswap(w0, w2);
                plswap(w1, w3);
                union { uint32_t u4[4]; short8 s; } pf;
                pf.u4[0] = w0; pf.u4[1] = w1; pf.u4[2] = w2; pf.u4[3] = w3;
                const short8 vf = *reinterpret_cast<const short8*>(
                    pVT + ((k0 * 2 + u * 32) ^ vtx));
                acc = __builtin_amdgcn_mfma_f32_32x32x16_bf16(vf, pf.s, acc, 0, 0, 0);
            }
        }

        float rsf = rs + __shfl_xor(rs, 32);
        float scl = r1 / rsf;
        const ushort* ap = &Abuf[(size_t)(b * Nn + nq) * DIMc + qoff];
        ushort* hp = &Hb[(size_t)(b * Nn + nq) * DIMc + qoff];
        #pragma unroll
        for (int gg = 0; gg < 4; ++gg) {
            int d0 = 8 * gg + 4 * hh;
            uint2 av = *reinterpret_cast<const uint2*>(&ap[d0]);
            float v0 = hswish(bflo(av.x) + acc[4 * gg + 0] * scl);
            float v1 = hswish(bfhi(av.x) + acc[4 * gg + 1] * scl);
            float v2 = hswish(bflo(av.y) + acc[4 * gg + 2] * scl);
            float v3 = hswish(bfhi(av.y) + acc[4 * gg + 3] * scl);
            uint2 pk; pk.x = cvtpk(v0, v1); pk.y = cvtpk(v2, v3);
            *reinterpret_cast<uint2*>(&hp[d0]) = pk;
        }
    }
}

// ---------------- BatchNorm normalize (x4 vectorized) ----------------
__global__ __launch_bounds__(256) void bnnorm_kernel(
    const float* __restrict__ Y, const float* __restrict__ stats,
    const float* __restrict__ g, const float* __restrict__ bta,
    float* __restrict__ out)
{
    int i4 = (blockIdx.x * 256 + threadIdx.x) * 4;
    int c = i4 & 255;
    float4 y = *reinterpret_cast<const float4*>(&Y[i4]);
    float4 mu = *reinterpret_cast<const float4*>(&stats[c]);
    float4 s2 = *reinterpret_cast<const float4*>(&stats[256 + c]);
    float4 gg = *reinterpret_cast<const float4*>(&g[c]);
    float4 bb = *reinterpret_cast<const float4*>(&bta[c]);
    const float inv_m = 1.f / (float)Mrows;
    float4 o;
    {
        float m = mu.x * inv_m, v = s2.x * inv_m - m * m;
        o.x = (y.x - m) * rsqrtf(v + 1e-5f) * gg.x + bb.x;
        m = mu.y * inv_m; v = s2.y * inv_m - m * m;
        o.y = (y.y - m) * rsqrtf(v + 1e-5f) * gg.y + bb.y;
        m = mu.z * inv_m; v = s2.z * inv_m - m * m;
        o.z = (y.z - m) * rsqrtf(v + 1e-5f) * gg.z + bb.z;
        m = mu.w * inv_m; v = s2.w * inv_m - m * m;
        o.w = (y.w - m) * rsqrtf(v + 1e-5f) * gg.w + bb.w;
    }
    *reinterpret_cast<float4*>(&out[i4]) = o;
}

// ---------------- launch ----------------
extern "C" void kernel_launch(void* const* d_in, const int* in_sizes, int n_in,
                              void* d_out, int out_size, void* d_ws, size_t ws_size,
                              hipStream_t stream)
{
    const float* x      = (const float*)d_in[0];
    const float* w_qkv  = (const float*)d_in[1];
    const float* b_qkv  = (const float*)d_in[2];
    const float* w_out  = (const float*)d_in[3];
    const float* b_out  = (const float*)d_in[4];
    const float* bn_g   = (const float*)d_in[5];
    const float* bn_b   = (const float*)d_in[6];
    const float* pconv_w = (const float*)d_in[7];
    const float* pconv_b = (const float*)d_in[8];
    const float* fc_w   = (const float*)d_in[9];
    const float* dep_w  = (const float*)d_in[10];
    const float* dep_b  = (const float*)d_in[11];
    const float* rate1  = (const float*)d_in[12];
    const float* rate2  = (const float*)d_in[13];
    float* out = (float*)d_out;

    char* ws = (char*)d_ws;
    ushort* qvb   = (ushort*)(ws);                           // 32 MB [0,32M)
    ushort* Hb    = (ushort*)(ws + (32u << 20));             // 16 MB [32M,48M)
    ushort* Abuf  = (ushort*)(ws + (48u << 20));             // 16 MB [48M,64M)
    ushort* xb    = (ushort*)(ws + (64u << 20));             // 16 MB [64M,80M)
    float*  Ybuf  = (float*)(ws + (96u << 20));              // 32 MB [96M,128M)
    float*  stats = (float*)(ws + (128u << 20));             // 2 KB
    ushort* Wt1   = (ushort*)(ws + (128u << 20) + 4096);     // 256 KB
    ushort* Wt2   = (ushort*)(ws + (128u << 20) + 4096 + (256u << 10)); // 128 KB
    uint32_t* Wp  = (uint32_t*)(ws + (128u << 20) + 4096 + (384u << 10)); // 36 KB

    // 0. prep: bf16 weights (transposed), packed composed conv weights, bf16 x
    wtconv_kernel<<<(512 * 256) / 256, 256, 0, stream>>>(w_qkv, Wt1, 256, 512);
    wtconv_kernel<<<(256 * 256) / 256, 256, 0, stream>>>(w_out, Wt2, 256, 256);
    weff_kernel<<<36, 256, 0, stream>>>(dep_w, fc_w, Wp);
    cvtbf_kernel<<<(Mrows * 256 / 8) / 256, 256, 0, stream>>>(x, xb);

    // 1. qvb = bf16(x @ w_qkv + b_qkv)
    hgemm_kernel<true, false><<<dim3(4, 256), 256, 0, stream>>>(
        xb, Wt1, b_qkv, qvb, nullptr, Mrows, 512, 256);

    // 2. Abuf = rate2 * out_conv  (first writer, pure store)
    convbranch_kernel<<<2048, 256, 0, stream>>>(qvb, Wp, dep_b, rate2, Abuf);

    // 3. Abuf += v_conv  (coalesced bf16 RMW)
    vconv_kernel<<<(Mrows * 128) / 256, 256, 0, stream>>>(qvb, pconv_w, pconv_b, Abuf);

    // 4. MFMA window attention; epilogue writes Hb = bf16(hswish(A + rate1*o))
    attn_mfma_kernel<<<512, 512, 0, stream>>>(qvb, rate1, Abuf, Hb);

    // 5. Y = Hb @ w_out + b_out, with fused BN stats
    hipMemsetAsync(stats, 0, 2 * 256 * sizeof(float), stream);
    hgemm_kernel<false, true><<<dim3(2, 256), 256, 0, stream>>>(
        Hb, Wt2, b_out, Ybuf, stats, Mrows, 256, 256);

    // 6. BatchNorm normalize
    bnnorm_kernel<<<(Mrows * 256 / 4) / 256, 256, 0, stream>>>(Ybuf, stats, bn_g, bn_b, out);
}